// Round 1
// baseline (10987.881 us; speedup 1.0000x reference)
//
#include <hip/hip_runtime.h>
#include <hip/hip_bf16.h>

// ---------------- problem constants ----------------
#define DIMC   512
#define HEADS  8
#define DH     64
#define MLM    256          // landmarks
#define NPATCH 40000
#define NTOK   40001        // with cls
#define PADF   191          // front zero pad
#define NSEQ   40192        // NTOK + PADF
#define LWIN   157          // NSEQ / MLM
#define INDIM  1024
#define GRID   200
#define CHUNKS 64
#define PER    628          // NSEQ / CHUNKS

// ---------------- reductions ----------------
template<int NW, bool ISMAX>
__device__ __forceinline__ float blkRed(float v, float* s) {
  #pragma unroll
  for (int o = 32; o; o >>= 1) {
    float t = __shfl_down(v, o, 64);
    v = ISMAX ? fmaxf(v, t) : v + t;
  }
  int lane = threadIdx.x & 63, w = threadIdx.x >> 6;
  __syncthreads();
  if (lane == 0) s[w] = v;
  __syncthreads();
  float r = s[0];
  #pragma unroll
  for (int i = 1; i < NW; i++) r = ISMAX ? fmaxf(r, s[i]) : r + s[i];
  return r;
}

// ---------------- misc small kernels ----------------
__global__ __launch_bounds__(512)
void k_set_cls(const float* __restrict__ cls, float* __restrict__ h) {
  h[threadIdx.x] = cls[threadIdx.x];
}

// ---------------- generic fp32 GEMM: C = [relu]( A(MrxK) @ B(KxN) + bias [+ C] ) ----------------
// flags: 1 = relu, 2 = accumulate into C
__global__ __launch_bounds__(256)
void k_gemm(const float* __restrict__ A, const float* __restrict__ B,
            const float* __restrict__ bias, float* __restrict__ C,
            int Mr, int K, int N, int flags)
{
  __shared__ float As[64][17];
  __shared__ float Bs[16][64];
  int bm = blockIdx.x * 64;
  int bn = blockIdx.y * 64;
  int tid = threadIdx.x;
  int tx = tid & 15, ty = tid >> 4;
  float acc[4][4] = {};
  for (int k0 = 0; k0 < K; k0 += 16) {
    #pragma unroll
    for (int e = tid; e < 64 * 16; e += 256) {
      int m = e >> 4, k = e & 15;
      int gm = bm + m;
      As[m][k] = (gm < Mr) ? A[(size_t)gm * K + k0 + k] : 0.f;
    }
    #pragma unroll
    for (int e = tid; e < 16 * 64; e += 256) {
      int k = e >> 6, n = e & 63;
      Bs[k][n] = B[(size_t)(k0 + k) * N + bn + n];
    }
    __syncthreads();
    #pragma unroll
    for (int k = 0; k < 16; k++) {
      float a[4], b[4];
      #pragma unroll
      for (int i = 0; i < 4; i++) a[i] = As[ty * 4 + i][k];
      #pragma unroll
      for (int j = 0; j < 4; j++) b[j] = Bs[k][tx * 4 + j];
      #pragma unroll
      for (int i = 0; i < 4; i++)
        #pragma unroll
        for (int j = 0; j < 4; j++) acc[i][j] += a[i] * b[j];
    }
    __syncthreads();
  }
  #pragma unroll
  for (int i = 0; i < 4; i++) {
    int gm = bm + ty * 4 + i;
    if (gm >= Mr) continue;
    #pragma unroll
    for (int j = 0; j < 4; j++) {
      int gn = bn + tx * 4 + j;
      float v = acc[i][j];
      if (bias) v += bias[gn];
      if (flags & 2) v += C[(size_t)gm * N + gn];
      if (flags & 1) v = fmaxf(v, 0.f);
      C[(size_t)gm * N + gn] = v;
    }
  }
}

// ---------------- layernorm + front zero pad ----------------
__global__ __launch_bounds__(256)
void k_ln_pad(const float* __restrict__ h, const float* __restrict__ w,
              const float* __restrict__ b, float* __restrict__ xln)
{
  __shared__ float sbuf[8];
  int t = blockIdx.x;
  int tid = threadIdx.x;
  float* out = xln + (size_t)t * DIMC;
  if (t < PADF) { out[tid] = 0.f; out[tid + 256] = 0.f; return; }
  const float* row = h + (size_t)(t - PADF) * DIMC;
  float x0 = row[tid], x1 = row[tid + 256];
  float mu = blkRed<4,false>(x0 + x1, sbuf) * (1.f / 512.f);
  float d0 = x0 - mu, d1 = x1 - mu;
  float var = blkRed<4,false>(d0 * d0 + d1 * d1, sbuf) * (1.f / 512.f);
  float rstd = rsqrtf(var + 1e-5f);
  out[tid]       = d0 * rstd * w[tid]       + b[tid];
  out[tid + 256] = d1 * rstd * w[tid + 256] + b[tid + 256];
}

// ---------------- landmarks (q scaled by DH^-0.5 folded here) ----------------
__global__ __launch_bounds__(64)
void k_landmarks(const float* __restrict__ qkv, float* __restrict__ ql, float* __restrict__ kl)
{
  int h = blockIdx.x >> 8;
  int i = blockIdx.x & 255;
  int d = threadIdx.x;
  const float* base = qkv + (size_t)(i * LWIN) * (3 * DIMC) + h * DH + d;
  float sq = 0.f, sk = 0.f;
  for (int j = 0; j < LWIN; j++) {
    sq += base[0];
    sk += base[DIMC];
    base += 3 * DIMC;
  }
  ql[(h * MLM + i) * DH + d] = sq * (0.125f / (float)LWIN);
  kl[(h * MLM + i) * DH + d] = sk * (1.f   / (float)LWIN);
}

// ---------------- attn2 = softmax(q_l @ k_l^T) ----------------
__global__ __launch_bounds__(256)
void k_attn2(const float* __restrict__ ql, const float* __restrict__ kl, float* __restrict__ a2)
{
  __shared__ float qrow[DH];
  __shared__ float sbuf[8];
  int h = blockIdx.x >> 8, i = blockIdx.x & 255;
  int j = threadIdx.x;
  if (j < DH) qrow[j] = ql[(h * MLM + i) * DH + j];
  __syncthreads();
  const float* krow = kl + (size_t)(h * MLM + j) * DH;
  float s = 0.f;
  #pragma unroll 16
  for (int d = 0; d < DH; d++) s += qrow[d] * krow[d];
  float mx = blkRed<4,true>(s, sbuf);
  float e = __expf(s - mx);
  float sum = blkRed<4,false>(e, sbuf);
  a2[((size_t)h * MLM + i) * MLM + j] = e / sum;
}

// ---------------- pinv init ----------------
__global__ __launch_bounds__(256)
void k_pinv_init1(const float* __restrict__ a2, float* __restrict__ hmax)
{
  __shared__ float sbuf[8];
  int h = blockIdx.x;
  int j = threadIdx.x;
  const float* A = a2 + (size_t)h * MLM * MLM;
  float cs = 0.f, rs = 0.f;
  for (int i = 0; i < MLM; i++) cs += A[i * MLM + j];
  for (int k = 0; k < MLM; k++) rs += A[j * MLM + k];
  float rmax = blkRed<4,true>(rs, sbuf);
  float cmax = blkRed<4,true>(cs, sbuf);
  if (j == 0) { hmax[h * 2] = rmax; hmax[h * 2 + 1] = cmax; }
}

__global__ void k_pinv_init2(const float* __restrict__ hmax, float* __restrict__ scal)
{
  float rm = 0.f, cm = 0.f;
  for (int h = 0; h < HEADS; h++) { rm = fmaxf(rm, hmax[2*h]); cm = fmaxf(cm, hmax[2*h+1]); }
  scal[0] = 1.f / (rm * cm);
}

__global__ __launch_bounds__(256)
void k_transpose_scale(const float* __restrict__ a2, const float* __restrict__ scal, float* __restrict__ z)
{
  int h = blockIdx.x >> 8, j = blockIdx.x & 255;
  int i = threadIdx.x;
  z[((size_t)h * MLM + j) * MLM + i] = a2[((size_t)h * MLM + i) * MLM + j] * scal[0];
}

// ---------------- batched 256xN matmul: C[h] = c0*(A[h]@B[h]) + c1*E[h] ----------------
// A: 8 x 256 x 256, B: 8 x 256 x N, C/E: 8 x 256 x N
__global__ __launch_bounds__(256)
void k_bmm(const float* __restrict__ A, const float* __restrict__ Bm,
           const float* __restrict__ E, float* __restrict__ C,
           int N, float c0, float c1)
{
  __shared__ float As[64][17];
  __shared__ float Bs[16][64];
  int ntiles = N >> 6;
  int h = blockIdx.y;
  int bm = (blockIdx.x / ntiles) << 6;
  int bn = (blockIdx.x % ntiles) << 6;
  const float* Ah = A + (size_t)h * (MLM * MLM);
  const float* Bh = Bm + (size_t)h * (MLM * N);
  int tid = threadIdx.x;
  int tx = tid & 15, ty = tid >> 4;
  float acc[4][4] = {};
  for (int k0 = 0; k0 < MLM; k0 += 16) {
    #pragma unroll
    for (int e = tid; e < 64 * 16; e += 256) {
      int m = e >> 4, k = e & 15;
      As[m][k] = Ah[(size_t)(bm + m) * MLM + k0 + k];
    }
    #pragma unroll
    for (int e = tid; e < 16 * 64; e += 256) {
      int k = e >> 6, n = e & 63;
      Bs[k][n] = Bh[(size_t)(k0 + k) * N + bn + n];
    }
    __syncthreads();
    #pragma unroll
    for (int k = 0; k < 16; k++) {
      float a[4], b[4];
      #pragma unroll
      for (int i = 0; i < 4; i++) a[i] = As[ty * 4 + i][k];
      #pragma unroll
      for (int j = 0; j < 4; j++) b[j] = Bs[k][tx * 4 + j];
      #pragma unroll
      for (int i = 0; i < 4; i++)
        #pragma unroll
        for (int j = 0; j < 4; j++) acc[i][j] += a[i] * b[j];
    }
    __syncthreads();
  }
  #pragma unroll
  for (int i = 0; i < 4; i++) {
    int gm = bm + ty * 4 + i;
    #pragma unroll
    for (int j = 0; j < 4; j++) {
      int gn = bn + tx * 4 + j;
      size_t idx = (size_t)h * (MLM * N) + (size_t)gm * N + gn;
      float v = c0 * acc[i][j];
      if (E) v += c1 * E[idx];
      C[idx] = v;
    }
  }
}

// ---------------- attn3 @ v, flash-style split over token chunks ----------------
__global__ __launch_bounds__(256)
void k_attn3_partial(const float* __restrict__ qkv, const float* __restrict__ ql,
                     float* __restrict__ pm, float* __restrict__ ps, float* __restrict__ pacc)
{
  int c = blockIdx.x, h = blockIdx.y;
  int i = threadIdx.x;           // landmark row
  int t0 = c * PER;
  float q[DH];
  {
    const float4* qr = (const float4*)(ql + ((size_t)h * MLM + i) * DH);
    #pragma unroll
    for (int dd = 0; dd < 16; dd++) {
      float4 v = qr[dd];
      q[4*dd] = v.x; q[4*dd+1] = v.y; q[4*dd+2] = v.z; q[4*dd+3] = v.w;
    }
  }
  __shared__ float ks[16][DH];
  __shared__ float vs[16][DH];
  // pass 1: row max
  float m = -1e30f;
  for (int tb = 0; tb < PER; tb += 16) {
    int nt = min(16, PER - tb);
    __syncthreads();
    for (int e = threadIdx.x; e < nt * 16; e += 256) {
      int tt = e >> 4, d4 = e & 15;
      ((float4*)&ks[0][0])[e] =
        *(const float4*)(qkv + (size_t)(t0 + tb + tt) * (3*DIMC) + DIMC + h * DH + d4 * 4);
    }
    __syncthreads();
    for (int tt = 0; tt < nt; tt++) {
      const float4* kr = (const float4*)&ks[tt][0];
      float s = 0.f;
      #pragma unroll
      for (int dd = 0; dd < 16; dd++) {
        float4 kv = kr[dd];
        s += q[4*dd]*kv.x + q[4*dd+1]*kv.y + q[4*dd+2]*kv.z + q[4*dd+3]*kv.w;
      }
      m = fmaxf(m, s);
    }
  }
  // pass 2: exp-sum + weighted v accumulation
  float l = 0.f;
  float acc[DH] = {};
  for (int tb = 0; tb < PER; tb += 16) {
    int nt = min(16, PER - tb);
    __syncthreads();
    for (int e = threadIdx.x; e < nt * 16; e += 256) {
      int tt = e >> 4, d4 = e & 15;
      const float* base = qkv + (size_t)(t0 + tb + tt) * (3*DIMC) + h * DH + d4 * 4;
      ((float4*)&ks[0][0])[e] = *(const float4*)(base + DIMC);
      ((float4*)&vs[0][0])[e] = *(const float4*)(base + 2*DIMC);
    }
    __syncthreads();
    for (int tt = 0; tt < nt; tt++) {
      const float4* kr = (const float4*)&ks[tt][0];
      float s = 0.f;
      #pragma unroll
      for (int dd = 0; dd < 16; dd++) {
        float4 kv = kr[dd];
        s += q[4*dd]*kv.x + q[4*dd+1]*kv.y + q[4*dd+2]*kv.z + q[4*dd+3]*kv.w;
      }
      float p = __expf(s - m);
      l += p;
      const float4* vr = (const float4*)&vs[tt][0];
      #pragma unroll
      for (int dd = 0; dd < 16; dd++) {
        float4 vv = vr[dd];
        acc[4*dd]   += p * vv.x; acc[4*dd+1] += p * vv.y;
        acc[4*dd+2] += p * vv.z; acc[4*dd+3] += p * vv.w;
      }
    }
  }
  int idx = (h * CHUNKS + c) * MLM + i;
  pm[idx] = m;
  ps[idx] = l;
  float4* pa = (float4*)(pacc + (size_t)idx * DH);
  #pragma unroll
  for (int dd = 0; dd < 16; dd++)
    pa[dd] = make_float4(acc[4*dd], acc[4*dd+1], acc[4*dd+2], acc[4*dd+3]);
}

__global__ __launch_bounds__(64)
void k_attn3_reduce(const float* __restrict__ pm, const float* __restrict__ ps,
                    const float* __restrict__ pacc, float* __restrict__ av)
{
  int h = blockIdx.x >> 8, i = blockIdx.x & 255;
  int d = threadIdx.x;
  float m = -1e30f;
  for (int c = 0; c < CHUNKS; c++) m = fmaxf(m, pm[(h * CHUNKS + c) * MLM + i]);
  float l = 0.f, a = 0.f;
  for (int c = 0; c < CHUNKS; c++) {
    int idx = (h * CHUNKS + c) * MLM + i;
    float w = __expf(pm[idx] - m);
    l += ps[idx] * w;
    a += pacc[(size_t)idx * DH + d] * w;
  }
  av[((size_t)h * MLM + i) * DH + d] = a / l;
}

// ---------------- attn1 @ w2 + depthwise conv residual on v ----------------
__global__ __launch_bounds__(256)
void k_attn1(const float* __restrict__ qkv, const float* __restrict__ kl,
             const float* __restrict__ w2, const float* __restrict__ rw,
             float* __restrict__ outh)
{
  int h = blockIdx.y;
  int t = PADF + blockIdx.x * 256 + threadIdx.x;
  bool act = (t < NSEQ);
  int tc = act ? t : (NSEQ - 1);
  float q[DH];
  {
    const float4* qr = (const float4*)(qkv + (size_t)tc * (3*DIMC) + h * DH);
    #pragma unroll
    for (int dd = 0; dd < 16; dd++) {
      float4 v = qr[dd];
      q[4*dd] = v.x*0.125f; q[4*dd+1] = v.y*0.125f; q[4*dd+2] = v.z*0.125f; q[4*dd+3] = v.w*0.125f;
    }
  }
  __shared__ float klt[64][DH];
  __shared__ float w2t[64][DH];
  // pass 1: max over 256 landmark scores
  float mx = -1e30f;
  for (int j0 = 0; j0 < MLM; j0 += 64) {
    __syncthreads();
    {
      const float4* src = (const float4*)(kl + ((size_t)h * MLM + j0) * DH);
      float4* dst = (float4*)&klt[0][0];
      #pragma unroll
      for (int e = threadIdx.x; e < 1024; e += 256) dst[e] = src[e];
    }
    __syncthreads();
    for (int j = 0; j < 64; j++) {
      const float4* kr = (const float4*)&klt[j][0];
      float s = 0.f;
      #pragma unroll
      for (int dd = 0; dd < 16; dd++) {
        float4 kv = kr[dd];
        s += q[4*dd]*kv.x + q[4*dd+1]*kv.y + q[4*dd+2]*kv.z + q[4*dd+3]*kv.w;
      }
      mx = fmaxf(mx, s);
    }
  }
  // pass 2: softmax-weighted sum of w2 rows
  float l = 0.f;
  float acc[DH] = {};
  for (int j0 = 0; j0 < MLM; j0 += 64) {
    __syncthreads();
    {
      const float4* src1 = (const float4*)(kl + ((size_t)h * MLM + j0) * DH);
      const float4* src2 = (const float4*)(w2 + ((size_t)h * MLM + j0) * DH);
      float4* dst1 = (float4*)&klt[0][0];
      float4* dst2 = (float4*)&w2t[0][0];
      #pragma unroll
      for (int e = threadIdx.x; e < 1024; e += 256) { dst1[e] = src1[e]; dst2[e] = src2[e]; }
    }
    __syncthreads();
    for (int j = 0; j < 64; j++) {
      const float4* kr = (const float4*)&klt[j][0];
      float s = 0.f;
      #pragma unroll
      for (int dd = 0; dd < 16; dd++) {
        float4 kv = kr[dd];
        s += q[4*dd]*kv.x + q[4*dd+1]*kv.y + q[4*dd+2]*kv.z + q[4*dd+3]*kv.w;
      }
      float p = __expf(s - mx);
      l += p;
      const float4* wr = (const float4*)&w2t[j][0];
      #pragma unroll
      for (int dd = 0; dd < 16; dd++) {
        float4 wv = wr[dd];
        acc[4*dd]   += p * wv.x; acc[4*dd+1] += p * wv.y;
        acc[4*dd+2] += p * wv.z; acc[4*dd+3] += p * wv.w;
      }
    }
  }
  if (act) {
    float inv = 1.f / l;
    #pragma unroll
    for (int d = 0; d < DH; d++) acc[d] *= inv;
    // depthwise conv residual: sum_k rw[h][k] * v[t-16+k]
    for (int kk = 0; kk < 33; kk++) {
      int ts = t - 16 + kk;
      if (ts < 0 || ts >= NSEQ) continue;
      float cf = rw[h * 33 + kk];
      const float4* vr = (const float4*)(qkv + (size_t)ts * (3*DIMC) + 2*DIMC + h * DH);
      #pragma unroll
      for (int dd = 0; dd < 16; dd++) {
        float4 vv = vr[dd];
        acc[4*dd]   += cf * vv.x; acc[4*dd+1] += cf * vv.y;
        acc[4*dd+2] += cf * vv.z; acc[4*dd+3] += cf * vv.w;
      }
    }
    float4* dst = (float4*)(outh + (size_t)t * DIMC + h * DH);
    #pragma unroll
    for (int dd = 0; dd < 16; dd++)
      dst[dd] = make_float4(acc[4*dd], acc[4*dd+1], acc[4*dd+2], acc[4*dd+3]);
  }
}

// ---------------- PPEG ----------------
__global__ __launch_bounds__(256)
void k_transpose_fw(const float* __restrict__ h, float* __restrict__ g)
{
  __shared__ float tile[32][33];
  int pb = blockIdx.x * 32, cb = blockIdx.y * 32;
  int x = threadIdx.x & 31, y0 = threadIdx.x >> 5;
  #pragma unroll
  for (int yy = y0; yy < 32; yy += 8)
    tile[yy][x] = h[(size_t)(1 + pb + yy) * DIMC + cb + x];
  __syncthreads();
  #pragma unroll
  for (int yy = y0; yy < 32; yy += 8)
    g[(size_t)(cb + yy) * NPATCH + pb + x] = tile[x][yy];
}

__global__ __launch_bounds__(256)
void k_ppeg(const float* __restrict__ g,
            const float* __restrict__ w7, const float* __restrict__ b7,
            const float* __restrict__ w5, const float* __restrict__ b5,
            const float* __restrict__ w3, const float* __restrict__ b3,
            float* __restrict__ o)
{
  __shared__ float tl[22][22];
  int c = blockIdx.y;
  int ty0 = (blockIdx.x / 13) * 16, tx0 = (blockIdx.x % 13) * 16;
  const float* gc = g + (size_t)c * NPATCH;
  for (int e = threadIdx.x; e < 22 * 22; e += 256) {
    int yy = e / 22, xx = e % 22;
    int y = ty0 - 3 + yy, x = tx0 - 3 + xx;
    tl[yy][xx] = (y >= 0 && y < GRID && x >= 0 && x < GRID) ? gc[y * GRID + x] : 0.f;
  }
  __syncthreads();
  int ly = threadIdx.x >> 4, lx = threadIdx.x & 15;
  int y = ty0 + ly, x = tx0 + lx;
  if (y >= GRID || x >= GRID) return;
  float acc = tl[ly + 3][lx + 3] + b7[c] + b5[c] + b3[c];
  #pragma unroll
  for (int ky = 0; ky < 7; ky++)
    #pragma unroll
    for (int kx = 0; kx < 7; kx++)
      acc += w7[c * 49 + ky * 7 + kx] * tl[ly + ky][lx + kx];
  #pragma unroll
  for (int ky = 0; ky < 5; ky++)
    #pragma unroll
    for (int kx = 0; kx < 5; kx++)
      acc += w5[c * 25 + ky * 5 + kx] * tl[ly + 1 + ky][lx + 1 + kx];
  #pragma unroll
  for (int ky = 0; ky < 3; ky++)
    #pragma unroll
    for (int kx = 0; kx < 3; kx++)
      acc += w3[c * 9 + ky * 3 + kx] * tl[ly + 2 + ky][lx + 2 + kx];
  o[(size_t)c * NPATCH + y * GRID + x] = acc;
}

__global__ __launch_bounds__(256)
void k_transpose_bw(const float* __restrict__ g, float* __restrict__ h)
{
  __shared__ float tile[32][33];
  int pb = blockIdx.x * 32, cb = blockIdx.y * 32;
  int x = threadIdx.x & 31, y0 = threadIdx.x >> 5;
  #pragma unroll
  for (int yy = y0; yy < 32; yy += 8)
    tile[yy][x] = g[(size_t)(cb + yy) * NPATCH + pb + x];
  __syncthreads();
  #pragma unroll
  for (int yy = y0; yy < 32; yy += 8)
    h[(size_t)(1 + pb + yy) * DIMC + cb + x] = tile[x][yy];
}

// ---------------- final: layernorm(row 0) @ fc2 ----------------
__global__ __launch_bounds__(512)
void k_final(const float* __restrict__ h, const float* __restrict__ nw, const float* __restrict__ nb,
             const float* __restrict__ fw, const float* __restrict__ fb, float* __restrict__ out)
{
  __shared__ float sbuf[8];
  int d = threadIdx.x;
  float x = h[d];
  float mu = blkRed<8,false>(x, sbuf) * (1.f / 512.f);
  float dd = x - mu;
  float var = blkRed<8,false>(dd * dd, sbuf) * (1.f / 512.f);
  float cls = dd * rsqrtf(var + 1e-5f) * nw[d] + nb[d];
  float l0 = blkRed<8,false>(cls * fw[d * 2 + 0], sbuf);
  float l1 = blkRed<8,false>(cls * fw[d * 2 + 1], sbuf);
  if (d == 0) { out[0] = l0 + fb[0]; out[1] = l1 + fb[1]; }
}

// ---------------- host orchestration ----------------
struct WsPtrs {
  float *h, *xln, *qkv, *ql, *kl, *a2, *zA, *zB, *xz, *u, *u2, *av, *w2, *hmax, *scal, *pm, *ps, *pacc;
};

static void attention_layer(const WsPtrs& P,
                            const float* nw, const float* nb, const float* qkvw,
                            const float* ow, const float* ob, const float* rw,
                            hipStream_t stream)
{
  k_ln_pad<<<NSEQ, 256, 0, stream>>>(P.h, nw, nb, P.xln);
  k_gemm<<<dim3(NSEQ / 64, 1536 / 64), 256, 0, stream>>>(P.xln, qkvw, nullptr, P.qkv, NSEQ, DIMC, 3 * DIMC, 0);
  k_landmarks<<<HEADS * MLM, 64, 0, stream>>>(P.qkv, P.ql, P.kl);
  k_attn2<<<HEADS * MLM, 256, 0, stream>>>(P.ql, P.kl, P.a2);
  k_pinv_init1<<<HEADS, 256, 0, stream>>>(P.a2, P.hmax);
  k_pinv_init2<<<1, 1, 0, stream>>>(P.hmax, P.scal);
  k_transpose_scale<<<HEADS * MLM, 256, 0, stream>>>(P.a2, P.scal, P.zA);
  float* z = P.zA; float* zn = P.zB;
  for (int it = 0; it < 6; it++) {
    k_bmm<<<dim3(16, HEADS), 256, 0, stream>>>(P.a2, z,    nullptr, P.xz, MLM, 1.f,   0.f);
    k_bmm<<<dim3(16, HEADS), 256, 0, stream>>>(P.xz, P.xz, P.xz,    P.u,  MLM, -1.f,  7.f);
    k_bmm<<<dim3(16, HEADS), 256, 0, stream>>>(P.xz, P.u,  P.xz,    P.u2, MLM, -1.f,  15.f);
    k_bmm<<<dim3(16, HEADS), 256, 0, stream>>>(z,    P.u2, z,       zn,   MLM, -0.25f, 3.25f);
    float* t = z; z = zn; zn = t;
  }
  k_attn3_partial<<<dim3(CHUNKS, HEADS), 256, 0, stream>>>(P.qkv, P.ql, P.pm, P.ps, P.pacc);
  k_attn3_reduce<<<HEADS * MLM, 64, 0, stream>>>(P.pm, P.ps, P.pacc, P.av);
  k_bmm<<<dim3(4, HEADS), 256, 0, stream>>>(z, P.av, nullptr, P.w2, DH, 1.f, 0.f);
  k_attn1<<<dim3(157, HEADS), 256, 0, stream>>>(P.qkv, P.kl, P.w2, rw, P.xln);
  // h += out @ out_w + out_b   (rows PADF.. of outh map to h rows 0..)
  k_gemm<<<dim3((NTOK + 63) / 64, DIMC / 64), 256, 0, stream>>>(
      P.xln + (size_t)PADF * DIMC, ow, ob, P.h, NTOK, DIMC, DIMC, 2);
}

extern "C" void kernel_launch(void* const* d_in, const int* in_sizes, int n_in,
                              void* d_out, int out_size, void* d_ws, size_t ws_size,
                              hipStream_t stream)
{
  const float* x      = (const float*)d_in[0];
  const float* fc1_w  = (const float*)d_in[1];
  const float* fc1_b  = (const float*)d_in[2];
  const float* cls    = (const float*)d_in[3];
  const float* l1_nw  = (const float*)d_in[4];
  const float* l1_nb  = (const float*)d_in[5];
  const float* l1_qkv = (const float*)d_in[6];
  const float* l1_ow  = (const float*)d_in[7];
  const float* l1_ob  = (const float*)d_in[8];
  const float* l1_rw  = (const float*)d_in[9];
  const float* p7w    = (const float*)d_in[10];
  const float* p7b    = (const float*)d_in[11];
  const float* p5w    = (const float*)d_in[12];
  const float* p5b    = (const float*)d_in[13];
  const float* p3w    = (const float*)d_in[14];
  const float* p3b    = (const float*)d_in[15];
  const float* l2_nw  = (const float*)d_in[16];
  const float* l2_nb  = (const float*)d_in[17];
  const float* l2_qkv = (const float*)d_in[18];
  const float* l2_ow  = (const float*)d_in[19];
  const float* l2_ob  = (const float*)d_in[20];
  const float* l2_rw  = (const float*)d_in[21];
  const float* nw     = (const float*)d_in[22];
  const float* nb     = (const float*)d_in[23];
  const float* fc2w   = (const float*)d_in[24];
  const float* fc2b   = (const float*)d_in[25];
  float* out = (float*)d_out;

  // ---- workspace carve-up (floats); total ~115.2M floats ~ 440 MB ----
  float* W = (float*)d_ws;
  WsPtrs P;
  P.h    = W;                                   // 20,480,512
  P.xln  = P.h    + 20480512ull;                // 20,578,304 (also attn output buffer)
  P.qkv  = P.xln  + 20578304ull;                // 61,734,912 (also ppeg grids)
  P.ql   = P.qkv  + 61734912ull;                // 131,072
  P.kl   = P.ql   + 131072;                     // 131,072
  P.a2   = P.kl   + 131072;                     // 524,288
  P.zA   = P.a2   + 524288;
  P.zB   = P.zA   + 524288;
  P.xz   = P.zB   + 524288;
  P.u    = P.xz   + 524288;
  P.u2   = P.u    + 524288;
  P.av   = P.u2   + 524288;                     // 131,072
  P.w2   = P.av   + 131072;                     // 131,072
  P.hmax = P.w2   + 131072;                     // 16
  P.scal = P.hmax + 16;                         // 16
  P.pm   = P.scal + 16;                         // 131,072
  P.ps   = P.pm   + 131072;                     // 131,072
  P.pacc = P.ps   + 131072;                     // 8,388,608

  // fc1 + relu -> h rows 1..40000 ; cls token -> h row 0
  k_gemm<<<dim3(NPATCH / 64, DIMC / 64), 256, 0, stream>>>(
      x, fc1_w, fc1_b, P.h + DIMC, NPATCH, INDIM, DIMC, 1);
  k_set_cls<<<1, 512, 0, stream>>>(cls, P.h);

  // layer 1 attention
  attention_layer(P, l1_nw, l1_nb, l1_qkv, l1_ow, l1_ob, l1_rw, stream);

  // PPEG: transpose to channel-major, fused 7/5/3 depthwise conv, transpose back
  float* fgrid = P.qkv;
  float* cout  = P.qkv + 20480000ull;
  k_transpose_fw<<<dim3(NPATCH / 32, DIMC / 32), 256, 0, stream>>>(P.h, fgrid);
  k_ppeg<<<dim3(13 * 13, DIMC), 256, 0, stream>>>(fgrid, p7w, p7b, p5w, p5b, p3w, p3b, cout);
  k_transpose_bw<<<dim3(NPATCH / 32, DIMC / 32), 256, 0, stream>>>(cout, P.h);

  // layer 2 attention
  attention_layer(P, l2_nw, l2_nb, l2_qkv, l2_ow, l2_ob, l2_rw, stream);

  // final layernorm (cls row only) + fc2
  k_final<<<1, 512, 0, stream>>>(P.h, nw, nb, fc2w, fc2b, out);
}

// Round 2
// 8384.305 us; speedup vs baseline: 1.3105x; 1.3105x over previous
//
#include <hip/hip_runtime.h>
#include <hip/hip_bf16.h>

// ---------------- problem constants ----------------
#define DIMC   512
#define HEADS  8
#define DH     64
#define MLM    256          // landmarks
#define NPATCH 40000
#define NTOK   40001        // with cls
#define PADF   191          // front zero pad
#define NSEQ   40192        // NTOK + PADF
#define LWIN   157          // NSEQ / MLM
#define INDIM  1024
#define GRID   200
#define CHUNKS 32
#define PER    1256         // NSEQ / CHUNKS

typedef _Float16 h8 __attribute__((ext_vector_type(8)));
typedef _Float16 h4 __attribute__((ext_vector_type(4)));
typedef float    f4 __attribute__((ext_vector_type(4)));

// ---------------- reductions ----------------
template<int NW, bool ISMAX>
__device__ __forceinline__ float blkRed(float v, float* s) {
  #pragma unroll
  for (int o = 32; o; o >>= 1) {
    float t = __shfl_down(v, o, 64);
    v = ISMAX ? fmaxf(v, t) : v + t;
  }
  int lane = threadIdx.x & 63, w = threadIdx.x >> 6;
  __syncthreads();
  if (lane == 0) s[w] = v;
  __syncthreads();
  float r = s[0];
  #pragma unroll
  for (int i = 1; i < NW; i++) r = ISMAX ? fmaxf(r, s[i]) : r + s[i];
  return r;
}

// ---------------- misc small kernels ----------------
__global__ __launch_bounds__(512)
void k_set_cls(const float* __restrict__ cls, float* __restrict__ h) {
  h[threadIdx.x] = cls[threadIdx.x];
}

// fp32 -> fp16, 4 elems per thread, n must be multiple of 4*blockDim*grid fit
__global__ __launch_bounds__(256)
void k_f32_to_f16(const float* __restrict__ in, _Float16* __restrict__ out) {
  int i = blockIdx.x * 256 + threadIdx.x;
  float4 v = ((const float4*)in)[i];
  h4 o = {(_Float16)v.x, (_Float16)v.y, (_Float16)v.z, (_Float16)v.w};
  *(h4*)(out + (size_t)i * 4) = o;
}

// weight K x N fp32 -> transposed N x K fp16
__global__ __launch_bounds__(256)
void k_wt16(const float* __restrict__ B, _Float16* __restrict__ Bt, int K, int N)
{
  __shared__ float tile[32][33];
  int kb = blockIdx.x * 32, nb = blockIdx.y * 32;
  int x = threadIdx.x & 31, y0 = threadIdx.x >> 5;
  #pragma unroll
  for (int yy = y0; yy < 32; yy += 8)
    tile[yy][x] = B[(size_t)(kb + yy) * N + nb + x];
  __syncthreads();
  #pragma unroll
  for (int yy = y0; yy < 32; yy += 8)
    Bt[(size_t)(nb + yy) * K + kb + x] = (_Float16)tile[x][yy];
}

// ---------------- fp16 MFMA GEMM: C = [relu]( A(MrxK) @ Bt(NxK)^T + bias [+ C] ) ----------------
// A: Mr x K fp16 row-major (rows clamped for OOB tiles); Bt: N x K fp16; C: fp32.
// flags: 1 = relu, 2 = accumulate into C. M tiles of 128, N multiple of 128, K multiple of 32.
__global__ __launch_bounds__(256)
void k_gemm16(const _Float16* __restrict__ A, const _Float16* __restrict__ Bt,
              const float* __restrict__ bias, float* __restrict__ C,
              int Mr, int K, int N, int flags)
{
  __shared__ __attribute__((aligned(16))) _Float16 As[128 * 32];
  __shared__ __attribute__((aligned(16))) _Float16 Bs[128 * 32];
  int bm = blockIdx.x * 128, bn = blockIdx.y * 128;
  int t = threadIdx.x;
  int lane = t & 63, w = t >> 6;
  int wm = (w >> 1) * 64, wn = (w & 1) * 64;
  int r = lane & 15, q = lane >> 4;

  const f4 zero = {0.f, 0.f, 0.f, 0.f};
  f4 acc[4][4];
  #pragma unroll
  for (int mi = 0; mi < 4; mi++)
    #pragma unroll
    for (int nj = 0; nj < 4; nj++) acc[mi][nj] = zero;

  for (int k0 = 0; k0 < K; k0 += 32) {
    // stage 128x32 A tile and 128x32 B tile (each 512 16B-chunks, 2 per thread)
    #pragma unroll
    for (int cc = 0; cc < 2; cc++) {
      int c = t + cc * 256;
      int m = c >> 2, kq = (c & 3) * 8;
      int gm = bm + m; if (gm > Mr - 1) gm = Mr - 1;
      ((uint4*)As)[c] = *(const uint4*)(A + (size_t)gm * K + k0 + kq);
      ((uint4*)Bs)[c] = *(const uint4*)(Bt + (size_t)(bn + m) * K + k0 + kq);
    }
    __syncthreads();
    h8 af[4], bf[4];
    #pragma unroll
    for (int i = 0; i < 4; i++) {
      af[i] = *(const h8*)(As + (wm + i * 16 + r) * 32 + q * 8);
      bf[i] = *(const h8*)(Bs + (wn + i * 16 + r) * 32 + q * 8);
    }
    #pragma unroll
    for (int mi = 0; mi < 4; mi++)
      #pragma unroll
      for (int nj = 0; nj < 4; nj++)
        acc[mi][nj] = __builtin_amdgcn_mfma_f32_16x16x32_f16(af[mi], bf[nj], acc[mi][nj], 0, 0, 0);
    __syncthreads();
  }
  // epilogue: acc[mi][nj][i] -> C[bm+wm+mi*16+q*4+i][bn+wn+nj*16+r]
  #pragma unroll
  for (int mi = 0; mi < 4; mi++) {
    #pragma unroll
    for (int i = 0; i < 4; i++) {
      int gm = bm + wm + mi * 16 + q * 4 + i;
      if (gm >= Mr) continue;
      #pragma unroll
      for (int nj = 0; nj < 4; nj++) {
        int gn = bn + wn + nj * 16 + r;
        float v = acc[mi][nj][i];
        if (bias) v += bias[gn];
        if (flags & 2) v += C[(size_t)gm * N + gn];
        if (flags & 1) v = fmaxf(v, 0.f);
        C[(size_t)gm * N + gn] = v;
      }
    }
  }
}

// ---------------- layernorm + front zero pad (fp16 out) ----------------
__global__ __launch_bounds__(256)
void k_ln_pad(const float* __restrict__ h, const float* __restrict__ w,
              const float* __restrict__ b, _Float16* __restrict__ xln)
{
  __shared__ float sbuf[8];
  int t = blockIdx.x;
  int tid = threadIdx.x;
  _Float16* out = xln + (size_t)t * DIMC;
  if (t < PADF) { out[tid] = (_Float16)0.f; out[tid + 256] = (_Float16)0.f; return; }
  const float* row = h + (size_t)(t - PADF) * DIMC;
  float x0 = row[tid], x1 = row[tid + 256];
  float mu = blkRed<4,false>(x0 + x1, sbuf) * (1.f / 512.f);
  float d0 = x0 - mu, d1 = x1 - mu;
  float var = blkRed<4,false>(d0 * d0 + d1 * d1, sbuf) * (1.f / 512.f);
  float rstd = rsqrtf(var + 1e-5f);
  out[tid]       = (_Float16)(d0 * rstd * w[tid]       + b[tid]);
  out[tid + 256] = (_Float16)(d1 * rstd * w[tid + 256] + b[tid + 256]);
}

// ---------------- landmarks (q scaled by DH^-0.5 folded here) ----------------
__global__ __launch_bounds__(64)
void k_landmarks(const float* __restrict__ qkv, float* __restrict__ ql, float* __restrict__ kl)
{
  int h = blockIdx.x >> 8;
  int i = blockIdx.x & 255;
  int d = threadIdx.x;
  const float* base = qkv + (size_t)(i * LWIN) * (3 * DIMC) + h * DH + d;
  float sq = 0.f, sk = 0.f;
  for (int j = 0; j < LWIN; j++) {
    sq += base[0];
    sk += base[DIMC];
    base += 3 * DIMC;
  }
  ql[(h * MLM + i) * DH + d] = sq * (0.125f / (float)LWIN);
  kl[(h * MLM + i) * DH + d] = sk * (1.f   / (float)LWIN);
}

// ---------------- attn2 = softmax(q_l @ k_l^T) ----------------
__global__ __launch_bounds__(256)
void k_attn2(const float* __restrict__ ql, const float* __restrict__ kl, float* __restrict__ a2)
{
  __shared__ float qrow[DH];
  __shared__ float sbuf[8];
  int h = blockIdx.x >> 8, i = blockIdx.x & 255;
  int j = threadIdx.x;
  if (j < DH) qrow[j] = ql[(h * MLM + i) * DH + j];
  __syncthreads();
  const float* krow = kl + (size_t)(h * MLM + j) * DH;
  float s = 0.f;
  #pragma unroll 16
  for (int d = 0; d < DH; d++) s += qrow[d] * krow[d];
  float mx = blkRed<4,true>(s, sbuf);
  float e = __expf(s - mx);
  float sum = blkRed<4,false>(e, sbuf);
  a2[((size_t)h * MLM + i) * MLM + j] = e / sum;
}

// ---------------- pinv init ----------------
__global__ __launch_bounds__(256)
void k_pinv_init1(const float* __restrict__ a2, float* __restrict__ hmax)
{
  __shared__ float sbuf[8];
  int h = blockIdx.x;
  int j = threadIdx.x;
  const float* A = a2 + (size_t)h * MLM * MLM;
  float cs = 0.f, rs = 0.f;
  for (int i = 0; i < MLM; i++) cs += A[i * MLM + j];
  for (int k = 0; k < MLM; k++) rs += A[j * MLM + k];
  float rmax = blkRed<4,true>(rs, sbuf);
  float cmax = blkRed<4,true>(cs, sbuf);
  if (j == 0) { hmax[h * 2] = rmax; hmax[h * 2 + 1] = cmax; }
}

__global__ void k_pinv_init2(const float* __restrict__ hmax, float* __restrict__ scal)
{
  float rm = 0.f, cm = 0.f;
  for (int h = 0; h < HEADS; h++) { rm = fmaxf(rm, hmax[2*h]); cm = fmaxf(cm, hmax[2*h+1]); }
  scal[0] = 1.f / (rm * cm);
}

__global__ __launch_bounds__(256)
void k_transpose_scale(const float* __restrict__ a2, const float* __restrict__ scal, float* __restrict__ z)
{
  int h = blockIdx.x >> 8, j = blockIdx.x & 255;
  int i = threadIdx.x;
  z[((size_t)h * MLM + j) * MLM + i] = a2[((size_t)h * MLM + i) * MLM + j] * scal[0];
}

// ---------------- batched 256xN matmul: C[h] = c0*(A[h]@B[h]) + c1*E[h] ----------------
__global__ __launch_bounds__(256)
void k_bmm(const float* __restrict__ A, const float* __restrict__ Bm,
           const float* __restrict__ E, float* __restrict__ C,
           int N, float c0, float c1)
{
  __shared__ float As[64][17];
  __shared__ float Bs[16][64];
  int ntiles = N >> 6;
  int h = blockIdx.y;
  int bm = (blockIdx.x / ntiles) << 6;
  int bn = (blockIdx.x % ntiles) << 6;
  const float* Ah = A + (size_t)h * (MLM * MLM);
  const float* Bh = Bm + (size_t)h * (MLM * N);
  int tid = threadIdx.x;
  int tx = tid & 15, ty = tid >> 4;
  float acc[4][4] = {};
  for (int k0 = 0; k0 < MLM; k0 += 16) {
    #pragma unroll
    for (int e = tid; e < 64 * 16; e += 256) {
      int m = e >> 4, k = e & 15;
      As[m][k] = Ah[(size_t)(bm + m) * MLM + k0 + k];
    }
    #pragma unroll
    for (int e = tid; e < 16 * 64; e += 256) {
      int k = e >> 6, n = e & 63;
      Bs[k][n] = Bh[(size_t)(k0 + k) * N + bn + n];
    }
    __syncthreads();
    #pragma unroll
    for (int k = 0; k < 16; k++) {
      float a[4], b[4];
      #pragma unroll
      for (int i = 0; i < 4; i++) a[i] = As[ty * 4 + i][k];
      #pragma unroll
      for (int j = 0; j < 4; j++) b[j] = Bs[k][tx * 4 + j];
      #pragma unroll
      for (int i = 0; i < 4; i++)
        #pragma unroll
        for (int j = 0; j < 4; j++) acc[i][j] += a[i] * b[j];
    }
    __syncthreads();
  }
  #pragma unroll
  for (int i = 0; i < 4; i++) {
    int gm = bm + ty * 4 + i;
    #pragma unroll
    for (int j = 0; j < 4; j++) {
      int gn = bn + tx * 4 + j;
      size_t idx = (size_t)h * (MLM * N) + (size_t)gm * N + gn;
      float v = c0 * acc[i][j];
      if (E) v += c1 * E[idx];
      C[idx] = v;
    }
  }
}

// ---------------- attn3 @ v, flash-style split over token chunks ----------------
__global__ __launch_bounds__(256)
void k_attn3_partial(const float* __restrict__ qkv, const float* __restrict__ ql,
                     float* __restrict__ pm, float* __restrict__ ps, float* __restrict__ pacc)
{
  int c = blockIdx.x, h = blockIdx.y;
  int i = threadIdx.x;           // landmark row
  int t0 = c * PER;
  float q[DH];
  {
    const float4* qr = (const float4*)(ql + ((size_t)h * MLM + i) * DH);
    #pragma unroll
    for (int dd = 0; dd < 16; dd++) {
      float4 v = qr[dd];
      q[4*dd] = v.x; q[4*dd+1] = v.y; q[4*dd+2] = v.z; q[4*dd+3] = v.w;
    }
  }
  __shared__ float ks[16][DH];
  __shared__ float vs[16][DH];
  // pass 1: row max
  float m = -1e30f;
  for (int tb = 0; tb < PER; tb += 16) {
    int nt = min(16, PER - tb);
    __syncthreads();
    for (int e = threadIdx.x; e < nt * 16; e += 256) {
      int tt = e >> 4, d4 = e & 15;
      ((float4*)&ks[0][0])[e] =
        *(const float4*)(qkv + (size_t)(t0 + tb + tt) * (3*DIMC) + DIMC + h * DH + d4 * 4);
    }
    __syncthreads();
    for (int tt = 0; tt < nt; tt++) {
      const float4* kr = (const float4*)&ks[tt][0];
      float s = 0.f;
      #pragma unroll
      for (int dd = 0; dd < 16; dd++) {
        float4 kv = kr[dd];
        s += q[4*dd]*kv.x + q[4*dd+1]*kv.y + q[4*dd+2]*kv.z + q[4*dd+3]*kv.w;
      }
      m = fmaxf(m, s);
    }
  }
  // pass 2: exp-sum + weighted v accumulation
  float l = 0.f;
  float acc[DH] = {};
  for (int tb = 0; tb < PER; tb += 16) {
    int nt = min(16, PER - tb);
    __syncthreads();
    for (int e = threadIdx.x; e < nt * 16; e += 256) {
      int tt = e >> 4, d4 = e & 15;
      const float* base = qkv + (size_t)(t0 + tb + tt) * (3*DIMC) + h * DH + d4 * 4;
      ((float4*)&ks[0][0])[e] = *(const float4*)(base + DIMC);
      ((float4*)&vs[0][0])[e] = *(const float4*)(base + 2*DIMC);
    }
    __syncthreads();
    for (int tt = 0; tt < nt; tt++) {
      const float4* kr = (const float4*)&ks[tt][0];
      float s = 0.f;
      #pragma unroll
      for (int dd = 0; dd < 16; dd++) {
        float4 kv = kr[dd];
        s += q[4*dd]*kv.x + q[4*dd+1]*kv.y + q[4*dd+2]*kv.z + q[4*dd+3]*kv.w;
      }
      float p = __expf(s - m);
      l += p;
      const float4* vr = (const float4*)&vs[tt][0];
      #pragma unroll
      for (int dd = 0; dd < 16; dd++) {
        float4 vv = vr[dd];
        acc[4*dd]   += p * vv.x; acc[4*dd+1] += p * vv.y;
        acc[4*dd+2] += p * vv.z; acc[4*dd+3] += p * vv.w;
      }
    }
  }
  int idx = (h * CHUNKS + c) * MLM + i;
  pm[idx] = m;
  ps[idx] = l;
  float4* pa = (float4*)(pacc + (size_t)idx * DH);
  #pragma unroll
  for (int dd = 0; dd < 16; dd++)
    pa[dd] = make_float4(acc[4*dd], acc[4*dd+1], acc[4*dd+2], acc[4*dd+3]);
}

__global__ __launch_bounds__(64)
void k_attn3_reduce(const float* __restrict__ pm, const float* __restrict__ ps,
                    const float* __restrict__ pacc, float* __restrict__ av)
{
  int h = blockIdx.x >> 8, i = blockIdx.x & 255;
  int d = threadIdx.x;
  float m = -1e30f;
  for (int c = 0; c < CHUNKS; c++) m = fmaxf(m, pm[(h * CHUNKS + c) * MLM + i]);
  float l = 0.f, a = 0.f;
  for (int c = 0; c < CHUNKS; c++) {
    int idx = (h * CHUNKS + c) * MLM + i;
    float w = __expf(pm[idx] - m);
    l += ps[idx] * w;
    a += pacc[(size_t)idx * DH + d] * w;
  }
  av[((size_t)h * MLM + i) * DH + d] = a / l;
}

// ---------------- attn1 @ w2 + depthwise conv residual on v (fp16 out) ----------------
__global__ __launch_bounds__(256)
void k_attn1(const float* __restrict__ qkv, const float* __restrict__ kl,
             const float* __restrict__ w2, const float* __restrict__ rw,
             _Float16* __restrict__ outh)
{
  int h = blockIdx.y;
  int t = PADF + blockIdx.x * 256 + threadIdx.x;
  bool act = (t < NSEQ);
  int tc = act ? t : (NSEQ - 1);
  float q[DH];
  {
    const float4* qr = (const float4*)(qkv + (size_t)tc * (3*DIMC) + h * DH);
    #pragma unroll
    for (int dd = 0; dd < 16; dd++) {
      float4 v = qr[dd];
      q[4*dd] = v.x*0.125f; q[4*dd+1] = v.y*0.125f; q[4*dd+2] = v.z*0.125f; q[4*dd+3] = v.w*0.125f;
    }
  }
  __shared__ float klt[64][DH];
  __shared__ float w2t[64][DH];
  // pass 1: max over 256 landmark scores
  float mx = -1e30f;
  for (int j0 = 0; j0 < MLM; j0 += 64) {
    __syncthreads();
    {
      const float4* src = (const float4*)(kl + ((size_t)h * MLM + j0) * DH);
      float4* dst = (float4*)&klt[0][0];
      #pragma unroll
      for (int e = threadIdx.x; e < 1024; e += 256) dst[e] = src[e];
    }
    __syncthreads();
    for (int j = 0; j < 64; j++) {
      const float4* kr = (const float4*)&klt[j][0];
      float s = 0.f;
      #pragma unroll
      for (int dd = 0; dd < 16; dd++) {
        float4 kv = kr[dd];
        s += q[4*dd]*kv.x + q[4*dd+1]*kv.y + q[4*dd+2]*kv.z + q[4*dd+3]*kv.w;
      }
      mx = fmaxf(mx, s);
    }
  }
  // pass 2: softmax-weighted sum of w2 rows
  float l = 0.f;
  float acc[DH] = {};
  for (int j0 = 0; j0 < MLM; j0 += 64) {
    __syncthreads();
    {
      const float4* src1 = (const float4*)(kl + ((size_t)h * MLM + j0) * DH);
      const float4* src2 = (const float4*)(w2 + ((size_t)h * MLM + j0) * DH);
      float4* dst1 = (float4*)&klt[0][0];
      float4* dst2 = (float4*)&w2t[0][0];
      #pragma unroll
      for (int e = threadIdx.x; e < 1024; e += 256) { dst1[e] = src1[e]; dst2[e] = src2[e]; }
    }
    __syncthreads();
    for (int j = 0; j < 64; j++) {
      const float4* kr = (const float4*)&klt[j][0];
      float s = 0.f;
      #pragma unroll
      for (int dd = 0; dd < 16; dd++) {
        float4 kv = kr[dd];
        s += q[4*dd]*kv.x + q[4*dd+1]*kv.y + q[4*dd+2]*kv.z + q[4*dd+3]*kv.w;
      }
      float p = __expf(s - mx);
      l += p;
      const float4* wr = (const float4*)&w2t[j][0];
      #pragma unroll
      for (int dd = 0; dd < 16; dd++) {
        float4 wv = wr[dd];
        acc[4*dd]   += p * wv.x; acc[4*dd+1] += p * wv.y;
        acc[4*dd+2] += p * wv.z; acc[4*dd+3] += p * wv.w;
      }
    }
  }
  if (act) {
    float inv = 1.f / l;
    #pragma unroll
    for (int d = 0; d < DH; d++) acc[d] *= inv;
    for (int kk = 0; kk < 33; kk++) {
      int ts = t - 16 + kk;
      if (ts < 0 || ts >= NSEQ) continue;
      float cf = rw[h * 33 + kk];
      const float4* vr = (const float4*)(qkv + (size_t)ts * (3*DIMC) + 2*DIMC + h * DH);
      #pragma unroll
      for (int dd = 0; dd < 16; dd++) {
        float4 vv = vr[dd];
        acc[4*dd]   += cf * vv.x; acc[4*dd+1] += cf * vv.y;
        acc[4*dd+2] += cf * vv.z; acc[4*dd+3] += cf * vv.w;
      }
    }
    _Float16* dst = outh + (size_t)t * DIMC + h * DH;
    #pragma unroll
    for (int dd = 0; dd < 16; dd++) {
      h4 hv = {(_Float16)acc[4*dd], (_Float16)acc[4*dd+1], (_Float16)acc[4*dd+2], (_Float16)acc[4*dd+3]};
      *(h4*)(dst + dd * 4) = hv;
    }
  }
}

// ---------------- PPEG ----------------
__global__ __launch_bounds__(256)
void k_transpose_fw(const float* __restrict__ h, float* __restrict__ g)
{
  __shared__ float tile[32][33];
  int pb = blockIdx.x * 32, cb = blockIdx.y * 32;
  int x = threadIdx.x & 31, y0 = threadIdx.x >> 5;
  #pragma unroll
  for (int yy = y0; yy < 32; yy += 8)
    tile[yy][x] = h[(size_t)(1 + pb + yy) * DIMC + cb + x];
  __syncthreads();
  #pragma unroll
  for (int yy = y0; yy < 32; yy += 8)
    g[(size_t)(cb + yy) * NPATCH + pb + x] = tile[x][yy];
}

__global__ __launch_bounds__(256)
void k_ppeg(const float* __restrict__ g,
            const float* __restrict__ w7, const float* __restrict__ b7,
            const float* __restrict__ w5, const float* __restrict__ b5,
            const float* __restrict__ w3, const float* __restrict__ b3,
            float* __restrict__ o)
{
  __shared__ float tl[22][22];
  int c = blockIdx.y;
  int ty0 = (blockIdx.x / 13) * 16, tx0 = (blockIdx.x % 13) * 16;
  const float* gc = g + (size_t)c * NPATCH;
  for (int e = threadIdx.x; e < 22 * 22; e += 256) {
    int yy = e / 22, xx = e % 22;
    int y = ty0 - 3 + yy, x = tx0 - 3 + xx;
    tl[yy][xx] = (y >= 0 && y < GRID && x >= 0 && x < GRID) ? gc[y * GRID + x] : 0.f;
  }
  __syncthreads();
  int ly = threadIdx.x >> 4, lx = threadIdx.x & 15;
  int y = ty0 + ly, x = tx0 + lx;
  if (y >= GRID || x >= GRID) return;
  float acc = tl[ly + 3][lx + 3] + b7[c] + b5[c] + b3[c];
  #pragma unroll
  for (int ky = 0; ky < 7; ky++)
    #pragma unroll
    for (int kx = 0; kx < 7; kx++)
      acc += w7[c * 49 + ky * 7 + kx] * tl[ly + ky][lx + kx];
  #pragma unroll
  for (int ky = 0; ky < 5; ky++)
    #pragma unroll
    for (int kx = 0; kx < 5; kx++)
      acc += w5[c * 25 + ky * 5 + kx] * tl[ly + 1 + ky][lx + 1 + kx];
  #pragma unroll
  for (int ky = 0; ky < 3; ky++)
    #pragma unroll
    for (int kx = 0; kx < 3; kx++)
      acc += w3[c * 9 + ky * 3 + kx] * tl[ly + 2 + ky][lx + 2 + kx];
  o[(size_t)c * NPATCH + y * GRID + x] = acc;
}

__global__ __launch_bounds__(256)
void k_transpose_bw(const float* __restrict__ g, float* __restrict__ h)
{
  __shared__ float tile[32][33];
  int pb = blockIdx.x * 32, cb = blockIdx.y * 32;
  int x = threadIdx.x & 31, y0 = threadIdx.x >> 5;
  #pragma unroll
  for (int yy = y0; yy < 32; yy += 8)
    tile[yy][x] = g[(size_t)(cb + yy) * NPATCH + pb + x];
  __syncthreads();
  #pragma unroll
  for (int yy = y0; yy < 32; yy += 8)
    h[(size_t)(1 + pb + yy) * DIMC + cb + x] = tile[x][yy];
}

// ---------------- final: layernorm(row 0) @ fc2 ----------------
__global__ __launch_bounds__(512)
void k_final(const float* __restrict__ h, const float* __restrict__ nw, const float* __restrict__ nb,
             const float* __restrict__ fw, const float* __restrict__ fb, float* __restrict__ out)
{
  __shared__ float sbuf[8];
  int d = threadIdx.x;
  float x = h[d];
  float mu = blkRed<8,false>(x, sbuf) * (1.f / 512.f);
  float dd = x - mu;
  float var = blkRed<8,false>(dd * dd, sbuf) * (1.f / 512.f);
  float cls = dd * rsqrtf(var + 1e-5f) * nw[d] + nb[d];
  float l0 = blkRed<8,false>(cls * fw[d * 2 + 0], sbuf);
  float l1 = blkRed<8,false>(cls * fw[d * 2 + 1], sbuf);
  if (d == 0) { out[0] = l0 + fb[0]; out[1] = l1 + fb[1]; }
}

// ---------------- host orchestration ----------------
struct WsPtrs {
  float *h, *qkv, *ql, *kl, *a2, *zA, *zB, *xz, *u, *u2, *av, *w2, *hmax, *scal, *pm, *ps, *pacc;
  _Float16 *xat16, *x16;
};

static void attention_layer(const WsPtrs& P,
                            const float* nw, const float* nb, const _Float16* qkvw16,
                            const _Float16* ow16, const float* ob, const float* rw,
                            hipStream_t stream)
{
  k_ln_pad<<<NSEQ, 256, 0, stream>>>(P.h, nw, nb, P.xat16);
  k_gemm16<<<dim3(NSEQ / 128, 1536 / 128), 256, 0, stream>>>(P.xat16, qkvw16, nullptr, P.qkv, NSEQ, DIMC, 3 * DIMC, 0);
  k_landmarks<<<HEADS * MLM, 64, 0, stream>>>(P.qkv, P.ql, P.kl);
  k_attn2<<<HEADS * MLM, 256, 0, stream>>>(P.ql, P.kl, P.a2);
  k_pinv_init1<<<HEADS, 256, 0, stream>>>(P.a2, P.hmax);
  k_pinv_init2<<<1, 1, 0, stream>>>(P.hmax, P.scal);
  k_transpose_scale<<<HEADS * MLM, 256, 0, stream>>>(P.a2, P.scal, P.zA);
  float* z = P.zA; float* zn = P.zB;
  for (int it = 0; it < 6; it++) {
    k_bmm<<<dim3(16, HEADS), 256, 0, stream>>>(P.a2, z,    nullptr, P.xz, MLM, 1.f,   0.f);
    k_bmm<<<dim3(16, HEADS), 256, 0, stream>>>(P.xz, P.xz, P.xz,    P.u,  MLM, -1.f,  7.f);
    k_bmm<<<dim3(16, HEADS), 256, 0, stream>>>(P.xz, P.u,  P.xz,    P.u2, MLM, -1.f,  15.f);
    k_bmm<<<dim3(16, HEADS), 256, 0, stream>>>(z,    P.u2, z,       zn,   MLM, -0.25f, 3.25f);
    float* t = z; z = zn; zn = t;
  }
  k_attn3_partial<<<dim3(CHUNKS, HEADS), 256, 0, stream>>>(P.qkv, P.ql, P.pm, P.ps, P.pacc);
  k_attn3_reduce<<<HEADS * MLM, 64, 0, stream>>>(P.pm, P.ps, P.pacc, P.av);
  k_bmm<<<dim3(4, HEADS), 256, 0, stream>>>(z, P.av, nullptr, P.w2, DH, 1.f, 0.f);
  k_attn1<<<dim3(157, HEADS), 256, 0, stream>>>(P.qkv, P.kl, P.w2, rw, P.xat16);
  // h += out @ out_w + out_b   (rows PADF.. of attn-out map to h rows 0..)
  k_gemm16<<<dim3((NTOK + 127) / 128, DIMC / 128), 256, 0, stream>>>(
      P.xat16 + (size_t)PADF * DIMC, ow16, ob, P.h, NTOK, DIMC, DIMC, 2);
}

extern "C" void kernel_launch(void* const* d_in, const int* in_sizes, int n_in,
                              void* d_out, int out_size, void* d_ws, size_t ws_size,
                              hipStream_t stream)
{
  const float* x      = (const float*)d_in[0];
  const float* fc1_w  = (const float*)d_in[1];
  const float* fc1_b  = (const float*)d_in[2];
  const float* cls    = (const float*)d_in[3];
  const float* l1_nw  = (const float*)d_in[4];
  const float* l1_nb  = (const float*)d_in[5];
  const float* l1_qkv = (const float*)d_in[6];
  const float* l1_ow  = (const float*)d_in[7];
  const float* l1_ob  = (const float*)d_in[8];
  const float* l1_rw  = (const float*)d_in[9];
  const float* p7w    = (const float*)d_in[10];
  const float* p7b    = (const float*)d_in[11];
  const float* p5w    = (const float*)d_in[12];
  const float* p5b    = (const float*)d_in[13];
  const float* p3w    = (const float*)d_in[14];
  const float* p3b    = (const float*)d_in[15];
  const float* l2_nw  = (const float*)d_in[16];
  const float* l2_nb  = (const float*)d_in[17];
  const float* l2_qkv = (const float*)d_in[18];
  const float* l2_ow  = (const float*)d_in[19];
  const float* l2_ob  = (const float*)d_in[20];
  const float* l2_rw  = (const float*)d_in[21];
  const float* nw     = (const float*)d_in[22];
  const float* nb     = (const float*)d_in[23];
  const float* fc2w   = (const float*)d_in[24];
  const float* fc2b   = (const float*)d_in[25];
  float* out = (float*)d_out;

  // ---- workspace carve-up (float offsets); total ~101.8M floats ~ 407 MB ----
  float* W = (float*)d_ws;
  WsPtrs P;
  size_t off = 0;
  P.h     = W + off;               off += 20480512ull;   // 40001 x 512
  P.xat16 = (_Float16*)(W + off);  off += 10289152ull;   // NSEQ x 512 halves (ln out / attn1 out)
  P.qkv   = W + off;                                      // NSEQ x 1536 fp32
  P.x16   = (_Float16*)P.qkv;                             // alias: x fp16 (only live before fc1 GEMM... used during it)
  off += 61734912ull;
  P.ql    = W + off; off += 131072;
  P.kl    = W + off; off += 131072;
  P.a2    = W + off; off += 524288;
  P.zA    = W + off; off += 524288;
  P.zB    = W + off; off += 524288;
  P.xz    = W + off; off += 524288;
  P.u     = W + off; off += 524288;
  P.u2    = W + off; off += 524288;
  P.av    = W + off; off += 131072;
  P.w2    = W + off; off += 131072;
  P.hmax  = W + off; P.scal = P.hmax + 16; off += 32;
  P.pm    = W + off; off += 65536;
  P.ps    = W + off; off += 65536;
  P.pacc  = W + off; off += 4194304;
  _Float16* fc1t  = (_Float16*)(W + off);   // 512x1024
  _Float16* qkv1t = fc1t  + 524288;         // 1536x512
  _Float16* out1t = qkv1t + 786432;         // 512x512
  _Float16* qkv2t = out1t + 262144;
  _Float16* out2t = qkv2t + 786432;

  // ---- weight fp32 -> fp16 transposed (N x K) ----
  k_wt16<<<dim3(INDIM / 32, DIMC / 32), 256, 0, stream>>>(fc1_w, fc1t, INDIM, DIMC);
  k_wt16<<<dim3(DIMC / 32, 1536 / 32), 256, 0, stream>>>(l1_qkv, qkv1t, DIMC, 1536);
  k_wt16<<<dim3(DIMC / 32, DIMC / 32), 256, 0, stream>>>(l1_ow, out1t, DIMC, DIMC);
  k_wt16<<<dim3(DIMC / 32, 1536 / 32), 256, 0, stream>>>(l2_qkv, qkv2t, DIMC, 1536);
  k_wt16<<<dim3(DIMC / 32, DIMC / 32), 256, 0, stream>>>(l2_ow, out2t, DIMC, DIMC);

  // fc1 + relu -> h rows 1..40000 ; cls token -> h row 0
  k_f32_to_f16<<<NPATCH * INDIM / 1024, 256, 0, stream>>>(x, P.x16);
  k_gemm16<<<dim3((NPATCH + 127) / 128, DIMC / 128), 256, 0, stream>>>(
      P.x16, fc1t, fc1_b, P.h + DIMC, NPATCH, INDIM, DIMC, 1);
  k_set_cls<<<1, 512, 0, stream>>>(cls, P.h);

  // layer 1 attention
  attention_layer(P, l1_nw, l1_nb, qkv1t, out1t, l1_ob, l1_rw, stream);

  // PPEG: transpose to channel-major, fused 7/5/3 depthwise conv, transpose back
  float* fgrid = P.qkv;
  float* cout  = P.qkv + 20480000ull;
  k_transpose_fw<<<dim3(NPATCH / 32, DIMC / 32), 256, 0, stream>>>(P.h, fgrid);
  k_ppeg<<<dim3(13 * 13, DIMC), 256, 0, stream>>>(fgrid, p7w, p7b, p5w, p5b, p3w, p3b, cout);
  k_transpose_bw<<<dim3(NPATCH / 32, DIMC / 32), 256, 0, stream>>>(cout, P.h);

  // layer 2 attention
  attention_layer(P, l2_nw, l2_nb, qkv2t, out2t, l2_ob, l2_rw, stream);

  // final layernorm (cls row only) + fc2
  k_final<<<1, 512, 0, stream>>>(P.h, nw, nb, fc2w, fc2b, out);
}

// Round 3
// 3897.198 us; speedup vs baseline: 2.8194x; 2.1514x over previous
//
#include <hip/hip_runtime.h>
#include <hip/hip_bf16.h>

// ---------------- problem constants ----------------
#define DIMC   512
#define HEADS  8
#define DH     64
#define MLM    256          // landmarks
#define NPATCH 40000
#define NTOK   40001        // with cls
#define PADF   191          // front zero pad
#define NSEQ   40192        // NTOK + PADF
#define NSEQP  40224        // NSEQ + 32 (zero pad for flash tiles)
#define LWIN   157          // NSEQ / MLM
#define INDIM  1024
#define GRID   200
#define CHUNKS 64
#define PER    628          // NSEQ / CHUNKS

typedef _Float16 h8 __attribute__((ext_vector_type(8)));
typedef _Float16 h4 __attribute__((ext_vector_type(4)));
typedef float    f4 __attribute__((ext_vector_type(4)));

// ---------------- reductions ----------------
template<int NW, bool ISMAX>
__device__ __forceinline__ float blkRed(float v, float* s) {
  #pragma unroll
  for (int o = 32; o; o >>= 1) {
    float t = __shfl_down(v, o, 64);
    v = ISMAX ? fmaxf(v, t) : v + t;
  }
  int lane = threadIdx.x & 63, w = threadIdx.x >> 6;
  __syncthreads();
  if (lane == 0) s[w] = v;
  __syncthreads();
  float r = s[0];
  #pragma unroll
  for (int i = 1; i < NW; i++) r = ISMAX ? fmaxf(r, s[i]) : r + s[i];
  return r;
}

// ---------------- misc small kernels ----------------
__global__ __launch_bounds__(512)
void k_set_cls(const float* __restrict__ cls, float* __restrict__ h) {
  h[threadIdx.x] = cls[threadIdx.x];
}

__global__ __launch_bounds__(256)
void k_f32_to_f16(const float* __restrict__ in, _Float16* __restrict__ out) {
  int i = blockIdx.x * 256 + threadIdx.x;
  float4 v = ((const float4*)in)[i];
  h4 o = {(_Float16)v.x, (_Float16)v.y, (_Float16)v.z, (_Float16)v.w};
  *(h4*)(out + (size_t)i * 4) = o;
}

// zero the 32-row pads of q16/k16/v16 (8 heads x 32 rows x 64)
__global__ __launch_bounds__(256)
void k_zpad(_Float16* q16, _Float16* k16, _Float16* v16) {
  int idx = blockIdx.x * 256 + threadIdx.x;       // 16384 total
  int h = idx >> 11, r = (idx >> 6) & 31, d = idx & 63;
  size_t a = ((size_t)h * NSEQP + NSEQ + r) * 64 + d;
  q16[a] = (_Float16)0.f; k16[a] = (_Float16)0.f; v16[a] = (_Float16)0.f;
}

// weight K x N fp32 -> transposed N x K fp16
__global__ __launch_bounds__(256)
void k_wt16(const float* __restrict__ B, _Float16* __restrict__ Bt, int K, int N)
{
  __shared__ float tile[32][33];
  int kb = blockIdx.x * 32, nb = blockIdx.y * 32;
  int x = threadIdx.x & 31, y0 = threadIdx.x >> 5;
  #pragma unroll
  for (int yy = y0; yy < 32; yy += 8)
    tile[yy][x] = B[(size_t)(kb + yy) * N + nb + x];
  __syncthreads();
  #pragma unroll
  for (int yy = y0; yy < 32; yy += 8)
    Bt[(size_t)(nb + yy) * K + kb + x] = (_Float16)tile[x][yy];
}

// ---------------- fp16 MFMA GEMM ----------------
// flags: 1 = relu, 2 = accumulate into C, 4 = qkv scatter store (fp16 head-major)
__global__ __launch_bounds__(256)
void k_gemm16(const _Float16* __restrict__ A, const _Float16* __restrict__ Bt,
              const float* __restrict__ bias, float* __restrict__ C,
              _Float16* __restrict__ q16, _Float16* __restrict__ k16, _Float16* __restrict__ v16,
              int Mr, int K, int N, int flags)
{
  __shared__ __attribute__((aligned(16))) _Float16 As[128 * 32];
  __shared__ __attribute__((aligned(16))) _Float16 Bs[128 * 32];
  int bm = blockIdx.x * 128, bn = blockIdx.y * 128;
  int t = threadIdx.x;
  int lane = t & 63, w = t >> 6;
  int wm = (w >> 1) * 64, wn = (w & 1) * 64;
  int r = lane & 15, q = lane >> 4;

  const f4 zero = {0.f, 0.f, 0.f, 0.f};
  f4 acc[4][4];
  #pragma unroll
  for (int mi = 0; mi < 4; mi++)
    #pragma unroll
    for (int nj = 0; nj < 4; nj++) acc[mi][nj] = zero;

  for (int k0 = 0; k0 < K; k0 += 32) {
    #pragma unroll
    for (int cc = 0; cc < 2; cc++) {
      int c = t + cc * 256;
      int m = c >> 2, kq = (c & 3) * 8;
      int gm = bm + m; if (gm > Mr - 1) gm = Mr - 1;
      ((uint4*)As)[c] = *(const uint4*)(A + (size_t)gm * K + k0 + kq);
      ((uint4*)Bs)[c] = *(const uint4*)(Bt + (size_t)(bn + m) * K + k0 + kq);
    }
    __syncthreads();
    h8 af[4], bf[4];
    #pragma unroll
    for (int i = 0; i < 4; i++) {
      af[i] = *(const h8*)(As + (wm + i * 16 + r) * 32 + q * 8);
      bf[i] = *(const h8*)(Bs + (wn + i * 16 + r) * 32 + q * 8);
    }
    #pragma unroll
    for (int mi = 0; mi < 4; mi++)
      #pragma unroll
      for (int nj = 0; nj < 4; nj++)
        acc[mi][nj] = __builtin_amdgcn_mfma_f32_16x16x32_f16(af[mi], bf[nj], acc[mi][nj], 0, 0, 0);
    __syncthreads();
  }
  #pragma unroll
  for (int mi = 0; mi < 4; mi++) {
    #pragma unroll
    for (int i = 0; i < 4; i++) {
      int gm = bm + wm + mi * 16 + q * 4 + i;
      if (gm >= Mr) continue;
      #pragma unroll
      for (int nj = 0; nj < 4; nj++) {
        int gn = bn + wn + nj * 16 + r;
        float v = acc[mi][nj][i];
        if (flags & 4) {
          int which = gn >> 9, hh = (gn >> 6) & 7, dd = gn & 63;
          _Float16* dst = (which == 0) ? q16 : (which == 1) ? k16 : v16;
          dst[((size_t)hh * NSEQP + gm) * 64 + dd] = (_Float16)v;
        } else {
          if (bias) v += bias[gn];
          if (flags & 2) v += C[(size_t)gm * N + gn];
          if (flags & 1) v = fmaxf(v, 0.f);
          C[(size_t)gm * N + gn] = v;
        }
      }
    }
  }
}

// ---------------- layernorm + front zero pad (fp16 out) ----------------
__global__ __launch_bounds__(256)
void k_ln_pad(const float* __restrict__ h, const float* __restrict__ w,
              const float* __restrict__ b, _Float16* __restrict__ xln)
{
  __shared__ float sbuf[8];
  int t = blockIdx.x;
  int tid = threadIdx.x;
  _Float16* out = xln + (size_t)t * DIMC;
  if (t < PADF) { out[tid] = (_Float16)0.f; out[tid + 256] = (_Float16)0.f; return; }
  const float* row = h + (size_t)(t - PADF) * DIMC;
  float x0 = row[tid], x1 = row[tid + 256];
  float mu = blkRed<4,false>(x0 + x1, sbuf) * (1.f / 512.f);
  float d0 = x0 - mu, d1 = x1 - mu;
  float var = blkRed<4,false>(d0 * d0 + d1 * d1, sbuf) * (1.f / 512.f);
  float rstd = rsqrtf(var + 1e-5f);
  out[tid]       = (_Float16)(d0 * rstd * w[tid]       + b[tid]);
  out[tid + 256] = (_Float16)(d1 * rstd * w[tid + 256] + b[tid + 256]);
}

// ---------------- v16 [h][t][64] -> vt16 [h][64][NSEQP] transpose ----------------
__global__ __launch_bounds__(256)
void k_vt(const _Float16* __restrict__ v16, _Float16* __restrict__ vt16)
{
  __shared__ _Float16 tl[64][72];
  int h = blockIdx.y;
  int t0 = blockIdx.x * 64;
  for (int c = threadIdx.x; c < 512; c += 256) {
    int row = c >> 3, ch = (c & 7) * 8;
    h8 v = {};
    if (t0 + row < NSEQP)
      v = *(const h8*)(v16 + ((size_t)h * NSEQP + t0 + row) * 64 + ch);
    *(h8*)&tl[row][ch] = v;
  }
  __syncthreads();
  int d = threadIdx.x & 63, tg = (threadIdx.x >> 6) * 16;
  if (t0 + tg < NSEQP) {
    _Float16 tmp[16];
    #pragma unroll
    for (int k = 0; k < 16; k++) tmp[k] = tl[tg + k][d];
    *(h8*)(vt16 + ((size_t)h * 64 + d) * NSEQP + t0 + tg)     = *(h8*)tmp;
    *(h8*)(vt16 + ((size_t)h * 64 + d) * NSEQP + t0 + tg + 8) = *(h8*)(tmp + 8);
  }
}

// ---------------- landmarks from fp16 q/k (q scale folded into ql) ----------------
__global__ __launch_bounds__(256)
void k_landmarks(const _Float16* __restrict__ q16, const _Float16* __restrict__ k16,
                 float* __restrict__ ql, float* __restrict__ kl,
                 _Float16* __restrict__ ql16, _Float16* __restrict__ kl16)
{
  __shared__ float red[2][16][64];
  int h = blockIdx.x >> 8, i = blockIdx.x & 255;
  int jg = threadIdx.x >> 4, d4 = (threadIdx.x & 15) * 4;
  const _Float16* qb = q16 + ((size_t)h * NSEQP + i * LWIN) * 64;
  const _Float16* kb = k16 + ((size_t)h * NSEQP + i * LWIN) * 64;
  float sq[4] = {}, sk[4] = {};
  for (int j = jg; j < LWIN; j += 16) {
    h4 qv = *(const h4*)(qb + j * 64 + d4);
    h4 kv = *(const h4*)(kb + j * 64 + d4);
    #pragma unroll
    for (int c = 0; c < 4; c++) { sq[c] += (float)qv[c]; sk[c] += (float)kv[c]; }
  }
  #pragma unroll
  for (int c = 0; c < 4; c++) { red[0][jg][d4 + c] = sq[c]; red[1][jg][d4 + c] = sk[c]; }
  __syncthreads();
  if (threadIdx.x < 64) {
    int d = threadIdx.x;
    float aq = 0.f, ak = 0.f;
    #pragma unroll
    for (int g = 0; g < 16; g++) { aq += red[0][g][d]; ak += red[1][g][d]; }
    aq *= (0.125f / (float)LWIN);
    ak *= (1.f / (float)LWIN);
    size_t o = ((size_t)h * MLM + i) * DH + d;
    ql[o] = aq; kl[o] = ak;
    ql16[o] = (_Float16)aq; kl16[o] = (_Float16)ak;
  }
}

// ---------------- attn2 = softmax(q_l @ k_l^T) ----------------
__global__ __launch_bounds__(256)
void k_attn2(const float* __restrict__ ql, const float* __restrict__ kl, float* __restrict__ a2)
{
  __shared__ float qrow[DH];
  __shared__ float sbuf[8];
  int h = blockIdx.x >> 8, i = blockIdx.x & 255;
  int j = threadIdx.x;
  if (j < DH) qrow[j] = ql[(h * MLM + i) * DH + j];
  __syncthreads();
  const float* krow = kl + (size_t)(h * MLM + j) * DH;
  float s = 0.f;
  #pragma unroll 16
  for (int d = 0; d < DH; d++) s += qrow[d] * krow[d];
  float mx = blkRed<4,true>(s, sbuf);
  float e = __expf(s - mx);
  float sum = blkRed<4,false>(e, sbuf);
  a2[((size_t)h * MLM + i) * MLM + j] = e / sum;
}

// ---------------- pinv init ----------------
__global__ __launch_bounds__(256)
void k_pinv_init1(const float* __restrict__ a2, float* __restrict__ hmax)
{
  __shared__ float sbuf[8];
  int h = blockIdx.x;
  int j = threadIdx.x;
  const float* A = a2 + (size_t)h * MLM * MLM;
  float cs = 0.f, rs = 0.f;
  for (int i = 0; i < MLM; i++) cs += A[i * MLM + j];
  for (int k = 0; k < MLM; k++) rs += A[j * MLM + k];
  float rmax = blkRed<4,true>(rs, sbuf);
  float cmax = blkRed<4,true>(cs, sbuf);
  if (j == 0) { hmax[h * 2] = rmax; hmax[h * 2 + 1] = cmax; }
}

__global__ void k_pinv_init2(const float* __restrict__ hmax, float* __restrict__ scal)
{
  float rm = 0.f, cm = 0.f;
  for (int h = 0; h < HEADS; h++) { rm = fmaxf(rm, hmax[2*h]); cm = fmaxf(cm, hmax[2*h+1]); }
  scal[0] = 1.f / (rm * cm);
}

__global__ __launch_bounds__(256)
void k_transpose_scale(const float* __restrict__ a2, const float* __restrict__ scal, float* __restrict__ z)
{
  int h = blockIdx.x >> 8, j = blockIdx.x & 255;
  int i = threadIdx.x;
  z[((size_t)h * MLM + j) * MLM + i] = a2[((size_t)h * MLM + i) * MLM + j] * scal[0];
}

// ---------------- batched 256xN matmul: C[h] = c0*(A[h]@B[h]) + c1*E[h] ----------------
__global__ __launch_bounds__(256)
void k_bmm(const float* __restrict__ A, const float* __restrict__ Bm,
           const float* __restrict__ E, float* __restrict__ C,
           int N, float c0, float c1)
{
  __shared__ float As[64][17];
  __shared__ float Bs[16][64];
  int ntiles = N >> 6;
  int h = blockIdx.y;
  int bm = (blockIdx.x / ntiles) << 6;
  int bn = (blockIdx.x % ntiles) << 6;
  const float* Ah = A + (size_t)h * (MLM * MLM);
  const float* Bh = Bm + (size_t)h * (MLM * N);
  int tid = threadIdx.x;
  int tx = tid & 15, ty = tid >> 4;
  float acc[4][4] = {};
  for (int k0 = 0; k0 < MLM; k0 += 16) {
    #pragma unroll
    for (int e = tid; e < 64 * 16; e += 256) {
      int m = e >> 4, k = e & 15;
      As[m][k] = Ah[(size_t)(bm + m) * MLM + k0 + k];
    }
    #pragma unroll
    for (int e = tid; e < 16 * 64; e += 256) {
      int k = e >> 6, n = e & 63;
      Bs[k][n] = Bh[(size_t)(k0 + k) * N + bn + n];
    }
    __syncthreads();
    #pragma unroll
    for (int k = 0; k < 16; k++) {
      float a[4], b[4];
      #pragma unroll
      for (int i = 0; i < 4; i++) a[i] = As[ty * 4 + i][k];
      #pragma unroll
      for (int j = 0; j < 4; j++) b[j] = Bs[k][tx * 4 + j];
      #pragma unroll
      for (int i = 0; i < 4; i++)
        #pragma unroll
        for (int j = 0; j < 4; j++) acc[i][j] += a[i] * b[j];
    }
    __syncthreads();
  }
  #pragma unroll
  for (int i = 0; i < 4; i++) {
    int gm = bm + ty * 4 + i;
    #pragma unroll
    for (int j = 0; j < 4; j++) {
      int gn = bn + tx * 4 + j;
      size_t idx = (size_t)h * (MLM * N) + (size_t)gm * N + gn;
      float v = c0 * acc[i][j];
      if (E) v += c1 * E[idx];
      C[idx] = v;
    }
  }
}

// ---------------- w2 fp32 [h][256][64] -> w2t16 fp16 [h][64][256] ----------------
__global__ __launch_bounds__(256)
void k_w2t(const float* __restrict__ w2, _Float16* __restrict__ w2t)
{
  __shared__ _Float16 tl[64 * 264];
  int h = blockIdx.x;
  for (int c = threadIdx.x; c < 256 * 16; c += 256) {
    int m = c >> 4, d4 = (c & 15) * 4;
    f4 v = *(const f4*)(w2 + ((size_t)h * 256 + m) * 64 + d4);
    #pragma unroll
    for (int k = 0; k < 4; k++) tl[(d4 + k) * 264 + m] = (_Float16)v[k];
  }
  __syncthreads();
  for (int c = threadIdx.x; c < 2048; c += 256) {
    int d = c >> 5, ch = (c & 31) * 8;
    *(h8*)(w2t + ((size_t)h * 64 + d) * 256 + ch) = *(h8*)&tl[d * 264 + ch];
  }
}

// ---------------- flash attn3: partials of softmax(ql @ k^T) @ v ----------------
__global__ __launch_bounds__(256)
void k_attn3(const _Float16* __restrict__ ql16, const _Float16* __restrict__ k16,
             const _Float16* __restrict__ vt16,
             float* __restrict__ pm, float* __restrict__ ps, float* __restrict__ pacc)
{
  __shared__ __attribute__((aligned(16))) _Float16 Pl[4][64 * 40];
  int c = blockIdx.x, h = blockIdx.y;
  int tid = threadIdx.x, lane = tid & 63, w = tid >> 6;
  int r = lane & 15, q = lane >> 4;
  int t0 = c * PER;
  int m0 = w * 64;
  const _Float16* qlh = ql16 + (size_t)h * MLM * 64;
  const _Float16* kh  = k16  + (size_t)h * NSEQP * 64;
  const _Float16* vh  = vt16 + (size_t)h * 64 * NSEQP;
  _Float16* Pw = &Pl[w][0];

  h8 af[4][2];
  #pragma unroll
  for (int mt = 0; mt < 4; mt++)
    #pragma unroll
    for (int ks = 0; ks < 2; ks++)
      af[mt][ks] = *(const h8*)(qlh + (size_t)(m0 + mt * 16 + r) * 64 + ks * 32 + q * 8);

  const f4 zero = {0.f, 0.f, 0.f, 0.f};
  f4 acc[4][4];
  float mrun[4][4], lrun[4][4];
  #pragma unroll
  for (int mt = 0; mt < 4; mt++) {
    #pragma unroll
    for (int nd = 0; nd < 4; nd++) acc[mt][nd] = zero;
    #pragma unroll
    for (int i = 0; i < 4; i++) { mrun[mt][i] = -1e30f; lrun[mt][i] = 0.f; }
  }

  for (int tb = 0; tb < 20; tb++) {
    int tt = t0 + tb * 32;
    f4 S[4][2];
    #pragma unroll
    for (int mt = 0; mt < 4; mt++) { S[mt][0] = zero; S[mt][1] = zero; }
    #pragma unroll
    for (int nt = 0; nt < 2; nt++) {
      h8 b0 = *(const h8*)(kh + (size_t)(tt + nt * 16 + r) * 64 + q * 8);
      h8 b1 = *(const h8*)(kh + (size_t)(tt + nt * 16 + r) * 64 + 32 + q * 8);
      #pragma unroll
      for (int mt = 0; mt < 4; mt++) {
        S[mt][nt] = __builtin_amdgcn_mfma_f32_16x16x32_f16(af[mt][0], b0, S[mt][nt], 0, 0, 0);
        S[mt][nt] = __builtin_amdgcn_mfma_f32_16x16x32_f16(af[mt][1], b1, S[mt][nt], 0, 0, 0);
      }
    }
    if (tb == 19) {
      #pragma unroll
      for (int nt = 0; nt < 2; nt++) {
        bool valid = (tb * 32 + nt * 16 + r) < PER;
        #pragma unroll
        for (int mt = 0; mt < 4; mt++)
          #pragma unroll
          for (int i = 0; i < 4; i++)
            S[mt][nt][i] = valid ? S[mt][nt][i] : -1e30f;
      }
    }
    #pragma unroll
    for (int mt = 0; mt < 4; mt++) {
      float nm[4], al[4], ls[4];
      #pragma unroll
      for (int i = 0; i < 4; i++) {
        nm[i] = fmaxf(S[mt][0][i], S[mt][1][i]);
        #pragma unroll
        for (int o = 1; o < 16; o <<= 1) nm[i] = fmaxf(nm[i], __shfl_xor(nm[i], o, 64));
        nm[i] = fmaxf(nm[i], mrun[mt][i]);
        al[i] = __expf(mrun[mt][i] - nm[i]);
        mrun[mt][i] = nm[i];
        float p0 = __expf(S[mt][0][i] - nm[i]);
        float p1 = __expf(S[mt][1][i] - nm[i]);
        S[mt][0][i] = p0; S[mt][1][i] = p1;
        ls[i] = p0 + p1;
        #pragma unroll
        for (int o = 1; o < 16; o <<= 1) ls[i] += __shfl_xor(ls[i], o, 64);
        lrun[mt][i] = lrun[mt][i] * al[i] + ls[i];
      }
      #pragma unroll
      for (int nd = 0; nd < 4; nd++)
        #pragma unroll
        for (int i = 0; i < 4; i++) acc[mt][nd][i] *= al[i];
      #pragma unroll
      for (int nt = 0; nt < 2; nt++)
        #pragma unroll
        for (int i = 0; i < 4; i++)
          Pw[(mt * 16 + q * 4 + i) * 40 + nt * 16 + r] = (_Float16)S[mt][nt][i];
    }
    __syncthreads();
    h8 bv[4];
    #pragma unroll
    for (int nd = 0; nd < 4; nd++)
      bv[nd] = *(const h8*)(vh + (size_t)(nd * 16 + r) * NSEQP + tt + q * 8);
    #pragma unroll
    for (int mt = 0; mt < 4; mt++) {
      h8 ap = *(const h8*)(Pw + (mt * 16 + r) * 40 + q * 8);
      #pragma unroll
      for (int nd = 0; nd < 4; nd++)
        acc[mt][nd] = __builtin_amdgcn_mfma_f32_16x16x32_f16(ap, bv[nd], acc[mt][nd], 0, 0, 0);
    }
    __syncthreads();
  }
  int cidx = h * CHUNKS + c;
  #pragma unroll
  for (int mt = 0; mt < 4; mt++) {
    int rowb = m0 + mt * 16 + q * 4;
    if (r == 0) {
      #pragma unroll
      for (int i = 0; i < 4; i++) {
        pm[(size_t)cidx * MLM + rowb + i] = mrun[mt][i];
        ps[(size_t)cidx * MLM + rowb + i] = lrun[mt][i];
      }
    }
    #pragma unroll
    for (int nd = 0; nd < 4; nd++)
      #pragma unroll
      for (int i = 0; i < 4; i++)
        pacc[((size_t)cidx * MLM + rowb + i) * 64 + nd * 16 + r] = acc[mt][nd][i];
  }
}

__global__ __launch_bounds__(64)
void k_attn3_reduce(const float* __restrict__ pm, const float* __restrict__ ps,
                    const float* __restrict__ pacc, float* __restrict__ av)
{
  int h = blockIdx.x >> 8, i = blockIdx.x & 255;
  int d = threadIdx.x;
  float m = -1e30f;
  for (int c = 0; c < CHUNKS; c++) m = fmaxf(m, pm[(h * CHUNKS + c) * MLM + i]);
  float l = 0.f, a = 0.f;
  for (int c = 0; c < CHUNKS; c++) {
    int idx = (h * CHUNKS + c) * MLM + i;
    float w = __expf(pm[idx] - m);
    l += ps[idx] * w;
    a += pacc[(size_t)idx * DH + d] * w;
  }
  av[((size_t)h * MLM + i) * DH + d] = a / l;
}

// ---------------- depthwise 33-tap conv on v -> xat16 ----------------
__global__ __launch_bounds__(256)
void k_conv(const _Float16* __restrict__ v16, const float* __restrict__ rw,
            _Float16* __restrict__ xat)
{
  __shared__ float tl[160][64];
  int h = blockIdx.y;
  int t0 = PADF + blockIdx.x * 128;
  for (int c = threadIdx.x; c < 160 * 16; c += 256) {
    int row = c >> 4, d4 = (c & 15) * 4;
    int ts = t0 - 16 + row;
    f4 val = {0.f, 0.f, 0.f, 0.f};
    if (ts >= 0 && ts < NSEQ) {
      h4 hv = *(const h4*)(v16 + ((size_t)h * NSEQP + ts) * 64 + d4);
      val[0] = (float)hv[0]; val[1] = (float)hv[1]; val[2] = (float)hv[2]; val[3] = (float)hv[3];
    }
    *(f4*)&tl[row][d4] = val;
  }
  __syncthreads();
  float wt[33];
  #pragma unroll
  for (int tap = 0; tap < 33; tap++) wt[tap] = rw[h * 33 + tap];
  int d4 = (threadIdx.x & 15) * 4, r0 = threadIdx.x >> 4;
  #pragma unroll
  for (int k = 0; k < 8; k++) {
    int r = k * 16 + r0;
    int t = t0 + r;
    f4 acc = {0.f, 0.f, 0.f, 0.f};
    #pragma unroll
    for (int tap = 0; tap < 33; tap++) {
      f4 vv = *(const f4*)&tl[r + tap][d4];
      acc[0] += wt[tap] * vv[0]; acc[1] += wt[tap] * vv[1];
      acc[2] += wt[tap] * vv[2]; acc[3] += wt[tap] * vv[3];
    }
    if (t < NSEQ) {
      h4 o = {(_Float16)acc[0], (_Float16)acc[1], (_Float16)acc[2], (_Float16)acc[3]};
      *(h4*)(xat + (size_t)t * DIMC + h * 64 + d4) = o;
    }
  }
}

// ---------------- MFMA attn1: xat += softmax(0.125 * q @ kl^T) @ w2 ----------------
__global__ __launch_bounds__(256)
void k_attn1(const _Float16* __restrict__ q16, const _Float16* __restrict__ kl16,
             const _Float16* __restrict__ w2t16, _Float16* __restrict__ xat)
{
  __shared__ __attribute__((aligned(16))) _Float16 qs[64 * 64];
  __shared__ __attribute__((aligned(16))) _Float16 Pl[4][16 * 264];
  int h = blockIdx.y;
  int t0 = PADF + blockIdx.x * 64;
  int tid = threadIdx.x, lane = tid & 63, w = tid >> 6;
  int r = lane & 15, q = lane >> 4;
  for (int c = tid; c < 512; c += 256) {
    int row = c >> 3, ch = (c & 7) * 8;
    int t = t0 + row; if (t > NSEQ - 1) t = NSEQ - 1;
    *(h8*)(qs + row * 64 + ch) = *(const h8*)(q16 + ((size_t)h * NSEQP + t) * 64 + ch);
  }
  __syncthreads();
  int m0 = w * 16;
  h8 af0 = *(const h8*)(qs + (m0 + r) * 64 + q * 8);
  h8 af1 = *(const h8*)(qs + (m0 + r) * 64 + 32 + q * 8);

  const f4 zero = {0.f, 0.f, 0.f, 0.f};
  f4 S[16];
  #pragma unroll
  for (int nj = 0; nj < 16; nj++) S[nj] = zero;
  const _Float16* klh = kl16 + (size_t)h * MLM * 64;
  #pragma unroll
  for (int nj = 0; nj < 16; nj++) {
    h8 b0 = *(const h8*)(klh + (size_t)(nj * 16 + r) * 64 + q * 8);
    h8 b1 = *(const h8*)(klh + (size_t)(nj * 16 + r) * 64 + 32 + q * 8);
    S[nj] = __builtin_amdgcn_mfma_f32_16x16x32_f16(af0, b0, S[nj], 0, 0, 0);
    S[nj] = __builtin_amdgcn_mfma_f32_16x16x32_f16(af1, b1, S[nj], 0, 0, 0);
  }
  float mx[4] = {-1e30f, -1e30f, -1e30f, -1e30f};
  #pragma unroll
  for (int nj = 0; nj < 16; nj++)
    #pragma unroll
    for (int i = 0; i < 4; i++) {
      S[nj][i] *= 0.125f;
      mx[i] = fmaxf(mx[i], S[nj][i]);
    }
  #pragma unroll
  for (int i = 0; i < 4; i++)
    #pragma unroll
    for (int o = 1; o < 16; o <<= 1) mx[i] = fmaxf(mx[i], __shfl_xor(mx[i], o, 64));
  float l[4] = {};
  _Float16* Pw = &Pl[w][0];
  #pragma unroll
  for (int nj = 0; nj < 16; nj++)
    #pragma unroll
    for (int i = 0; i < 4; i++) {
      float p = __expf(S[nj][i] - mx[i]);
      l[i] += p;
      Pw[(q * 4 + i) * 264 + nj * 16 + r] = (_Float16)p;
    }
  #pragma unroll
  for (int i = 0; i < 4; i++)
    #pragma unroll
    for (int o = 1; o < 16; o <<= 1) l[i] += __shfl_xor(l[i], o, 64);
  __syncthreads();
  f4 o4[4];
  #pragma unroll
  for (int nd = 0; nd < 4; nd++) o4[nd] = zero;
  const _Float16* w2h = w2t16 + (size_t)h * 64 * 256;
  #pragma unroll
  for (int ks = 0; ks < 8; ks++) {
    h8 ap = *(const h8*)(Pw + r * 264 + ks * 32 + q * 8);
    #pragma unroll
    for (int nd = 0; nd < 4; nd++) {
      h8 bw = *(const h8*)(w2h + (size_t)(nd * 16 + r) * 256 + ks * 32 + q * 8);
      o4[nd] = __builtin_amdgcn_mfma_f32_16x16x32_f16(ap, bw, o4[nd], 0, 0, 0);
    }
  }
  __syncthreads();
  float* ow = (float*)&Pl[w][0];     // 16 x 66 fp32
  float li[4];
  #pragma unroll
  for (int i = 0; i < 4; i++) li[i] = 1.f / l[i];
  #pragma unroll
  for (int nd = 0; nd < 4; nd++)
    #pragma unroll
    for (int i = 0; i < 4; i++)
      ow[(q * 4 + i) * 66 + nd * 16 + r] = o4[nd][i] * li[i];
  __syncthreads();
  #pragma unroll
  for (int c = 0; c < 2; c++) {
    int e = lane + c * 64;
    int row = e >> 3, ch = (e & 7) * 8;
    int t = t0 + m0 + row;
    if (t < NSEQ) {
      float* src = ow + row * 66 + ch;
      _Float16* dst = xat + (size_t)t * DIMC + h * 64 + ch;
      h8 cv = *(h8*)dst;
      h8 outv;
      #pragma unroll
      for (int k = 0; k < 8; k++) outv[k] = (_Float16)(src[k] + (float)cv[k]);
      *(h8*)dst = outv;
    }
  }
}

// ---------------- PPEG ----------------
__global__ __launch_bounds__(256)
void k_transpose_fw(const float* __restrict__ h, float* __restrict__ g)
{
  __shared__ float tile[32][33];
  int pb = blockIdx.x * 32, cb = blockIdx.y * 32;
  int x = threadIdx.x & 31, y0 = threadIdx.x >> 5;
  #pragma unroll
  for (int yy = y0; yy < 32; yy += 8)
    tile[yy][x] = h[(size_t)(1 + pb + yy) * DIMC + cb + x];
  __syncthreads();
  #pragma unroll
  for (int yy = y0; yy < 32; yy += 8)
    g[(size_t)(cb + yy) * NPATCH + pb + x] = tile[x][yy];
}

__global__ __launch_bounds__(256)
void k_ppeg(const float* __restrict__ g,
            const float* __restrict__ w7, const float* __restrict__ b7,
            const float* __restrict__ w5, const float* __restrict__ b5,
            const float* __restrict__ w3, const float* __restrict__ b3,
            float* __restrict__ o)
{
  __shared__ float tl[22][22];
  int c = blockIdx.y;
  int ty0 = (blockIdx.x / 13) * 16, tx0 = (blockIdx.x % 13) * 16;
  const float* gc = g + (size_t)c * NPATCH;
  for (int e = threadIdx.x; e < 22 * 22; e += 256) {
    int yy = e / 22, xx = e % 22;
    int y = ty0 - 3 + yy, x = tx0 - 3 + xx;
    tl[yy][xx] = (y >= 0 && y < GRID && x >= 0 && x < GRID) ? gc[y * GRID + x] : 0.f;
  }
  __syncthreads();
  int ly = threadIdx.x >> 4, lx = threadIdx.x & 15;
  int y = ty0 + ly, x = tx0 + lx;
  if (y >= GRID || x >= GRID) return;
  float acc = tl[ly + 3][lx + 3] + b7[c] + b5[c] + b3[c];
  #pragma unroll
  for (int ky = 0; ky < 7; ky++)
    #pragma unroll
    for (int kx = 0; kx < 7; kx++)
      acc += w7[c * 49 + ky * 7 + kx] * tl[ly + ky][lx + kx];
  #pragma unroll
  for (int ky = 0; ky < 5; ky++)
    #pragma unroll
    for (int kx = 0; kx < 5; kx++)
      acc += w5[c * 25 + ky * 5 + kx] * tl[ly + 1 + ky][lx + 1 + kx];
  #pragma unroll
  for (int ky = 0; ky < 3; ky++)
    #pragma unroll
    for (int kx = 0; kx < 3; kx++)
      acc += w3[c * 9 + ky * 3 + kx] * tl[ly + 2 + ky][lx + 2 + kx];
  o[(size_t)c * NPATCH + y * GRID + x] = acc;
}

__global__ __launch_bounds__(256)
void k_transpose_bw(const float* __restrict__ g, float* __restrict__ h)
{
  __shared__ float tile[32][33];
  int pb = blockIdx.x * 32, cb = blockIdx.y * 32;
  int x = threadIdx.x & 31, y0 = threadIdx.x >> 5;
  #pragma unroll
  for (int yy = y0; yy < 32; yy += 8)
    tile[yy][x] = g[(size_t)(cb + yy) * NPATCH + pb + x];
  __syncthreads();
  #pragma unroll
  for (int yy = y0; yy < 32; yy += 8)
    h[(size_t)(1 + pb + yy) * DIMC + cb + x] = tile[x][yy];
}

// ---------------- final: layernorm(row 0) @ fc2 ----------------
__global__ __launch_bounds__(512)
void k_final(const float* __restrict__ h, const float* __restrict__ nw, const float* __restrict__ nb,
             const float* __restrict__ fw, const float* __restrict__ fb, float* __restrict__ out)
{
  __shared__ float sbuf[8];
  int d = threadIdx.x;
  float x = h[d];
  float mu = blkRed<8,false>(x, sbuf) * (1.f / 512.f);
  float dd = x - mu;
  float var = blkRed<8,false>(dd * dd, sbuf) * (1.f / 512.f);
  float cls = dd * rsqrtf(var + 1e-5f) * nw[d] + nb[d];
  float l0 = blkRed<8,false>(cls * fw[d * 2 + 0], sbuf);
  float l1 = blkRed<8,false>(cls * fw[d * 2 + 1], sbuf);
  if (d == 0) { out[0] = l0 + fb[0]; out[1] = l1 + fb[1]; }
}

// ---------------- host orchestration ----------------
struct WsPtrs {
  float *h, *ql, *kl, *a2, *zA, *zB, *xz, *u, *u2, *av, *w2, *hmax, *scal, *pm, *ps, *pacc;
  _Float16 *xat16, *q16, *k16, *v16, *vt16, *ql16, *kl16, *w2t16, *x16;
};

static void attention_layer(const WsPtrs& P,
                            const float* nw, const float* nb, const _Float16* qkvw16,
                            const _Float16* ow16, const float* ob, const float* rw,
                            hipStream_t stream)
{
  k_zpad<<<64, 256, 0, stream>>>(P.q16, P.k16, P.v16);
  k_ln_pad<<<NSEQ, 256, 0, stream>>>(P.h, nw, nb, P.xat16);
  k_gemm16<<<dim3(NSEQ / 128, 1536 / 128), 256, 0, stream>>>(
      P.xat16, qkvw16, nullptr, nullptr, P.q16, P.k16, P.v16, NSEQ, DIMC, 3 * DIMC, 4);
  k_vt<<<dim3(629, HEADS), 256, 0, stream>>>(P.v16, P.vt16);
  k_landmarks<<<HEADS * MLM, 256, 0, stream>>>(P.q16, P.k16, P.ql, P.kl, P.ql16, P.kl16);
  k_attn2<<<HEADS * MLM, 256, 0, stream>>>(P.ql, P.kl, P.a2);
  k_pinv_init1<<<HEADS, 256, 0, stream>>>(P.a2, P.hmax);
  k_pinv_init2<<<1, 1, 0, stream>>>(P.hmax, P.scal);
  k_transpose_scale<<<HEADS * MLM, 256, 0, stream>>>(P.a2, P.scal, P.zA);
  float* z = P.zA; float* zn = P.zB;
  for (int it = 0; it < 6; it++) {
    k_bmm<<<dim3(16, HEADS), 256, 0, stream>>>(P.a2, z,    nullptr, P.xz, MLM, 1.f,   0.f);
    k_bmm<<<dim3(16, HEADS), 256, 0, stream>>>(P.xz, P.xz, P.xz,    P.u,  MLM, -1.f,  7.f);
    k_bmm<<<dim3(16, HEADS), 256, 0, stream>>>(P.xz, P.u,  P.xz,    P.u2, MLM, -1.f,  15.f);
    k_bmm<<<dim3(16, HEADS), 256, 0, stream>>>(z,    P.u2, z,       zn,   MLM, -0.25f, 3.25f);
    float* t = z; z = zn; zn = t;
  }
  k_attn3<<<dim3(CHUNKS, HEADS), 256, 0, stream>>>(P.ql16, P.k16, P.vt16, P.pm, P.ps, P.pacc);
  k_attn3_reduce<<<HEADS * MLM, 64, 0, stream>>>(P.pm, P.ps, P.pacc, P.av);
  k_bmm<<<dim3(4, HEADS), 256, 0, stream>>>(z, P.av, nullptr, P.w2, DH, 1.f, 0.f);
  k_w2t<<<HEADS, 256, 0, stream>>>(P.w2, P.w2t16);
  k_conv<<<dim3(313, HEADS), 256, 0, stream>>>(P.v16, rw, P.xat16);
  k_attn1<<<dim3(626, HEADS), 256, 0, stream>>>(P.q16, P.kl16, P.w2t16, P.xat16);
  k_gemm16<<<dim3((NTOK + 127) / 128, DIMC / 128), 256, 0, stream>>>(
      P.xat16 + (size_t)PADF * DIMC, ow16, ob, P.h, nullptr, nullptr, nullptr, NTOK, DIMC, DIMC, 2);
}

extern "C" void kernel_launch(void* const* d_in, const int* in_sizes, int n_in,
                              void* d_out, int out_size, void* d_ws, size_t ws_size,
                              hipStream_t stream)
{
  const float* x      = (const float*)d_in[0];
  const float* fc1_w  = (const float*)d_in[1];
  const float* fc1_b  = (const float*)d_in[2];
  const float* cls    = (const float*)d_in[3];
  const float* l1_nw  = (const float*)d_in[4];
  const float* l1_nb  = (const float*)d_in[5];
  const float* l1_qkv = (const float*)d_in[6];
  const float* l1_ow  = (const float*)d_in[7];
  const float* l1_ob  = (const float*)d_in[8];
  const float* l1_rw  = (const float*)d_in[9];
  const float* p7w    = (const float*)d_in[10];
  const float* p7b    = (const float*)d_in[11];
  const float* p5w    = (const float*)d_in[12];
  const float* p5b    = (const float*)d_in[13];
  const float* p3w    = (const float*)d_in[14];
  const float* p3b    = (const float*)d_in[15];
  const float* l2_nw  = (const float*)d_in[16];
  const float* l2_nb  = (const float*)d_in[17];
  const float* l2_qkv = (const float*)d_in[18];
  const float* l2_ow  = (const float*)d_in[19];
  const float* l2_ob  = (const float*)d_in[20];
  const float* l2_rw  = (const float*)d_in[21];
  const float* nw     = (const float*)d_in[22];
  const float* nb     = (const float*)d_in[23];
  const float* fc2w   = (const float*)d_in[24];
  const float* fc2b   = (const float*)d_in[25];
  float* out = (float*)d_out;

  // ---- workspace carve-up (float offsets); total ~86M floats ~ 344 MB ----
  float* W = (float*)d_ws;
  WsPtrs P;
  size_t off = 0;
  P.h     = W + off;               off += 20480512ull;   // 40001 x 512 fp32
  P.xat16 = (_Float16*)(W + off);  off += 10289152ull;   // NSEQ x 512 fp16
  float* R0 = W + off;                                   // fp16 q/k/v/vt region
  P.q16   = (_Float16*)R0;
  P.k16   = P.q16 + 20594688ull;   // 8 x 40224 x 64
  P.v16   = P.k16 + 20594688ull;
  P.vt16  = P.v16 + 20594688ull;   // 8 x 64 x 40224
  P.x16   = P.q16;                 // alias: fc1 input fp16 (dead before qkv GEMM)
  off += 41189376ull;              // 4 x 20594688 halfs / 2
  P.ql    = W + off; off += 131072;
  P.kl    = W + off; off += 131072;
  P.ql16  = (_Float16*)(W + off); off += 65536;
  P.kl16  = (_Float16*)(W + off); off += 65536;
  P.a2    = W + off; off += 524288;
  P.zA    = W + off; off += 524288;
  P.zB    = W + off; off += 524288;
  P.xz    = W + off; off += 524288;
  P.u     = W + off; off += 524288;
  P.u2    = W + off; off += 524288;
  P.av    = W + off; off += 131072;
  P.w2    = W + off; off += 131072;
  P.w2t16 = (_Float16*)(W + off); off += 32768;
  P.hmax  = W + off; P.scal = P.hmax + 16; off += 32;
  P.pm    = W + off; off += 131072;
  P.ps    = W + off; off += 131072;
  P.pacc  = W + off; off += 8388608;
  _Float16* fc1t  = (_Float16*)(W + off);   // 512x1024
  _Float16* qkv1t = fc1t  + 524288;         // 1536x512
  _Float16* out1t = qkv1t + 786432;         // 512x512
  _Float16* qkv2t = out1t + 262144;
  _Float16* out2t = qkv2t + 786432;

  // ---- weight fp32 -> fp16 transposed (N x K) ----
  k_wt16<<<dim3(INDIM / 32, DIMC / 32), 256, 0, stream>>>(fc1_w, fc1t, INDIM, DIMC);
  k_wt16<<<dim3(DIMC / 32, 1536 / 32), 256, 0, stream>>>(l1_qkv, qkv1t, DIMC, 1536);
  k_wt16<<<dim3(DIMC / 32, DIMC / 32), 256, 0, stream>>>(l1_ow, out1t, DIMC, DIMC);
  k_wt16<<<dim3(DIMC / 32, 1536 / 32), 256, 0, stream>>>(l2_qkv, qkv2t, DIMC, 1536);
  k_wt16<<<dim3(DIMC / 32, DIMC / 32), 256, 0, stream>>>(l2_ow, out2t, DIMC, DIMC);

  // fc1 + relu -> h rows 1..40000 ; cls token -> h row 0
  k_f32_to_f16<<<NPATCH * INDIM / 1024, 256, 0, stream>>>(x, P.x16);
  k_gemm16<<<dim3((NPATCH + 127) / 128, DIMC / 128), 256, 0, stream>>>(
      P.x16, fc1t, fc1_b, P.h + DIMC, nullptr, nullptr, nullptr, NPATCH, INDIM, DIMC, 1);
  k_set_cls<<<1, 512, 0, stream>>>(cls, P.h);

  // layer 1 attention
  attention_layer(P, l1_nw, l1_nb, qkv1t, out1t, l1_ob, l1_rw, stream);

  // PPEG (aliases the q/k/v fp16 region as fp32 scratch)
  float* fgrid = R0;
  float* cout  = R0 + 20480000ull;
  k_transpose_fw<<<dim3(NPATCH / 32, DIMC / 32), 256, 0, stream>>>(P.h, fgrid);
  k_ppeg<<<dim3(13 * 13, DIMC), 256, 0, stream>>>(fgrid, p7w, p7b, p5w, p5b, p3w, p3b, cout);
  k_transpose_bw<<<dim3(NPATCH / 32, DIMC / 32), 256, 0, stream>>>(cout, P.h);

  // layer 2 attention
  attention_layer(P, l2_nw, l2_nb, qkv2t, out2t, l2_ob, l2_rw, stream);

  // final layernorm (cls row only) + fc2
  k_final<<<1, 512, 0, stream>>>(P.h, nw, nb, fc2w, fc2b, out);
}

// Round 4
// 3892.775 us; speedup vs baseline: 2.8226x; 1.0011x over previous
//
#include <hip/hip_runtime.h>
#include <hip/hip_bf16.h>

// ---------------- problem constants ----------------
#define DIMC   512
#define HEADS  8
#define DH     64
#define MLM    256          // landmarks
#define NPATCH 40000
#define NTOK   40001        // with cls
#define PADF   191          // front zero pad
#define NSEQ   40192        // NTOK + PADF
#define NSEQP  40224        // NSEQ + 32 (zero pad for flash tiles)
#define LWIN   157          // NSEQ / MLM
#define INDIM  1024
#define GRID   200
#define CHUNKS 64
#define PER    628          // NSEQ / CHUNKS

typedef _Float16 h8 __attribute__((ext_vector_type(8)));
typedef _Float16 h4 __attribute__((ext_vector_type(4)));
typedef float    f4 __attribute__((ext_vector_type(4)));

// async global->LDS, 16B per lane; LDS dest = wave-uniform base + lane*16
__device__ __forceinline__ void gl_lds(const _Float16* g, _Float16* l) {
  __builtin_amdgcn_global_load_lds(
      (const __attribute__((address_space(1))) void*)g,
      (__attribute__((address_space(3))) void*)l, 16, 0, 0);
}

// ---------------- reductions ----------------
template<int NW, bool ISMAX>
__device__ __forceinline__ float blkRed(float v, float* s) {
  #pragma unroll
  for (int o = 32; o; o >>= 1) {
    float t = __shfl_down(v, o, 64);
    v = ISMAX ? fmaxf(v, t) : v + t;
  }
  int lane = threadIdx.x & 63, w = threadIdx.x >> 6;
  __syncthreads();
  if (lane == 0) s[w] = v;
  __syncthreads();
  float r = s[0];
  #pragma unroll
  for (int i = 1; i < NW; i++) r = ISMAX ? fmaxf(r, s[i]) : r + s[i];
  return r;
}

// ---------------- misc small kernels ----------------
__global__ __launch_bounds__(512)
void k_set_cls(const float* __restrict__ cls, float* __restrict__ h) {
  h[threadIdx.x] = cls[threadIdx.x];
}

__global__ __launch_bounds__(256)
void k_f32_to_f16(const float* __restrict__ in, _Float16* __restrict__ out) {
  int i = blockIdx.x * 256 + threadIdx.x;
  float4 v = ((const float4*)in)[i];
  h4 o = {(_Float16)v.x, (_Float16)v.y, (_Float16)v.z, (_Float16)v.w};
  *(h4*)(out + (size_t)i * 4) = o;
}

// zero the 32-row pads of q16/k16/v16 (8 heads x 32 rows x 64)
__global__ __launch_bounds__(256)
void k_zpad(_Float16* q16, _Float16* k16, _Float16* v16) {
  int idx = blockIdx.x * 256 + threadIdx.x;       // 16384 total
  int h = idx >> 11, r = (idx >> 6) & 31, d = idx & 63;
  size_t a = ((size_t)h * NSEQP + NSEQ + r) * 64 + d;
  q16[a] = (_Float16)0.f; k16[a] = (_Float16)0.f; v16[a] = (_Float16)0.f;
}

// weight K x N fp32 -> transposed N x K fp16
__global__ __launch_bounds__(256)
void k_wt16(const float* __restrict__ B, _Float16* __restrict__ Bt, int K, int N)
{
  __shared__ float tile[32][33];
  int kb = blockIdx.x * 32, nb = blockIdx.y * 32;
  int x = threadIdx.x & 31, y0 = threadIdx.x >> 5;
  #pragma unroll
  for (int yy = y0; yy < 32; yy += 8)
    tile[yy][x] = B[(size_t)(kb + yy) * N + nb + x];
  __syncthreads();
  #pragma unroll
  for (int yy = y0; yy < 32; yy += 8)
    Bt[(size_t)(nb + yy) * K + kb + x] = (_Float16)tile[x][yy];
}

// ---------------- fp16 MFMA GEMM (global_load_lds staging, m97-style) ----------------
// flags: 1 = relu, 2 = accumulate into C, 4 = qkv scatter store (fp16 head-major)
__global__ __launch_bounds__(256)
void k_gemm16(const _Float16* __restrict__ A, const _Float16* __restrict__ Bt,
              const float* __restrict__ bias, float* __restrict__ C,
              _Float16* __restrict__ q16, _Float16* __restrict__ k16, _Float16* __restrict__ v16,
              int Mr, int K, int N, int flags)
{
  __shared__ __attribute__((aligned(16))) _Float16 As[128 * 32];
  __shared__ __attribute__((aligned(16))) _Float16 Bs[128 * 32];
  int bm = blockIdx.x * 128, bn = blockIdx.y * 128;
  int t = threadIdx.x;
  int lane = t & 63, w = t >> 6;
  int wm = (w >> 1) * 64, wn = (w & 1) * 64;
  int r = lane & 15, q = lane >> 4;
  int sub = lane >> 2;            // row within 16-row staging group
  int kq = (lane & 3) * 8;        // col (halves) within row

  const f4 zero = {0.f, 0.f, 0.f, 0.f};
  f4 acc[4][4];
  #pragma unroll
  for (int mi = 0; mi < 4; mi++)
    #pragma unroll
    for (int nj = 0; nj < 4; nj++) acc[mi][nj] = zero;

  for (int k0 = 0; k0 < K; k0 += 32) {
    // async-stage 128x32 A and B tiles: each wave deposits 2x1KB per tile
    #pragma unroll
    for (int c = 0; c < 2; c++) {
      int rowA = (w * 2 + c) * 16 + sub;
      int gmA = bm + rowA; if (gmA > Mr - 1) gmA = Mr - 1;
      gl_lds(A  + (size_t)gmA * K + k0 + kq,          As + (w * 2 + c) * 512);
      gl_lds(Bt + (size_t)(bn + rowA) * K + k0 + kq,  Bs + (w * 2 + c) * 512);
    }
    __syncthreads();
    h8 af[4], bf[4];
    #pragma unroll
    for (int i = 0; i < 4; i++) {
      af[i] = *(const h8*)(As + (wm + i * 16 + r) * 32 + q * 8);
      bf[i] = *(const h8*)(Bs + (wn + i * 16 + r) * 32 + q * 8);
    }
    #pragma unroll
    for (int mi = 0; mi < 4; mi++)
      #pragma unroll
      for (int nj = 0; nj < 4; nj++)
        acc[mi][nj] = __builtin_amdgcn_mfma_f32_16x16x32_f16(af[mi], bf[nj], acc[mi][nj], 0, 0, 0);
    __syncthreads();
  }
  #pragma unroll
  for (int mi = 0; mi < 4; mi++) {
    #pragma unroll
    for (int i = 0; i < 4; i++) {
      int gm = bm + wm + mi * 16 + q * 4 + i;
      if (gm >= Mr) continue;
      #pragma unroll
      for (int nj = 0; nj < 4; nj++) {
        int gn = bn + wn + nj * 16 + r;
        float v = acc[mi][nj][i];
        if (flags & 4) {
          int which = gn >> 9, hh = (gn >> 6) & 7, dd = gn & 63;
          _Float16* dst = (which == 0) ? q16 : (which == 1) ? k16 : v16;
          dst[((size_t)hh * NSEQP + gm) * 64 + dd] = (_Float16)v;
        } else {
          if (bias) v += bias[gn];
          if (flags & 2) v += C[(size_t)gm * N + gn];
          if (flags & 1) v = fmaxf(v, 0.f);
          C[(size_t)gm * N + gn] = v;
        }
      }
    }
  }
}

// ---------------- layernorm + front zero pad (fp16 out) ----------------
__global__ __launch_bounds__(256)
void k_ln_pad(const float* __restrict__ h, const float* __restrict__ w,
              const float* __restrict__ b, _Float16* __restrict__ xln)
{
  __shared__ float sbuf[8];
  int t = blockIdx.x;
  int tid = threadIdx.x;
  _Float16* out = xln + (size_t)t * DIMC;
  if (t < PADF) { out[tid] = (_Float16)0.f; out[tid + 256] = (_Float16)0.f; return; }
  const float* row = h + (size_t)(t - PADF) * DIMC;
  float x0 = row[tid], x1 = row[tid + 256];
  float mu = blkRed<4,false>(x0 + x1, sbuf) * (1.f / 512.f);
  float d0 = x0 - mu, d1 = x1 - mu;
  float var = blkRed<4,false>(d0 * d0 + d1 * d1, sbuf) * (1.f / 512.f);
  float rstd = rsqrtf(var + 1e-5f);
  out[tid]       = (_Float16)(d0 * rstd * w[tid]       + b[tid]);
  out[tid + 256] = (_Float16)(d1 * rstd * w[tid + 256] + b[tid + 256]);
}

// ---------------- v16 [h][t][64] -> vt16 [h][64][NSEQP] transpose ----------------
__global__ __launch_bounds__(256)
void k_vt(const _Float16* __restrict__ v16, _Float16* __restrict__ vt16)
{
  __shared__ _Float16 tl[64][72];
  int h = blockIdx.y;
  int t0 = blockIdx.x * 64;
  for (int c = threadIdx.x; c < 512; c += 256) {
    int row = c >> 3, ch = (c & 7) * 8;
    h8 v = {};
    if (t0 + row < NSEQP)
      v = *(const h8*)(v16 + ((size_t)h * NSEQP + t0 + row) * 64 + ch);
    *(h8*)&tl[row][ch] = v;
  }
  __syncthreads();
  int d = threadIdx.x & 63, tg = (threadIdx.x >> 6) * 16;
  if (t0 + tg < NSEQP) {
    _Float16 tmp[16];
    #pragma unroll
    for (int k = 0; k < 16; k++) tmp[k] = tl[tg + k][d];
    *(h8*)(vt16 + ((size_t)h * 64 + d) * NSEQP + t0 + tg)     = *(h8*)tmp;
    *(h8*)(vt16 + ((size_t)h * 64 + d) * NSEQP + t0 + tg + 8) = *(h8*)(tmp + 8);
  }
}

// ---------------- landmarks from fp16 q/k ----------------
// ql/ql16 get 0.125 fold (used by attn2/attn3); kl16 gets 0.125 fold (used by attn1 vs raw q)
__global__ __launch_bounds__(256)
void k_landmarks(const _Float16* __restrict__ q16, const _Float16* __restrict__ k16,
                 float* __restrict__ ql, float* __restrict__ kl,
                 _Float16* __restrict__ ql16, _Float16* __restrict__ kl16)
{
  __shared__ float red[2][16][64];
  int h = blockIdx.x >> 8, i = blockIdx.x & 255;
  int jg = threadIdx.x >> 4, d4 = (threadIdx.x & 15) * 4;
  const _Float16* qb = q16 + ((size_t)h * NSEQP + i * LWIN) * 64;
  const _Float16* kb = k16 + ((size_t)h * NSEQP + i * LWIN) * 64;
  float sq[4] = {}, sk[4] = {};
  for (int j = jg; j < LWIN; j += 16) {
    h4 qv = *(const h4*)(qb + j * 64 + d4);
    h4 kv = *(const h4*)(kb + j * 64 + d4);
    #pragma unroll
    for (int c = 0; c < 4; c++) { sq[c] += (float)qv[c]; sk[c] += (float)kv[c]; }
  }
  #pragma unroll
  for (int c = 0; c < 4; c++) { red[0][jg][d4 + c] = sq[c]; red[1][jg][d4 + c] = sk[c]; }
  __syncthreads();
  if (threadIdx.x < 64) {
    int d = threadIdx.x;
    float aq = 0.f, ak = 0.f;
    #pragma unroll
    for (int g = 0; g < 16; g++) { aq += red[0][g][d]; ak += red[1][g][d]; }
    aq *= (0.125f / (float)LWIN);
    ak *= (1.f / (float)LWIN);
    size_t o = ((size_t)h * MLM + i) * DH + d;
    ql[o] = aq; kl[o] = ak;
    ql16[o] = (_Float16)aq;
    kl16[o] = (_Float16)(ak * 0.125f);   // fold q-scale for attn1
  }
}

// ---------------- attn2 = softmax(q_l @ k_l^T) ----------------
__global__ __launch_bounds__(256)
void k_attn2(const float* __restrict__ ql, const float* __restrict__ kl, float* __restrict__ a2)
{
  __shared__ float qrow[DH];
  __shared__ float sbuf[8];
  int h = blockIdx.x >> 8, i = blockIdx.x & 255;
  int j = threadIdx.x;
  if (j < DH) qrow[j] = ql[(h * MLM + i) * DH + j];
  __syncthreads();
  const float* krow = kl + (size_t)(h * MLM + j) * DH;
  float s = 0.f;
  #pragma unroll 16
  for (int d = 0; d < DH; d++) s += qrow[d] * krow[d];
  float mx = blkRed<4,true>(s, sbuf);
  float e = __expf(s - mx);
  float sum = blkRed<4,false>(e, sbuf);
  a2[((size_t)h * MLM + i) * MLM + j] = e / sum;
}

// ---------------- pinv init ----------------
__global__ __launch_bounds__(256)
void k_pinv_init1(const float* __restrict__ a2, float* __restrict__ hmax)
{
  __shared__ float sbuf[8];
  int h = blockIdx.x;
  int j = threadIdx.x;
  const float* A = a2 + (size_t)h * MLM * MLM;
  float cs = 0.f, rs = 0.f;
  for (int i = 0; i < MLM; i++) cs += A[i * MLM + j];
  for (int k = 0; k < MLM; k++) rs += A[j * MLM + k];
  float rmax = blkRed<4,true>(rs, sbuf);
  float cmax = blkRed<4,true>(cs, sbuf);
  if (j == 0) { hmax[h * 2] = rmax; hmax[h * 2 + 1] = cmax; }
}

__global__ void k_pinv_init2(const float* __restrict__ hmax, float* __restrict__ scal)
{
  float rm = 0.f, cm = 0.f;
  for (int h = 0; h < HEADS; h++) { rm = fmaxf(rm, hmax[2*h]); cm = fmaxf(cm, hmax[2*h+1]); }
  scal[0] = 1.f / (rm * cm);
}

__global__ __launch_bounds__(256)
void k_transpose_scale(const float* __restrict__ a2, const float* __restrict__ scal, float* __restrict__ z)
{
  int h = blockIdx.x >> 8, j = blockIdx.x & 255;
  int i = threadIdx.x;
  z[((size_t)h * MLM + j) * MLM + i] = a2[((size_t)h * MLM + i) * MLM + j] * scal[0];
}

// ---------------- batched 256xN matmul: C[h] = c0*(A[h]@B[h]) + c1*E[h] ----------------
__global__ __launch_bounds__(256)
void k_bmm(const float* __restrict__ A, const float* __restrict__ Bm,
           const float* __restrict__ E, float* __restrict__ C,
           int N, float c0, float c1)
{
  __shared__ float As[64][17];
  __shared__ float Bs[16][64];
  int ntiles = N >> 6;
  int h = blockIdx.y;
  int bm = (blockIdx.x / ntiles) << 6;
  int bn = (blockIdx.x % ntiles) << 6;
  const float* Ah = A + (size_t)h * (MLM * MLM);
  const float* Bh = Bm + (size_t)h * (MLM * N);
  int tid = threadIdx.x;
  int tx = tid & 15, ty = tid >> 4;
  float acc[4][4] = {};
  for (int k0 = 0; k0 < MLM; k0 += 16) {
    #pragma unroll
    for (int e = tid; e < 64 * 16; e += 256) {
      int m = e >> 4, k = e & 15;
      As[m][k] = Ah[(size_t)(bm + m) * MLM + k0 + k];
    }
    #pragma unroll
    for (int e = tid; e < 16 * 64; e += 256) {
      int k = e >> 6, n = e & 63;
      Bs[k][n] = Bh[(size_t)(k0 + k) * N + bn + n];
    }
    __syncthreads();
    #pragma unroll
    for (int k = 0; k < 16; k++) {
      float a[4], b[4];
      #pragma unroll
      for (int i = 0; i < 4; i++) a[i] = As[ty * 4 + i][k];
      #pragma unroll
      for (int j = 0; j < 4; j++) b[j] = Bs[k][tx * 4 + j];
      #pragma unroll
      for (int i = 0; i < 4; i++)
        #pragma unroll
        for (int j = 0; j < 4; j++) acc[i][j] += a[i] * b[j];
    }
    __syncthreads();
  }
  #pragma unroll
  for (int i = 0; i < 4; i++) {
    int gm = bm + ty * 4 + i;
    #pragma unroll
    for (int j = 0; j < 4; j++) {
      int gn = bn + tx * 4 + j;
      size_t idx = (size_t)h * (MLM * N) + (size_t)gm * N + gn;
      float v = c0 * acc[i][j];
      if (E) v += c1 * E[idx];
      C[idx] = v;
    }
  }
}

// ---------------- w2 fp32 [h][256][64] -> w2t16 fp16 [h][64][256] ----------------
__global__ __launch_bounds__(256)
void k_w2t(const float* __restrict__ w2, _Float16* __restrict__ w2t)
{
  __shared__ _Float16 tl[64 * 264];
  int h = blockIdx.x;
  for (int c = threadIdx.x; c < 256 * 16; c += 256) {
    int m = c >> 4, d4 = (c & 15) * 4;
    f4 v = *(const f4*)(w2 + ((size_t)h * 256 + m) * 64 + d4);
    #pragma unroll
    for (int k = 0; k < 4; k++) tl[(d4 + k) * 264 + m] = (_Float16)v[k];
  }
  __syncthreads();
  for (int c = threadIdx.x; c < 2048; c += 256) {
    int d = c >> 5, ch = (c & 31) * 8;
    *(h8*)(w2t + ((size_t)h * 64 + d) * 256 + ch) = *(h8*)&tl[d * 264 + ch];
  }
}

// ---------------- flash attn3: partials of softmax(ql @ k^T) @ v ----------------
__global__ __launch_bounds__(256)
void k_attn3(const _Float16* __restrict__ ql16, const _Float16* __restrict__ k16,
             const _Float16* __restrict__ vt16,
             float* __restrict__ pm, float* __restrict__ ps, float* __restrict__ pacc)
{
  __shared__ __attribute__((aligned(16))) _Float16 Pl[4][64 * 40];
  int c = blockIdx.x, h = blockIdx.y;
  int tid = threadIdx.x, lane = tid & 63, w = tid >> 6;
  int r = lane & 15, q = lane >> 4;
  int t0 = c * PER;
  int m0 = w * 64;
  const _Float16* qlh = ql16 + (size_t)h * MLM * 64;
  const _Float16* kh  = k16  + (size_t)h * NSEQP * 64;
  const _Float16* vh  = vt16 + (size_t)h * 64 * NSEQP;
  _Float16* Pw = &Pl[w][0];

  h8 af[4][2];
  #pragma unroll
  for (int mt = 0; mt < 4; mt++)
    #pragma unroll
    for (int ks = 0; ks < 2; ks++)
      af[mt][ks] = *(const h8*)(qlh + (size_t)(m0 + mt * 16 + r) * 64 + ks * 32 + q * 8);

  const f4 zero = {0.f, 0.f, 0.f, 0.f};
  f4 acc[4][4];
  float mrun[4][4], lrun[4][4];
  #pragma unroll
  for (int mt = 0; mt < 4; mt++) {
    #pragma unroll
    for (int nd = 0; nd < 4; nd++) acc[mt][nd] = zero;
    #pragma unroll
    for (int i = 0; i < 4; i++) { mrun[mt][i] = -1e30f; lrun[mt][i] = 0.f; }
  }

  for (int tb = 0; tb < 20; tb++) {
    int tt = t0 + tb * 32;
    f4 S[4][2];
    #pragma unroll
    for (int mt = 0; mt < 4; mt++) { S[mt][0] = zero; S[mt][1] = zero; }
    #pragma unroll
    for (int nt = 0; nt < 2; nt++) {
      h8 b0 = *(const h8*)(kh + (size_t)(tt + nt * 16 + r) * 64 + q * 8);
      h8 b1 = *(const h8*)(kh + (size_t)(tt + nt * 16 + r) * 64 + 32 + q * 8);
      #pragma unroll
      for (int mt = 0; mt < 4; mt++) {
        S[mt][nt] = __builtin_amdgcn_mfma_f32_16x16x32_f16(af[mt][0], b0, S[mt][nt], 0, 0, 0);
        S[mt][nt] = __builtin_amdgcn_mfma_f32_16x16x32_f16(af[mt][1], b1, S[mt][nt], 0, 0, 0);
      }
    }
    if (tb == 19) {
      #pragma unroll
      for (int nt = 0; nt < 2; nt++) {
        bool valid = (tb * 32 + nt * 16 + r) < PER;
        #pragma unroll
        for (int mt = 0; mt < 4; mt++)
          #pragma unroll
          for (int i = 0; i < 4; i++)
            S[mt][nt][i] = valid ? S[mt][nt][i] : -1e30f;
      }
    }
    #pragma unroll
    for (int mt = 0; mt < 4; mt++) {
      float nm[4], al[4], ls[4];
      #pragma unroll
      for (int i = 0; i < 4; i++) {
        nm[i] = fmaxf(S[mt][0][i], S[mt][1][i]);
        #pragma unroll
        for (int o = 1; o < 16; o <<= 1) nm[i] = fmaxf(nm[i], __shfl_xor(nm[i], o, 64));
        nm[i] = fmaxf(nm[i], mrun[mt][i]);
        al[i] = __expf(mrun[mt][i] - nm[i]);
        mrun[mt][i] = nm[i];
        float p0 = __expf(S[mt][0][i] - nm[i]);
        float p1 = __expf(S[mt][1][i] - nm[i]);
        S[mt][0][i] = p0; S[mt][1][i] = p1;
        ls[i] = p0 + p1;
        #pragma unroll
        for (int o = 1; o < 16; o <<= 1) ls[i] += __shfl_xor(ls[i], o, 64);
        lrun[mt][i] = lrun[mt][i] * al[i] + ls[i];
      }
      #pragma unroll
      for (int nd = 0; nd < 4; nd++)
        #pragma unroll
        for (int i = 0; i < 4; i++) acc[mt][nd][i] *= al[i];
      #pragma unroll
      for (int nt = 0; nt < 2; nt++)
        #pragma unroll
        for (int i = 0; i < 4; i++)
          Pw[(mt * 16 + q * 4 + i) * 40 + nt * 16 + r] = (_Float16)S[mt][nt][i];
    }
    __syncthreads();
    h8 bv[4];
    #pragma unroll
    for (int nd = 0; nd < 4; nd++)
      bv[nd] = *(const h8*)(vh + (size_t)(nd * 16 + r) * NSEQP + tt + q * 8);
    #pragma unroll
    for (int mt = 0; mt < 4; mt++) {
      h8 ap = *(const h8*)(Pw + (mt * 16 + r) * 40 + q * 8);
      #pragma unroll
      for (int nd = 0; nd < 4; nd++)
        acc[mt][nd] = __builtin_amdgcn_mfma_f32_16x16x32_f16(ap, bv[nd], acc[mt][nd], 0, 0, 0);
    }
    __syncthreads();
  }
  int cidx = h * CHUNKS + c;
  #pragma unroll
  for (int mt = 0; mt < 4; mt++) {
    int rowb = m0 + mt * 16 + q * 4;
    if (r == 0) {
      #pragma unroll
      for (int i = 0; i < 4; i++) {
        pm[(size_t)cidx * MLM + rowb + i] = mrun[mt][i];
        ps[(size_t)cidx * MLM + rowb + i] = lrun[mt][i];
      }
    }
    #pragma unroll
    for (int nd = 0; nd < 4; nd++)
      #pragma unroll
      for (int i = 0; i < 4; i++)
        pacc[((size_t)cidx * MLM + rowb + i) * 64 + nd * 16 + r] = acc[mt][nd][i];
  }
}

__global__ __launch_bounds__(64)
void k_attn3_reduce(const float* __restrict__ pm, const float* __restrict__ ps,
                    const float* __restrict__ pacc, float* __restrict__ av)
{
  int h = blockIdx.x >> 8, i = blockIdx.x & 255;
  int d = threadIdx.x;
  float m = -1e30f;
  for (int c = 0; c < CHUNKS; c++) m = fmaxf(m, pm[(h * CHUNKS + c) * MLM + i]);
  float l = 0.f, a = 0.f;
  for (int c = 0; c < CHUNKS; c++) {
    int idx = (h * CHUNKS + c) * MLM + i;
    float w = __expf(pm[idx] - m);
    l += ps[idx] * w;
    a += pacc[(size_t)idx * DH + d] * w;
  }
  av[((size_t)h * MLM + i) * DH + d] = a / l;
}

// ---------------- depthwise 33-tap conv on v -> xat16 ----------------
__global__ __launch_bounds__(256)
void k_conv(const _Float16* __restrict__ v16, const float* __restrict__ rw,
            _Float16* __restrict__ xat)
{
  __shared__ float tl[160][64];
  int h = blockIdx.y;
  int t0 = PADF + blockIdx.x * 128;
  for (int c = threadIdx.x; c < 160 * 16; c += 256) {
    int row = c >> 4, d4 = (c & 15) * 4;
    int ts = t0 - 16 + row;
    f4 val = {0.f, 0.f, 0.f, 0.f};
    if (ts >= 0 && ts < NSEQ) {
      h4 hv = *(const h4*)(v16 + ((size_t)h * NSEQP + ts) * 64 + d4);
      val[0] = (float)hv[0]; val[1] = (float)hv[1]; val[2] = (float)hv[2]; val[3] = (float)hv[3];
    }
    *(f4*)&tl[row][d4] = val;
  }
  __syncthreads();
  float wt[33];
  #pragma unroll
  for (int tap = 0; tap < 33; tap++) wt[tap] = rw[h * 33 + tap];
  int d4 = (threadIdx.x & 15) * 4, r0 = threadIdx.x >> 4;
  #pragma unroll
  for (int k = 0; k < 8; k++) {
    int r = k * 16 + r0;
    int t = t0 + r;
    f4 acc = {0.f, 0.f, 0.f, 0.f};
    #pragma unroll
    for (int tap = 0; tap < 33; tap++) {
      f4 vv = *(const f4*)&tl[r + tap][d4];
      acc[0] += wt[tap] * vv[0]; acc[1] += wt[tap] * vv[1];
      acc[2] += wt[tap] * vv[2]; acc[3] += wt[tap] * vv[3];
    }
    if (t < NSEQ) {
      h4 o = {(_Float16)acc[0], (_Float16)acc[1], (_Float16)acc[2], (_Float16)acc[3]};
      *(h4*)(xat + (size_t)t * DIMC + h * 64 + d4) = o;
    }
  }
}

// ---------------- MFMA attn1 (S^T trick): xat += softmax(q @ kl16^T) @ w2 ----------------
// kl16 pre-scaled by 0.125. Lane owns one token column of S^T -> softmax needs 2+2 shfls.
__global__ __launch_bounds__(256)
void k_attn1(const _Float16* __restrict__ q16, const _Float16* __restrict__ kl16,
             const _Float16* __restrict__ w2t16, _Float16* __restrict__ xat)
{
  __shared__ __attribute__((aligned(16))) _Float16 qs[64 * 64];      // 8 KB
  __shared__ __attribute__((aligned(16))) _Float16 Pl[4][16 * 264];  // 33.8 KB
  __shared__ float linv_s[4][16];
  int h = blockIdx.y;
  int t0 = PADF + blockIdx.x * 64;
  int tid = threadIdx.x, lane = tid & 63, w = tid >> 6;
  int r = lane & 15, q = lane >> 4;
  // stage 64 q rows
  for (int c = tid; c < 512; c += 256) {
    int row = c >> 3, ch = (c & 7) * 8;
    int t = t0 + row; if (t > NSEQ - 1) t = NSEQ - 1;
    *(h8*)(qs + row * 64 + ch) = *(const h8*)(q16 + ((size_t)h * NSEQP + t) * 64 + ch);
  }
  __syncthreads();
  // B-frag: this wave's token (n = r), k = q*8..q*8+7 (+32)
  h8 bq0 = *(const h8*)(qs + (w * 16 + r) * 64 + q * 8);
  h8 bq1 = *(const h8*)(qs + (w * 16 + r) * 64 + 32 + q * 8);
  const _Float16* klh = kl16 + (size_t)h * MLM * 64;
  const f4 zero = {0.f, 0.f, 0.f, 0.f};
  // S^T: D[m=landmark][n=token]; lane holds token r, landmarks nj*16+q*4+i
  f4 S[16];
  #pragma unroll
  for (int nj = 0; nj < 16; nj++) {
    h8 a0 = *(const h8*)(klh + (size_t)(nj * 16 + r) * 64 + q * 8);
    h8 a1 = *(const h8*)(klh + (size_t)(nj * 16 + r) * 64 + 32 + q * 8);
    f4 s = zero;
    s = __builtin_amdgcn_mfma_f32_16x16x32_f16(a0, bq0, s, 0, 0, 0);
    s = __builtin_amdgcn_mfma_f32_16x16x32_f16(a1, bq1, s, 0, 0, 0);
    S[nj] = s;
  }
  // softmax over the token's 256 scores: 64 local + 4-lane quad reduce
  float mx = -1e30f;
  #pragma unroll
  for (int nj = 0; nj < 16; nj++)
    #pragma unroll
    for (int i = 0; i < 4; i++) mx = fmaxf(mx, S[nj][i]);
  mx = fmaxf(mx, __shfl_xor(mx, 16, 64));
  mx = fmaxf(mx, __shfl_xor(mx, 32, 64));
  float l = 0.f;
  _Float16* Pw = &Pl[w][0];
  #pragma unroll
  for (int nj = 0; nj < 16; nj++) {
    h4 pv;
    #pragma unroll
    for (int i = 0; i < 4; i++) {
      float p = __expf(S[nj][i] - mx);
      l += p;
      pv[i] = (_Float16)p;
    }
    *(h4*)(Pw + r * 264 + nj * 16 + q * 4) = pv;   // P[token r][landmark]
  }
  l += __shfl_xor(l, 16, 64);
  l += __shfl_xor(l, 32, 64);
  if (q == 0) linv_s[w][r] = 1.f / l;
  __syncthreads();
  // PV: out[m=token][n=dim] = P @ w2 ; A=P rows (token), B=w2t16 rows (dim)
  const _Float16* w2h = w2t16 + (size_t)h * 64 * 256;
  f4 o4[4];
  #pragma unroll
  for (int nd = 0; nd < 4; nd++) o4[nd] = zero;
  #pragma unroll
  for (int ks = 0; ks < 8; ks++) {
    h8 ap = *(const h8*)(Pw + r * 264 + ks * 32 + q * 8);
    #pragma unroll
    for (int nd = 0; nd < 4; nd++) {
      h8 bw = *(const h8*)(w2h + (size_t)(nd * 16 + r) * 256 + ks * 32 + q * 8);
      o4[nd] = __builtin_amdgcn_mfma_f32_16x16x32_f16(ap, bw, o4[nd], 0, 0, 0);
    }
  }
  __syncthreads();
  // epilogue: normalize + vectorized accumulate into xat
  float* ow = (float*)Pw;     // 16 x 66 fp32
  float li[4];
  #pragma unroll
  for (int i = 0; i < 4; i++) li[i] = linv_s[w][q * 4 + i];
  #pragma unroll
  for (int nd = 0; nd < 4; nd++)
    #pragma unroll
    for (int i = 0; i < 4; i++)
      ow[(q * 4 + i) * 66 + nd * 16 + r] = o4[nd][i] * li[i];
  __syncthreads();
  #pragma unroll
  for (int c = 0; c < 2; c++) {
    int e = lane + c * 64;
    int row = e >> 3, ch = (e & 7) * 8;
    int t = t0 + w * 16 + row;
    if (t < NSEQ) {
      float* src = ow + row * 66 + ch;
      _Float16* dst = xat + (size_t)t * DIMC + h * 64 + ch;
      h8 cv = *(h8*)dst;
      h8 outv;
      #pragma unroll
      for (int k = 0; k < 8; k++) outv[k] = (_Float16)(src[k] + (float)cv[k]);
      *(h8*)dst = outv;
    }
  }
}

// ---------------- PPEG ----------------
__global__ __launch_bounds__(256)
void k_transpose_fw(const float* __restrict__ h, float* __restrict__ g)
{
  __shared__ float tile[32][33];
  int pb = blockIdx.x * 32, cb = blockIdx.y * 32;
  int x = threadIdx.x & 31, y0 = threadIdx.x >> 5;
  #pragma unroll
  for (int yy = y0; yy < 32; yy += 8)
    tile[yy][x] = h[(size_t)(1 + pb + yy) * DIMC + cb + x];
  __syncthreads();
  #pragma unroll
  for (int yy = y0; yy < 32; yy += 8)
    g[(size_t)(cb + yy) * NPATCH + pb + x] = tile[x][yy];
}

__global__ __launch_bounds__(256)
void k_ppeg(const float* __restrict__ g,
            const float* __restrict__ w7, const float* __restrict__ b7,
            const float* __restrict__ w5, const float* __restrict__ b5,
            const float* __restrict__ w3, const float* __restrict__ b3,
            float* __restrict__ o)
{
  __shared__ float tl[22][22];
  int c = blockIdx.y;
  int ty0 = (blockIdx.x / 13) * 16, tx0 = (blockIdx.x % 13) * 16;
  const float* gc = g + (size_t)c * NPATCH;
  for (int e = threadIdx.x; e < 22 * 22; e += 256) {
    int yy = e / 22, xx = e % 22;
    int y = ty0 - 3 + yy, x = tx0 - 3 + xx;
    tl[yy][xx] = (y >= 0 && y < GRID && x >= 0 && x < GRID) ? gc[y * GRID + x] : 0.f;
  }
  __syncthreads();
  int ly = threadIdx.x >> 4, lx = threadIdx.x & 15;
  int y = ty0 + ly, x = tx0 + lx;
  if (y >= GRID || x >= GRID) return;
  float acc = tl[ly + 3][lx + 3] + b7[c] + b5[c] + b3[c];
  #pragma unroll
  for (int ky = 0; ky < 7; ky++)
    #pragma unroll
    for (int kx = 0; kx < 7; kx++)
      acc += w7[c * 49 + ky * 7 + kx] * tl[ly + ky][lx + kx];
  #pragma unroll
  for (int ky = 0; ky < 5; ky++)
    #pragma unroll
    for (int kx = 0; kx < 5; kx++)
      acc += w5[c * 25 + ky * 5 + kx] * tl[ly + 1 + ky][lx + 1 + kx];
  #pragma unroll
  for (int ky = 0; ky < 3; ky++)
    #pragma unroll
    for (int kx = 0; kx < 3; kx++)
      acc += w3[c * 9 + ky * 3 + kx] * tl[ly + 2 + ky][lx + 2 + kx];
  o[(size_t)c * NPATCH + y * GRID + x] = acc;
}

__global__ __launch_bounds__(256)
void k_transpose_bw(const float* __restrict__ g, float* __restrict__ h)
{
  __shared__ float tile[32][33];
  int pb = blockIdx.x * 32, cb = blockIdx.y * 32;
  int x = threadIdx.x & 31, y0 = threadIdx.x >> 5;
  #pragma unroll
  for (int yy = y0; yy < 32; yy += 8)
    tile[yy][x] = g[(size_t)(cb + yy) * NPATCH + pb + x];
  __syncthreads();
  #pragma unroll
  for (int yy = y0; yy < 32; yy += 8)
    h[(size_t)(1 + pb + yy) * DIMC + cb + x] = tile[x][yy];
}

// ---------------- final: layernorm(row 0) @ fc2 ----------------
__global__ __launch_bounds__(512)
void k_final(const float* __restrict__ h, const float* __restrict__ nw, const float* __restrict__ nb,
             const float* __restrict__ fw, const float* __restrict__ fb, float* __restrict__ out)
{
  __shared__ float sbuf[8];
  int d = threadIdx.x;
  float x = h[d];
  float mu = blkRed<8,false>(x, sbuf) * (1.f / 512.f);
  float dd = x - mu;
  float var = blkRed<8,false>(dd * dd, sbuf) * (1.f / 512.f);
  float cls = dd * rsqrtf(var + 1e-5f) * nw[d] + nb[d];
  float l0 = blkRed<8,false>(cls * fw[d * 2 + 0], sbuf);
  float l1 = blkRed<8,false>(cls * fw[d * 2 + 1], sbuf);
  if (d == 0) { out[0] = l0 + fb[0]; out[1] = l1 + fb[1]; }
}

// ---------------- host orchestration ----------------
struct WsPtrs {
  float *h, *ql, *kl, *a2, *zA, *zB, *xz, *u, *u2, *av, *w2, *hmax, *scal, *pm, *ps, *pacc;
  _Float16 *xat16, *q16, *k16, *v16, *vt16, *ql16, *kl16, *w2t16, *x16;
};

static void attention_layer(const WsPtrs& P,
                            const float* nw, const float* nb, const _Float16* qkvw16,
                            const _Float16* ow16, const float* ob, const float* rw,
                            hipStream_t stream)
{
  k_zpad<<<64, 256, 0, stream>>>(P.q16, P.k16, P.v16);
  k_ln_pad<<<NSEQ, 256, 0, stream>>>(P.h, nw, nb, P.xat16);
  k_gemm16<<<dim3(NSEQ / 128, 1536 / 128), 256, 0, stream>>>(
      P.xat16, qkvw16, nullptr, nullptr, P.q16, P.k16, P.v16, NSEQ, DIMC, 3 * DIMC, 4);
  k_vt<<<dim3(629, HEADS), 256, 0, stream>>>(P.v16, P.vt16);
  k_landmarks<<<HEADS * MLM, 256, 0, stream>>>(P.q16, P.k16, P.ql, P.kl, P.ql16, P.kl16);
  k_attn2<<<HEADS * MLM, 256, 0, stream>>>(P.ql, P.kl, P.a2);
  k_pinv_init1<<<HEADS, 256, 0, stream>>>(P.a2, P.hmax);
  k_pinv_init2<<<1, 1, 0, stream>>>(P.hmax, P.scal);
  k_transpose_scale<<<HEADS * MLM, 256, 0, stream>>>(P.a2, P.scal, P.zA);
  float* z = P.zA; float* zn = P.zB;
  for (int it = 0; it < 6; it++) {
    k_bmm<<<dim3(16, HEADS), 256, 0, stream>>>(P.a2, z,    nullptr, P.xz, MLM, 1.f,   0.f);
    k_bmm<<<dim3(16, HEADS), 256, 0, stream>>>(P.xz, P.xz, P.xz,    P.u,  MLM, -1.f,  7.f);
    k_bmm<<<dim3(16, HEADS), 256, 0, stream>>>(P.xz, P.u,  P.xz,    P.u2, MLM, -1.f,  15.f);
    k_bmm<<<dim3(16, HEADS), 256, 0, stream>>>(z,    P.u2, z,       zn,   MLM, -0.25f, 3.25f);
    float* t = z; z = zn; zn = t;
  }
  k_attn3<<<dim3(CHUNKS, HEADS), 256, 0, stream>>>(P.ql16, P.k16, P.vt16, P.pm, P.ps, P.pacc);
  k_attn3_reduce<<<HEADS * MLM, 64, 0, stream>>>(P.pm, P.ps, P.pacc, P.av);
  k_bmm<<<dim3(4, HEADS), 256, 0, stream>>>(z, P.av, nullptr, P.w2, DH, 1.f, 0.f);
  k_w2t<<<HEADS, 256, 0, stream>>>(P.w2, P.w2t16);
  k_conv<<<dim3(313, HEADS), 256, 0, stream>>>(P.v16, rw, P.xat16);
  k_attn1<<<dim3(626, HEADS), 256, 0, stream>>>(P.q16, P.kl16, P.w2t16, P.xat16);
  k_gemm16<<<dim3((NTOK + 127) / 128, DIMC / 128), 256, 0, stream>>>(
      P.xat16 + (size_t)PADF * DIMC, ow16, ob, P.h, nullptr, nullptr, nullptr, NTOK, DIMC, DIMC, 2);
}

extern "C" void kernel_launch(void* const* d_in, const int* in_sizes, int n_in,
                              void* d_out, int out_size, void* d_ws, size_t ws_size,
                              hipStream_t stream)
{
  const float* x      = (const float*)d_in[0];
  const float* fc1_w  = (const float*)d_in[1];
  const float* fc1_b  = (const float*)d_in[2];
  const float* cls    = (const float*)d_in[3];
  const float* l1_nw  = (const float*)d_in[4];
  const float* l1_nb  = (const float*)d_in[5];
  const float* l1_qkv = (const float*)d_in[6];
  const float* l1_ow  = (const float*)d_in[7];
  const float* l1_ob  = (const float*)d_in[8];
  const float* l1_rw  = (const float*)d_in[9];
  const float* p7w    = (const float*)d_in[10];
  const float* p7b    = (const float*)d_in[11];
  const float* p5w    = (const float*)d_in[12];
  const float* p5b    = (const float*)d_in[13];
  const float* p3w    = (const float*)d_in[14];
  const float* p3b    = (const float*)d_in[15];
  const float* l2_nw  = (const float*)d_in[16];
  const float* l2_nb  = (const float*)d_in[17];
  const float* l2_qkv = (const float*)d_in[18];
  const float* l2_ow  = (const float*)d_in[19];
  const float* l2_ob  = (const float*)d_in[20];
  const float* l2_rw  = (const float*)d_in[21];
  const float* nw     = (const float*)d_in[22];
  const float* nb     = (const float*)d_in[23];
  const float* fc2w   = (const float*)d_in[24];
  const float* fc2b   = (const float*)d_in[25];
  float* out = (float*)d_out;

  // ---- workspace carve-up (float offsets) ----
  float* W = (float*)d_ws;
  WsPtrs P;
  size_t off = 0;
  P.h     = W + off;               off += 20480512ull;   // 40001 x 512 fp32
  P.xat16 = (_Float16*)(W + off);  off += 10289152ull;   // NSEQ x 512 fp16
  float* R0 = W + off;                                   // fp16 q/k/v/vt region
  P.q16   = (_Float16*)R0;
  P.k16   = P.q16 + 20594688ull;   // 8 x 40224 x 64
  P.v16   = P.k16 + 20594688ull;
  P.vt16  = P.v16 + 20594688ull;   // 8 x 64 x 40224
  P.x16   = P.q16;                 // alias: fc1 input fp16 (dead before qkv GEMM)
  off += 41189376ull;              // 4 x 20594688 halfs / 2
  P.ql    = W + off; off += 131072;
  P.kl    = W + off; off += 131072;
  P.ql16  = (_Float16*)(W + off); off += 65536;
  P.kl16  = (_Float16*)(W + off); off += 65536;
  P.a2    = W + off; off += 524288;
  P.zA    = W + off; off += 524288;
  P.zB    = W + off; off += 524288;
  P.xz    = W + off; off += 524288;
  P.u     = W + off; off += 524288;
  P.u2    = W + off; off += 524288;
  P.av    = W + off; off += 131072;
  P.w2    = W + off; off += 131072;
  P.w2t16 = (_Float16*)(W + off); off += 32768;
  P.hmax  = W + off; P.scal = P.hmax + 16; off += 32;
  P.pm    = W + off; off += 131072;
  P.ps    = W + off; off += 131072;
  P.pacc  = W + off; off += 8388608;
  _Float16* fc1t  = (_Float16*)(W + off);   // 512x1024
  _Float16* qkv1t = fc1t  + 524288;         // 1536x512
  _Float16* out1t = qkv1t + 786432;         // 512x512
  _Float16* qkv2t = out1t + 262144;
  _Float16* out2t = qkv2t + 786432;

  // ---- weight fp32 -> fp16 transposed (N x K) ----
  k_wt16<<<dim3(INDIM / 32, DIMC / 32), 256, 0, stream>>>(fc1_w, fc1t, INDIM, DIMC);
  k_wt16<<<dim3(DIMC / 32, 1536 / 32), 256, 0, stream>>>(l1_qkv, qkv1t, DIMC, 1536);
  k_wt16<<<dim3(DIMC / 32, DIMC / 32), 256, 0, stream>>>(l1_ow, out1t, DIMC, DIMC);
  k_wt16<<<dim3(DIMC / 32, 1536 / 32), 256, 0, stream>>>(l2_qkv, qkv2t, DIMC, 1536);
  k_wt16<<<dim3(DIMC / 32, DIMC / 32), 256, 0, stream>>>(l2_ow, out2t, DIMC, DIMC);

  // fc1 + relu -> h rows 1..40000 ; cls token -> h row 0
  k_f32_to_f16<<<NPATCH * INDIM / 1024, 256, 0, stream>>>(x, P.x16);
  k_gemm16<<<dim3((NPATCH + 127) / 128, DIMC / 128), 256, 0, stream>>>(
      P.x16, fc1t, fc1_b, P.h + DIMC, nullptr, nullptr, nullptr, NPATCH, INDIM, DIMC, 1);
  k_set_cls<<<1, 512, 0, stream>>>(cls, P.h);

  // layer 1 attention
  attention_layer(P, l1_nw, l1_nb, qkv1t, out1t, l1_ob, l1_rw, stream);

  // PPEG (aliases the q/k/v fp16 region as fp32 scratch)
  float* fgrid = R0;
  float* cout  = R0 + 20480000ull;
  k_transpose_fw<<<dim3(NPATCH / 32, DIMC / 32), 256, 0, stream>>>(P.h, fgrid);
  k_ppeg<<<dim3(13 * 13, DIMC), 256, 0, stream>>>(fgrid, p7w, p7b, p5w, p5b, p3w, p3b, cout);
  k_transpose_bw<<<dim3(NPATCH / 32, DIMC / 32), 256, 0, stream>>>(cout, P.h);

  // layer 2 attention
  attention_layer(P, l2_nw, l2_nb, qkv2t, out2t, l2_ob, l2_rw, stream);

  // final layernorm (cls row only) + fc2
  k_final<<<1, 512, 0, stream>>>(P.h, nw, nb, fc2w, fc2b, out);
}

// Round 5
// 2665.567 us; speedup vs baseline: 4.1222x; 1.4604x over previous
//
#include <hip/hip_runtime.h>
#include <hip/hip_bf16.h>

// ---------------- problem constants ----------------
#define DIMC   512
#define HEADS  8
#define DH     64
#define MLM    256          // landmarks
#define NPATCH 40000
#define NTOK   40001        // with cls
#define PADF   191          // front zero pad
#define NSEQ   40192        // NTOK + PADF
#define NSEQP  40224        // NSEQ + 32 (zero pad for flash tiles)
#define LWIN   157          // NSEQ / MLM
#define INDIM  1024
#define GRID   200
#define CHUNKS 64
#define PER    628          // NSEQ / CHUNKS

typedef _Float16 h8 __attribute__((ext_vector_type(8)));
typedef _Float16 h4 __attribute__((ext_vector_type(4)));
typedef float    f4 __attribute__((ext_vector_type(4)));

// async global->LDS, 16B per lane; LDS dest = wave-uniform base + lane*16
__device__ __forceinline__ void gl_lds(const _Float16* g, _Float16* l) {
  __builtin_amdgcn_global_load_lds(
      (const __attribute__((address_space(1))) void*)g,
      (__attribute__((address_space(3))) void*)l, 16, 0, 0);
}

// ---------------- reductions ----------------
template<int NW, bool ISMAX>
__device__ __forceinline__ float blkRed(float v, float* s) {
  #pragma unroll
  for (int o = 32; o; o >>= 1) {
    float t = __shfl_down(v, o, 64);
    v = ISMAX ? fmaxf(v, t) : v + t;
  }
  int lane = threadIdx.x & 63, w = threadIdx.x >> 6;
  __syncthreads();
  if (lane == 0) s[w] = v;
  __syncthreads();
  float r = s[0];
  #pragma unroll
  for (int i = 1; i < NW; i++) r = ISMAX ? fmaxf(r, s[i]) : r + s[i];
  return r;
}

// ---------------- misc small kernels ----------------
__global__ __launch_bounds__(512)
void k_set_cls(const float* __restrict__ cls, float* __restrict__ h) {
  h[threadIdx.x] = cls[threadIdx.x];
}

__global__ __launch_bounds__(256)
void k_f32_to_f16(const float* __restrict__ in, _Float16* __restrict__ out) {
  int i = blockIdx.x * 256 + threadIdx.x;
  float4 v = ((const float4*)in)[i];
  h4 o = {(_Float16)v.x, (_Float16)v.y, (_Float16)v.z, (_Float16)v.w};
  *(h4*)(out + (size_t)i * 4) = o;
}

// zero the 32-row pads of q16/k16/v16 (8 heads x 32 rows x 64)
__global__ __launch_bounds__(256)
void k_zpad(_Float16* q16, _Float16* k16, _Float16* v16) {
  int idx = blockIdx.x * 256 + threadIdx.x;       // 16384 total
  int h = idx >> 11, r = (idx >> 6) & 31, d = idx & 63;
  size_t a = ((size_t)h * NSEQP + NSEQ + r) * 64 + d;
  q16[a] = (_Float16)0.f; k16[a] = (_Float16)0.f; v16[a] = (_Float16)0.f;
}

// weight K x N fp32 -> transposed N x K fp16
__global__ __launch_bounds__(256)
void k_wt16(const float* __restrict__ B, _Float16* __restrict__ Bt, int K, int N)
{
  __shared__ float tile[32][33];
  int kb = blockIdx.x * 32, nb = blockIdx.y * 32;
  int x = threadIdx.x & 31, y0 = threadIdx.x >> 5;
  #pragma unroll
  for (int yy = y0; yy < 32; yy += 8)
    tile[yy][x] = B[(size_t)(kb + yy) * N + nb + x];
  __syncthreads();
  #pragma unroll
  for (int yy = y0; yy < 32; yy += 8)
    Bt[(size_t)(nb + yy) * K + kb + x] = (_Float16)tile[x][yy];
}

// ---------------- fp16 MFMA GEMM (global_load_lds staging, m97-style) ----------------
// flags: 1 = relu, 2 = accumulate into C, 4 = qkv scatter store (fp16 head-major)
__global__ __launch_bounds__(256)
void k_gemm16(const _Float16* __restrict__ A, const _Float16* __restrict__ Bt,
              const float* __restrict__ bias, float* __restrict__ C,
              _Float16* __restrict__ q16, _Float16* __restrict__ k16, _Float16* __restrict__ v16,
              int Mr, int K, int N, int flags)
{
  __shared__ __attribute__((aligned(16))) _Float16 As[128 * 32];
  __shared__ __attribute__((aligned(16))) _Float16 Bs[128 * 32];
  int bm = blockIdx.x * 128, bn = blockIdx.y * 128;
  int t = threadIdx.x;
  int lane = t & 63, w = t >> 6;
  int wm = (w >> 1) * 64, wn = (w & 1) * 64;
  int r = lane & 15, q = lane >> 4;
  int sub = lane >> 2;            // row within 16-row staging group
  int kq = (lane & 3) * 8;        // col (halves) within row

  const f4 zero = {0.f, 0.f, 0.f, 0.f};
  f4 acc[4][4];
  #pragma unroll
  for (int mi = 0; mi < 4; mi++)
    #pragma unroll
    for (int nj = 0; nj < 4; nj++) acc[mi][nj] = zero;

  for (int k0 = 0; k0 < K; k0 += 32) {
    #pragma unroll
    for (int c = 0; c < 2; c++) {
      int rowA = (w * 2 + c) * 16 + sub;
      int gmA = bm + rowA; if (gmA > Mr - 1) gmA = Mr - 1;
      gl_lds(A  + (size_t)gmA * K + k0 + kq,          As + (w * 2 + c) * 512);
      gl_lds(Bt + (size_t)(bn + rowA) * K + k0 + kq,  Bs + (w * 2 + c) * 512);
    }
    __syncthreads();
    h8 af[4], bf[4];
    #pragma unroll
    for (int i = 0; i < 4; i++) {
      af[i] = *(const h8*)(As + (wm + i * 16 + r) * 32 + q * 8);
      bf[i] = *(const h8*)(Bs + (wn + i * 16 + r) * 32 + q * 8);
    }
    #pragma unroll
    for (int mi = 0; mi < 4; mi++)
      #pragma unroll
      for (int nj = 0; nj < 4; nj++)
        acc[mi][nj] = __builtin_amdgcn_mfma_f32_16x16x32_f16(af[mi], bf[nj], acc[mi][nj], 0, 0, 0);
    __syncthreads();
  }
  #pragma unroll
  for (int mi = 0; mi < 4; mi++) {
    #pragma unroll
    for (int i = 0; i < 4; i++) {
      int gm = bm + wm + mi * 16 + q * 4 + i;
      if (gm >= Mr) continue;
      #pragma unroll
      for (int nj = 0; nj < 4; nj++) {
        int gn = bn + wn + nj * 16 + r;
        float v = acc[mi][nj][i];
        if (flags & 4) {
          int which = gn >> 9, hh = (gn >> 6) & 7, dd = gn & 63;
          _Float16* dst = (which == 0) ? q16 : (which == 1) ? k16 : v16;
          dst[((size_t)hh * NSEQP + gm) * 64 + dd] = (_Float16)v;
        } else {
          if (bias) v += bias[gn];
          if (flags & 2) v += C[(size_t)gm * N + gn];
          if (flags & 1) v = fmaxf(v, 0.f);
          C[(size_t)gm * N + gn] = v;
        }
      }
    }
  }
}

// ---------------- layernorm + front zero pad (fp16 out) ----------------
__global__ __launch_bounds__(256)
void k_ln_pad(const float* __restrict__ h, const float* __restrict__ w,
              const float* __restrict__ b, _Float16* __restrict__ xln)
{
  __shared__ float sbuf[8];
  int t = blockIdx.x;
  int tid = threadIdx.x;
  _Float16* out = xln + (size_t)t * DIMC;
  if (t < PADF) { out[tid] = (_Float16)0.f; out[tid + 256] = (_Float16)0.f; return; }
  const float* row = h + (size_t)(t - PADF) * DIMC;
  float x0 = row[tid], x1 = row[tid + 256];
  float mu = blkRed<4,false>(x0 + x1, sbuf) * (1.f / 512.f);
  float d0 = x0 - mu, d1 = x1 - mu;
  float var = blkRed<4,false>(d0 * d0 + d1 * d1, sbuf) * (1.f / 512.f);
  float rstd = rsqrtf(var + 1e-5f);
  out[tid]       = (_Float16)(d0 * rstd * w[tid]       + b[tid]);
  out[tid + 256] = (_Float16)(d1 * rstd * w[tid + 256] + b[tid + 256]);
}

// ---------------- v16 [h][t][64] -> vt16 [h][64][NSEQP] transpose ----------------
__global__ __launch_bounds__(256)
void k_vt(const _Float16* __restrict__ v16, _Float16* __restrict__ vt16)
{
  __shared__ _Float16 tl[64][72];
  int h = blockIdx.y;
  int t0 = blockIdx.x * 64;
  for (int c = threadIdx.x; c < 512; c += 256) {
    int row = c >> 3, ch = (c & 7) * 8;
    h8 v = {};
    if (t0 + row < NSEQP)
      v = *(const h8*)(v16 + ((size_t)h * NSEQP + t0 + row) * 64 + ch);
    *(h8*)&tl[row][ch] = v;
  }
  __syncthreads();
  int d = threadIdx.x & 63, tg = (threadIdx.x >> 6) * 16;
  if (t0 + tg < NSEQP) {
    _Float16 tmp[16];
    #pragma unroll
    for (int k = 0; k < 16; k++) tmp[k] = tl[tg + k][d];
    *(h8*)(vt16 + ((size_t)h * 64 + d) * NSEQP + t0 + tg)     = *(h8*)tmp;
    *(h8*)(vt16 + ((size_t)h * 64 + d) * NSEQP + t0 + tg + 8) = *(h8*)(tmp + 8);
  }
}

// ---------------- landmarks from fp16 q/k ----------------
__global__ __launch_bounds__(256)
void k_landmarks(const _Float16* __restrict__ q16, const _Float16* __restrict__ k16,
                 float* __restrict__ ql, float* __restrict__ kl,
                 _Float16* __restrict__ ql16, _Float16* __restrict__ kl16)
{
  __shared__ float red[2][16][64];
  int h = blockIdx.x >> 8, i = blockIdx.x & 255;
  int jg = threadIdx.x >> 4, d4 = (threadIdx.x & 15) * 4;
  const _Float16* qb = q16 + ((size_t)h * NSEQP + i * LWIN) * 64;
  const _Float16* kb = k16 + ((size_t)h * NSEQP + i * LWIN) * 64;
  float sq[4] = {}, sk[4] = {};
  for (int j = jg; j < LWIN; j += 16) {
    h4 qv = *(const h4*)(qb + j * 64 + d4);
    h4 kv = *(const h4*)(kb + j * 64 + d4);
    #pragma unroll
    for (int c = 0; c < 4; c++) { sq[c] += (float)qv[c]; sk[c] += (float)kv[c]; }
  }
  #pragma unroll
  for (int c = 0; c < 4; c++) { red[0][jg][d4 + c] = sq[c]; red[1][jg][d4 + c] = sk[c]; }
  __syncthreads();
  if (threadIdx.x < 64) {
    int d = threadIdx.x;
    float aq = 0.f, ak = 0.f;
    #pragma unroll
    for (int g = 0; g < 16; g++) { aq += red[0][g][d]; ak += red[1][g][d]; }
    aq *= (0.125f / (float)LWIN);
    ak *= (1.f / (float)LWIN);
    size_t o = ((size_t)h * MLM + i) * DH + d;
    ql[o] = aq; kl[o] = ak;
    ql16[o] = (_Float16)aq;
    kl16[o] = (_Float16)(ak * 0.125f);   // fold q-scale for attn1
  }
}

// ---------------- attn2 = softmax(q_l @ k_l^T) ----------------
__global__ __launch_bounds__(256)
void k_attn2(const float* __restrict__ ql, const float* __restrict__ kl, float* __restrict__ a2)
{
  __shared__ float qrow[DH];
  __shared__ float sbuf[8];
  int h = blockIdx.x >> 8, i = blockIdx.x & 255;
  int j = threadIdx.x;
  if (j < DH) qrow[j] = ql[(h * MLM + i) * DH + j];
  __syncthreads();
  const float* krow = kl + (size_t)(h * MLM + j) * DH;
  float s = 0.f;
  #pragma unroll 16
  for (int d = 0; d < DH; d++) s += qrow[d] * krow[d];
  float mx = blkRed<4,true>(s, sbuf);
  float e = __expf(s - mx);
  float sum = blkRed<4,false>(e, sbuf);
  a2[((size_t)h * MLM + i) * MLM + j] = e / sum;
}

// ---------------- pinv init ----------------
__global__ __launch_bounds__(256)
void k_pinv_init1(const float* __restrict__ a2, float* __restrict__ hmax)
{
  __shared__ float sbuf[8];
  int h = blockIdx.x;
  int j = threadIdx.x;
  const float* A = a2 + (size_t)h * MLM * MLM;
  float cs = 0.f, rs = 0.f;
  for (int i = 0; i < MLM; i++) cs += A[i * MLM + j];
  for (int k = 0; k < MLM; k++) rs += A[j * MLM + k];
  float rmax = blkRed<4,true>(rs, sbuf);
  float cmax = blkRed<4,true>(cs, sbuf);
  if (j == 0) { hmax[h * 2] = rmax; hmax[h * 2 + 1] = cmax; }
}

__global__ void k_pinv_init2(const float* __restrict__ hmax, float* __restrict__ scal)
{
  float rm = 0.f, cm = 0.f;
  for (int h = 0; h < HEADS; h++) { rm = fmaxf(rm, hmax[2*h]); cm = fmaxf(cm, hmax[2*h+1]); }
  scal[0] = 1.f / (rm * cm);
}

// ---------------- pinv prep: a2 fp32 -> pair arrays; z0 = scal*a2^T (pairs, both layouts) ----------------
// a2P: [h][i][j] pairs ; z: [h][j][i] pairs (= scal*a2^T) ; zT: [h][i][j] pairs (= scal*a2)
__global__ __launch_bounds__(256)
void k_pinv_prep(const float* __restrict__ a2, const float* __restrict__ scal,
                 _Float16* __restrict__ a2h, _Float16* __restrict__ a2l,
                 _Float16* __restrict__ zh,  _Float16* __restrict__ zl,
                 _Float16* __restrict__ zth, _Float16* __restrict__ ztl)
{
  __shared__ float tl[64][65];
  int h = blockIdx.x >> 4, tile = blockIdx.x & 15;
  int ti = (tile >> 2) * 64, tj = (tile & 3) * 64;
  float s = scal[0];
  int row = threadIdx.x >> 4, c4 = (threadIdx.x & 15) * 4;
  #pragma unroll
  for (int rr = 0; rr < 4; rr++) {
    int rloc = rr * 16 + row;
    f4 v = *(const f4*)(a2 + ((size_t)h * MLM + ti + rloc) * MLM + tj + c4);
    h4 hi, lo, zhi, zlo;
    #pragma unroll
    for (int c = 0; c < 4; c++) {
      hi[c] = (_Float16)v[c];
      lo[c] = (_Float16)(v[c] - (float)hi[c]);
      float zv = v[c] * s;
      zhi[c] = (_Float16)zv;
      zlo[c] = (_Float16)(zv - (float)zhi[c]);
      tl[rloc][c4 + c] = zv;
    }
    size_t idx = ((size_t)h * MLM + ti + rloc) * MLM + tj + c4;
    *(h4*)(a2h + idx) = hi;  *(h4*)(a2l + idx) = lo;
    *(h4*)(zth + idx) = zhi; *(h4*)(ztl + idx) = zlo;
  }
  __syncthreads();
  // z[tj+r][ti+c] = tl[c][r]
  #pragma unroll
  for (int rr = 0; rr < 4; rr++) {
    int rloc = rr * 16 + row;
    h4 hi, lo;
    #pragma unroll
    for (int c = 0; c < 4; c++) {
      float zv = tl[c4 + c][rloc];
      hi[c] = (_Float16)zv;
      lo[c] = (_Float16)(zv - (float)hi[c]);
    }
    size_t idx = ((size_t)h * MLM + tj + rloc) * MLM + ti + c4;
    *(h4*)(zh + idx) = hi; *(h4*)(zl + idx) = lo;
  }
}

// ---------------- split-fp16 pair MFMA bmm ----------------
// C = c0*(A@B) + c1*E, all 256xN per head, fp32-class precision via hi/lo pairs.
// A pairs [h][256][256]; Bt pairs [h][N][256] (B transposed); E pairs [h][256][N] (or null).
// Outputs C pairs [h][256][N] AND C^T pairs [h][N][256].
__global__ __launch_bounds__(256)
void k_pbmm(const _Float16* __restrict__ Ah, const _Float16* __restrict__ Al,
            const _Float16* __restrict__ Bth, const _Float16* __restrict__ Btl,
            const _Float16* __restrict__ Eh, const _Float16* __restrict__ El,
            _Float16* __restrict__ Ch,  _Float16* __restrict__ Cl,
            _Float16* __restrict__ Cth, _Float16* __restrict__ Ctl,
            int N, float c0, float c1)
{
  __shared__ __attribute__((aligned(16))) _Float16 Ash[64 * 32];
  __shared__ __attribute__((aligned(16))) _Float16 Asl[64 * 32];
  __shared__ __attribute__((aligned(16))) _Float16 Bsh[64 * 32];
  __shared__ __attribute__((aligned(16))) _Float16 Bsl[64 * 32];
  int tn = N >> 6;
  int bm = (blockIdx.x / tn) * 64, bn = (blockIdx.x % tn) * 64;
  int h = blockIdx.y;
  int tid = threadIdx.x, lane = tid & 63, w = tid >> 6;
  int wm = (w >> 1) * 32, wn = (w & 1) * 32;
  int r = lane & 15, q = lane >> 4;
  int sub = lane >> 2, kq = (lane & 3) * 8;

  const _Float16* Ahb = Ah + ((size_t)h * MLM + bm) * MLM;
  const _Float16* Alb = Al + ((size_t)h * MLM + bm) * MLM;
  const _Float16* Bhb = Bth + ((size_t)h * N + bn) * MLM;
  const _Float16* Blb = Btl + ((size_t)h * N + bn) * MLM;

  const f4 zero = {0.f, 0.f, 0.f, 0.f};
  f4 acc[2][2];
  #pragma unroll
  for (int mi = 0; mi < 2; mi++)
    #pragma unroll
    for (int nj = 0; nj < 2; nj++) acc[mi][nj] = zero;

  for (int k0 = 0; k0 < MLM; k0 += 32) {
    int rw = w * 16 + sub;
    gl_lds(Ahb + (size_t)rw * MLM + k0 + kq, Ash + w * 512);
    gl_lds(Alb + (size_t)rw * MLM + k0 + kq, Asl + w * 512);
    gl_lds(Bhb + (size_t)rw * MLM + k0 + kq, Bsh + w * 512);
    gl_lds(Blb + (size_t)rw * MLM + k0 + kq, Bsl + w * 512);
    __syncthreads();
    h8 afh[2], afl[2], bfh[2], bfl[2];
    #pragma unroll
    for (int i = 0; i < 2; i++) {
      afh[i] = *(const h8*)(Ash + (wm + i * 16 + r) * 32 + q * 8);
      afl[i] = *(const h8*)(Asl + (wm + i * 16 + r) * 32 + q * 8);
      bfh[i] = *(const h8*)(Bsh + (wn + i * 16 + r) * 32 + q * 8);
      bfl[i] = *(const h8*)(Bsl + (wn + i * 16 + r) * 32 + q * 8);
    }
    #pragma unroll
    for (int mi = 0; mi < 2; mi++)
      #pragma unroll
      for (int nj = 0; nj < 2; nj++) {
        acc[mi][nj] = __builtin_amdgcn_mfma_f32_16x16x32_f16(afh[mi], bfh[nj], acc[mi][nj], 0, 0, 0);
        acc[mi][nj] = __builtin_amdgcn_mfma_f32_16x16x32_f16(afh[mi], bfl[nj], acc[mi][nj], 0, 0, 0);
        acc[mi][nj] = __builtin_amdgcn_mfma_f32_16x16x32_f16(afl[mi], bfh[nj], acc[mi][nj], 0, 0, 0);
      }
    __syncthreads();
  }
  #pragma unroll
  for (int mi = 0; mi < 2; mi++) {
    #pragma unroll
    for (int i = 0; i < 4; i++) {
      int gm = bm + wm + mi * 16 + q * 4 + i;
      #pragma unroll
      for (int nj = 0; nj < 2; nj++) {
        int gn = bn + wn + nj * 16 + r;
        size_t ide = ((size_t)h * MLM + gm) * N + gn;
        float v = c0 * acc[mi][nj][i];
        if (Eh) v += c1 * ((float)Eh[ide] + (float)El[ide]);
        _Float16 hi = (_Float16)v;
        _Float16 lo = (_Float16)(v - (float)hi);
        Ch[ide] = hi; Cl[ide] = lo;
        size_t idt = ((size_t)h * N + gn) * MLM + gm;
        Cth[idt] = hi; Ctl[idt] = lo;
      }
    }
  }
}

// ---------------- flash attn3: partials of softmax(ql @ k^T) @ v ----------------
__global__ __launch_bounds__(256)
void k_attn3(const _Float16* __restrict__ ql16, const _Float16* __restrict__ k16,
             const _Float16* __restrict__ vt16,
             float* __restrict__ pm, float* __restrict__ ps, float* __restrict__ pacc)
{
  __shared__ __attribute__((aligned(16))) _Float16 Pl[4][64 * 40];
  int c = blockIdx.x, h = blockIdx.y;
  int tid = threadIdx.x, lane = tid & 63, w = tid >> 6;
  int r = lane & 15, q = lane >> 4;
  int t0 = c * PER;
  int m0 = w * 64;
  const _Float16* qlh = ql16 + (size_t)h * MLM * 64;
  const _Float16* kh  = k16  + (size_t)h * NSEQP * 64;
  const _Float16* vh  = vt16 + (size_t)h * 64 * NSEQP;
  _Float16* Pw = &Pl[w][0];

  h8 af[4][2];
  #pragma unroll
  for (int mt = 0; mt < 4; mt++)
    #pragma unroll
    for (int ks = 0; ks < 2; ks++)
      af[mt][ks] = *(const h8*)(qlh + (size_t)(m0 + mt * 16 + r) * 64 + ks * 32 + q * 8);

  const f4 zero = {0.f, 0.f, 0.f, 0.f};
  f4 acc[4][4];
  float mrun[4][4], lrun[4][4];
  #pragma unroll
  for (int mt = 0; mt < 4; mt++) {
    #pragma unroll
    for (int nd = 0; nd < 4; nd++) acc[mt][nd] = zero;
    #pragma unroll
    for (int i = 0; i < 4; i++) { mrun[mt][i] = -1e30f; lrun[mt][i] = 0.f; }
  }

  for (int tb = 0; tb < 20; tb++) {
    int tt = t0 + tb * 32;
    f4 S[4][2];
    #pragma unroll
    for (int mt = 0; mt < 4; mt++) { S[mt][0] = zero; S[mt][1] = zero; }
    #pragma unroll
    for (int nt = 0; nt < 2; nt++) {
      h8 b0 = *(const h8*)(kh + (size_t)(tt + nt * 16 + r) * 64 + q * 8);
      h8 b1 = *(const h8*)(kh + (size_t)(tt + nt * 16 + r) * 64 + 32 + q * 8);
      #pragma unroll
      for (int mt = 0; mt < 4; mt++) {
        S[mt][nt] = __builtin_amdgcn_mfma_f32_16x16x32_f16(af[mt][0], b0, S[mt][nt], 0, 0, 0);
        S[mt][nt] = __builtin_amdgcn_mfma_f32_16x16x32_f16(af[mt][1], b1, S[mt][nt], 0, 0, 0);
      }
    }
    if (tb == 19) {
      #pragma unroll
      for (int nt = 0; nt < 2; nt++) {
        bool valid = (tb * 32 + nt * 16 + r) < PER;
        #pragma unroll
        for (int mt = 0; mt < 4; mt++)
          #pragma unroll
          for (int i = 0; i < 4; i++)
            S[mt][nt][i] = valid ? S[mt][nt][i] : -1e30f;
      }
    }
    #pragma unroll
    for (int mt = 0; mt < 4; mt++) {
      float nm[4], al[4], ls[4];
      #pragma unroll
      for (int i = 0; i < 4; i++) {
        nm[i] = fmaxf(S[mt][0][i], S[mt][1][i]);
        #pragma unroll
        for (int o = 1; o < 16; o <<= 1) nm[i] = fmaxf(nm[i], __shfl_xor(nm[i], o, 64));
        nm[i] = fmaxf(nm[i], mrun[mt][i]);
        al[i] = __expf(mrun[mt][i] - nm[i]);
        mrun[mt][i] = nm[i];
        float p0 = __expf(S[mt][0][i] - nm[i]);
        float p1 = __expf(S[mt][1][i] - nm[i]);
        S[mt][0][i] = p0; S[mt][1][i] = p1;
        ls[i] = p0 + p1;
        #pragma unroll
        for (int o = 1; o < 16; o <<= 1) ls[i] += __shfl_xor(ls[i], o, 64);
        lrun[mt][i] = lrun[mt][i] * al[i] + ls[i];
      }
      #pragma unroll
      for (int nd = 0; nd < 4; nd++)
        #pragma unroll
        for (int i = 0; i < 4; i++) acc[mt][nd][i] *= al[i];
      #pragma unroll
      for (int nt = 0; nt < 2; nt++)
        #pragma unroll
        for (int i = 0; i < 4; i++)
          Pw[(mt * 16 + q * 4 + i) * 40 + nt * 16 + r] = (_Float16)S[mt][nt][i];
    }
    __syncthreads();
    h8 bv[4];
    #pragma unroll
    for (int nd = 0; nd < 4; nd++)
      bv[nd] = *(const h8*)(vh + (size_t)(nd * 16 + r) * NSEQP + tt + q * 8);
    #pragma unroll
    for (int mt = 0; mt < 4; mt++) {
      h8 ap = *(const h8*)(Pw + (mt * 16 + r) * 40 + q * 8);
      #pragma unroll
      for (int nd = 0; nd < 4; nd++)
        acc[mt][nd] = __builtin_amdgcn_mfma_f32_16x16x32_f16(ap, bv[nd], acc[mt][nd], 0, 0, 0);
    }
    __syncthreads();
  }
  int cidx = h * CHUNKS + c;
  #pragma unroll
  for (int mt = 0; mt < 4; mt++) {
    int rowb = m0 + mt * 16 + q * 4;
    if (r == 0) {
      #pragma unroll
      for (int i = 0; i < 4; i++) {
        pm[(size_t)cidx * MLM + rowb + i] = mrun[mt][i];
        ps[(size_t)cidx * MLM + rowb + i] = lrun[mt][i];
      }
    }
    #pragma unroll
    for (int nd = 0; nd < 4; nd++)
      #pragma unroll
      for (int i = 0; i < 4; i++)
        pacc[((size_t)cidx * MLM + rowb + i) * 64 + nd * 16 + r] = acc[mt][nd][i];
  }
}

// reduce partials -> avT pairs [h][64][256]
__global__ __launch_bounds__(64)
void k_attn3_reduce(const float* __restrict__ pm, const float* __restrict__ ps,
                    const float* __restrict__ pacc,
                    _Float16* __restrict__ avth, _Float16* __restrict__ avtl)
{
  int h = blockIdx.x >> 8, i = blockIdx.x & 255;
  int d = threadIdx.x;
  float m = -1e30f;
  for (int c = 0; c < CHUNKS; c++) m = fmaxf(m, pm[(h * CHUNKS + c) * MLM + i]);
  float l = 0.f, a = 0.f;
  for (int c = 0; c < CHUNKS; c++) {
    int idx = (h * CHUNKS + c) * MLM + i;
    float w = __expf(pm[idx] - m);
    l += ps[idx] * w;
    a += pacc[(size_t)idx * DH + d] * w;
  }
  float v = a / l;
  _Float16 hi = (_Float16)v;
  size_t o = ((size_t)h * DH + d) * MLM + i;
  avth[o] = hi;
  avtl[o] = (_Float16)(v - (float)hi);
}

// ---------------- depthwise 33-tap conv on v -> xat16 ----------------
__global__ __launch_bounds__(256)
void k_conv(const _Float16* __restrict__ v16, const float* __restrict__ rw,
            _Float16* __restrict__ xat)
{
  __shared__ float tl[160][64];
  int h = blockIdx.y;
  int t0 = PADF + blockIdx.x * 128;
  for (int c = threadIdx.x; c < 160 * 16; c += 256) {
    int row = c >> 4, d4 = (c & 15) * 4;
    int ts = t0 - 16 + row;
    f4 val = {0.f, 0.f, 0.f, 0.f};
    if (ts >= 0 && ts < NSEQ) {
      h4 hv = *(const h4*)(v16 + ((size_t)h * NSEQP + ts) * 64 + d4);
      val[0] = (float)hv[0]; val[1] = (float)hv[1]; val[2] = (float)hv[2]; val[3] = (float)hv[3];
    }
    *(f4*)&tl[row][d4] = val;
  }
  __syncthreads();
  float wt[33];
  #pragma unroll
  for (int tap = 0; tap < 33; tap++) wt[tap] = rw[h * 33 + tap];
  int d4 = (threadIdx.x & 15) * 4, r0 = threadIdx.x >> 4;
  #pragma unroll
  for (int k = 0; k < 8; k++) {
    int r = k * 16 + r0;
    int t = t0 + r;
    f4 acc = {0.f, 0.f, 0.f, 0.f};
    #pragma unroll
    for (int tap = 0; tap < 33; tap++) {
      f4 vv = *(const f4*)&tl[r + tap][d4];
      acc[0] += wt[tap] * vv[0]; acc[1] += wt[tap] * vv[1];
      acc[2] += wt[tap] * vv[2]; acc[3] += wt[tap] * vv[3];
    }
    if (t < NSEQ) {
      h4 o = {(_Float16)acc[0], (_Float16)acc[1], (_Float16)acc[2], (_Float16)acc[3]};
      *(h4*)(xat + (size_t)t * DIMC + h * 64 + d4) = o;
    }
  }
}

// ---------------- MFMA attn1 (S^T trick): xat += softmax(q @ kl16^T) @ w2 ----------------
__global__ __launch_bounds__(256)
void k_attn1(const _Float16* __restrict__ q16, const _Float16* __restrict__ kl16,
             const _Float16* __restrict__ w2t16, _Float16* __restrict__ xat)
{
  __shared__ __attribute__((aligned(16))) _Float16 qs[64 * 64];      // 8 KB
  __shared__ __attribute__((aligned(16))) _Float16 Pl[4][16 * 264];  // 33.8 KB
  __shared__ float linv_s[4][16];
  int h = blockIdx.y;
  int t0 = PADF + blockIdx.x * 64;
  int tid = threadIdx.x, lane = tid & 63, w = tid >> 6;
  int r = lane & 15, q = lane >> 4;
  for (int c = tid; c < 512; c += 256) {
    int row = c >> 3, ch = (c & 7) * 8;
    int t = t0 + row; if (t > NSEQ - 1) t = NSEQ - 1;
    *(h8*)(qs + row * 64 + ch) = *(const h8*)(q16 + ((size_t)h * NSEQP + t) * 64 + ch);
  }
  __syncthreads();
  h8 bq0 = *(const h8*)(qs + (w * 16 + r) * 64 + q * 8);
  h8 bq1 = *(const h8*)(qs + (w * 16 + r) * 64 + 32 + q * 8);
  const _Float16* klh = kl16 + (size_t)h * MLM * 64;
  const f4 zero = {0.f, 0.f, 0.f, 0.f};
  f4 S[16];
  #pragma unroll
  for (int nj = 0; nj < 16; nj++) {
    h8 a0 = *(const h8*)(klh + (size_t)(nj * 16 + r) * 64 + q * 8);
    h8 a1 = *(const h8*)(klh + (size_t)(nj * 16 + r) * 64 + 32 + q * 8);
    f4 s = zero;
    s = __builtin_amdgcn_mfma_f32_16x16x32_f16(a0, bq0, s, 0, 0, 0);
    s = __builtin_amdgcn_mfma_f32_16x16x32_f16(a1, bq1, s, 0, 0, 0);
    S[nj] = s;
  }
  float mx = -1e30f;
  #pragma unroll
  for (int nj = 0; nj < 16; nj++)
    #pragma unroll
    for (int i = 0; i < 4; i++) mx = fmaxf(mx, S[nj][i]);
  mx = fmaxf(mx, __shfl_xor(mx, 16, 64));
  mx = fmaxf(mx, __shfl_xor(mx, 32, 64));
  float l = 0.f;
  _Float16* Pw = &Pl[w][0];
  #pragma unroll
  for (int nj = 0; nj < 16; nj++) {
    h4 pv;
    #pragma unroll
    for (int i = 0; i < 4; i++) {
      float p = __expf(S[nj][i] - mx);
      l += p;
      pv[i] = (_Float16)p;
    }
    *(h4*)(Pw + r * 264 + nj * 16 + q * 4) = pv;
  }
  l += __shfl_xor(l, 16, 64);
  l += __shfl_xor(l, 32, 64);
  if (q == 0) linv_s[w][r] = 1.f / l;
  __syncthreads();
  const _Float16* w2h = w2t16 + (size_t)h * 64 * 256;
  f4 o4[4];
  #pragma unroll
  for (int nd = 0; nd < 4; nd++) o4[nd] = zero;
  #pragma unroll
  for (int ks = 0; ks < 8; ks++) {
    h8 ap = *(const h8*)(Pw + r * 264 + ks * 32 + q * 8);
    #pragma unroll
    for (int nd = 0; nd < 4; nd++) {
      h8 bw = *(const h8*)(w2h + (size_t)(nd * 16 + r) * 256 + ks * 32 + q * 8);
      o4[nd] = __builtin_amdgcn_mfma_f32_16x16x32_f16(ap, bw, o4[nd], 0, 0, 0);
    }
  }
  __syncthreads();
  float* ow = (float*)Pw;     // 16 x 66 fp32
  float li[4];
  #pragma unroll
  for (int i = 0; i < 4; i++) li[i] = linv_s[w][q * 4 + i];
  #pragma unroll
  for (int nd = 0; nd < 4; nd++)
    #pragma unroll
    for (int i = 0; i < 4; i++)
      ow[(q * 4 + i) * 66 + nd * 16 + r] = o4[nd][i] * li[i];
  __syncthreads();
  #pragma unroll
  for (int c = 0; c < 2; c++) {
    int e = lane + c * 64;
    int row = e >> 3, ch = (e & 7) * 8;
    int t = t0 + w * 16 + row;
    if (t < NSEQ) {
      float* src = ow + row * 66 + ch;
      _Float16* dst = xat + (size_t)t * DIMC + h * 64 + ch;
      h8 cv = *(h8*)dst;
      h8 outv;
      #pragma unroll
      for (int k = 0; k < 8; k++) outv[k] = (_Float16)(src[k] + (float)cv[k]);
      *(h8*)dst = outv;
    }
  }
}

// ---------------- PPEG ----------------
__global__ __launch_bounds__(256)
void k_transpose_fw(const float* __restrict__ h, float* __restrict__ g)
{
  __shared__ float tile[32][33];
  int pb = blockIdx.x * 32, cb = blockIdx.y * 32;
  int x = threadIdx.x & 31, y0 = threadIdx.x >> 5;
  #pragma unroll
  for (int yy = y0; yy < 32; yy += 8)
    tile[yy][x] = h[(size_t)(1 + pb + yy) * DIMC + cb + x];
  __syncthreads();
  #pragma unroll
  for (int yy = y0; yy < 32; yy += 8)
    g[(size_t)(cb + yy) * NPATCH + pb + x] = tile[x][yy];
}

__global__ __launch_bounds__(256)
void k_ppeg(const float* __restrict__ g,
            const float* __restrict__ w7, const float* __restrict__ b7,
            const float* __restrict__ w5, const float* __restrict__ b5,
            const float* __restrict__ w3, const float* __restrict__ b3,
            float* __restrict__ o)
{
  __shared__ float tl[22][22];
  int c = blockIdx.y;
  int ty0 = (blockIdx.x / 13) * 16, tx0 = (blockIdx.x % 13) * 16;
  const float* gc = g + (size_t)c * NPATCH;
  for (int e = threadIdx.x; e < 22 * 22; e += 256) {
    int yy = e / 22, xx = e % 22;
    int y = ty0 - 3 + yy, x = tx0 - 3 + xx;
    tl[yy][xx] = (y >= 0 && y < GRID && x >= 0 && x < GRID) ? gc[y * GRID + x] : 0.f;
  }
  __syncthreads();
  int ly = threadIdx.x >> 4, lx = threadIdx.x & 15;
  int y = ty0 + ly, x = tx0 + lx;
  if (y >= GRID || x >= GRID) return;
  float acc = tl[ly + 3][lx + 3] + b7[c] + b5[c] + b3[c];
  #pragma unroll
  for (int ky = 0; ky < 7; ky++)
    #pragma unroll
    for (int kx = 0; kx < 7; kx++)
      acc += w7[c * 49 + ky * 7 + kx] * tl[ly + ky][lx + kx];
  #pragma unroll
  for (int ky = 0; ky < 5; ky++)
    #pragma unroll
    for (int kx = 0; kx < 5; kx++)
      acc += w5[c * 25 + ky * 5 + kx] * tl[ly + 1 + ky][lx + 1 + kx];
  #pragma unroll
  for (int ky = 0; ky < 3; ky++)
    #pragma unroll
    for (int kx = 0; kx < 3; kx++)
      acc += w3[c * 9 + ky * 3 + kx] * tl[ly + 2 + ky][lx + 2 + kx];
  o[(size_t)c * NPATCH + y * GRID + x] = acc;
}

__global__ __launch_bounds__(256)
void k_transpose_bw(const float* __restrict__ g, float* __restrict__ h)
{
  __shared__ float tile[32][33];
  int pb = blockIdx.x * 32, cb = blockIdx.y * 32;
  int x = threadIdx.x & 31, y0 = threadIdx.x >> 5;
  #pragma unroll
  for (int yy = y0; yy < 32; yy += 8)
    tile[yy][x] = g[(size_t)(cb + yy) * NPATCH + pb + x];
  __syncthreads();
  #pragma unroll
  for (int yy = y0; yy < 32; yy += 8)
    h[(size_t)(1 + pb + yy) * DIMC + cb + x] = tile[x][yy];
}

// ---------------- final: layernorm(row 0) @ fc2 ----------------
__global__ __launch_bounds__(512)
void k_final(const float* __restrict__ h, const float* __restrict__ nw, const float* __restrict__ nb,
             const float* __restrict__ fw, const float* __restrict__ fb, float* __restrict__ out)
{
  __shared__ float sbuf[8];
  int d = threadIdx.x;
  float x = h[d];
  float mu = blkRed<8,false>(x, sbuf) * (1.f / 512.f);
  float dd = x - mu;
  float var = blkRed<8,false>(dd * dd, sbuf) * (1.f / 512.f);
  float cls = dd * rsqrtf(var + 1e-5f) * nw[d] + nb[d];
  float l0 = blkRed<8,false>(cls * fw[d * 2 + 0], sbuf);
  float l1 = blkRed<8,false>(cls * fw[d * 2 + 1], sbuf);
  if (d == 0) { out[0] = l0 + fb[0]; out[1] = l1 + fb[1]; }
}

// ---------------- host orchestration ----------------
struct Pair4 { _Float16 *h, *l, *th, *tl; };
struct WsPtrs {
  float *h, *ql, *kl, *a2, *hmax, *scal, *pm, *ps, *pacc;
  _Float16 *xat16, *q16, *k16, *v16, *vt16, *ql16, *kl16, *x16;
  _Float16 *a2h, *a2l, *avth, *avtl;
  Pair4 zA, zB, xz, u, u2, w2;
};

static void attention_layer(const WsPtrs& P,
                            const float* nw, const float* nb, const _Float16* qkvw16,
                            const _Float16* ow16, const float* ob, const float* rw,
                            hipStream_t stream)
{
  k_zpad<<<64, 256, 0, stream>>>(P.q16, P.k16, P.v16);
  k_ln_pad<<<NSEQ, 256, 0, stream>>>(P.h, nw, nb, P.xat16);
  k_gemm16<<<dim3(NSEQ / 128, 1536 / 128), 256, 0, stream>>>(
      P.xat16, qkvw16, nullptr, nullptr, P.q16, P.k16, P.v16, NSEQ, DIMC, 3 * DIMC, 4);
  k_vt<<<dim3(629, HEADS), 256, 0, stream>>>(P.v16, P.vt16);
  k_landmarks<<<HEADS * MLM, 256, 0, stream>>>(P.q16, P.k16, P.ql, P.kl, P.ql16, P.kl16);
  k_attn2<<<HEADS * MLM, 256, 0, stream>>>(P.ql, P.kl, P.a2);
  k_pinv_init1<<<HEADS, 256, 0, stream>>>(P.a2, P.hmax);
  k_pinv_init2<<<1, 1, 0, stream>>>(P.hmax, P.scal);
  k_pinv_prep<<<HEADS * 16, 256, 0, stream>>>(P.a2, P.scal,
      P.a2h, P.a2l, P.zA.h, P.zA.l, P.zA.th, P.zA.tl);
  Pair4 z = P.zA, zn = P.zB;
  for (int it = 0; it < 6; it++) {
    k_pbmm<<<dim3(16, HEADS), 256, 0, stream>>>(P.a2h, P.a2l, z.th, z.tl,
        nullptr, nullptr, P.xz.h, P.xz.l, P.xz.th, P.xz.tl, MLM, 1.f, 0.f);
    k_pbmm<<<dim3(16, HEADS), 256, 0, stream>>>(P.xz.h, P.xz.l, P.xz.th, P.xz.tl,
        P.xz.h, P.xz.l, P.u.h, P.u.l, P.u.th, P.u.tl, MLM, -1.f, 7.f);
    k_pbmm<<<dim3(16, HEADS), 256, 0, stream>>>(P.xz.h, P.xz.l, P.u.th, P.u.tl,
        P.xz.h, P.xz.l, P.u2.h, P.u2.l, P.u2.th, P.u2.tl, MLM, -1.f, 15.f);
    k_pbmm<<<dim3(16, HEADS), 256, 0, stream>>>(z.h, z.l, P.u2.th, P.u2.tl,
        z.h, z.l, zn.h, zn.l, zn.th, zn.tl, MLM, -0.25f, 3.25f);
    Pair4 t = z; z = zn; zn = t;
  }
  k_attn3<<<dim3(CHUNKS, HEADS), 256, 0, stream>>>(P.ql16, P.k16, P.vt16, P.pm, P.ps, P.pacc);
  k_attn3_reduce<<<HEADS * MLM, 64, 0, stream>>>(P.pm, P.ps, P.pacc, P.avth, P.avtl);
  // w2 = z @ av ; w2^T-hi is the fp16 [h][64][256] operand attn1 wants
  k_pbmm<<<dim3(4, HEADS), 256, 0, stream>>>(z.h, z.l, P.avth, P.avtl,
      nullptr, nullptr, P.w2.h, P.w2.l, P.w2.th, P.w2.tl, DH, 1.f, 0.f);
  k_conv<<<dim3(313, HEADS), 256, 0, stream>>>(P.v16, rw, P.xat16);
  k_attn1<<<dim3(626, HEADS), 256, 0, stream>>>(P.q16, P.kl16, P.w2.th, P.xat16);
  k_gemm16<<<dim3((NTOK + 127) / 128, DIMC / 128), 256, 0, stream>>>(
      P.xat16 + (size_t)PADF * DIMC, ow16, ob, P.h, nullptr, nullptr, nullptr, NTOK, DIMC, DIMC, 2);
}

extern "C" void kernel_launch(void* const* d_in, const int* in_sizes, int n_in,
                              void* d_out, int out_size, void* d_ws, size_t ws_size,
                              hipStream_t stream)
{
  const float* x      = (const float*)d_in[0];
  const float* fc1_w  = (const float*)d_in[1];
  const float* fc1_b  = (const float*)d_in[2];
  const float* cls    = (const float*)d_in[3];
  const float* l1_nw  = (const float*)d_in[4];
  const float* l1_nb  = (const float*)d_in[5];
  const float* l1_qkv = (const float*)d_in[6];
  const float* l1_ow  = (const float*)d_in[7];
  const float* l1_ob  = (const float*)d_in[8];
  const float* l1_rw  = (const float*)d_in[9];
  const float* p7w    = (const float*)d_in[10];
  const float* p7b    = (const float*)d_in[11];
  const float* p5w    = (const float*)d_in[12];
  const float* p5b    = (const float*)d_in[13];
  const float* p3w    = (const float*)d_in[14];
  const float* p3b    = (const float*)d_in[15];
  const float* l2_nw  = (const float*)d_in[16];
  const float* l2_nb  = (const float*)d_in[17];
  const float* l2_qkv = (const float*)d_in[18];
  const float* l2_ow  = (const float*)d_in[19];
  const float* l2_ob  = (const float*)d_in[20];
  const float* l2_rw  = (const float*)d_in[21];
  const float* nw     = (const float*)d_in[22];
  const float* nb     = (const float*)d_in[23];
  const float* fc2w   = (const float*)d_in[24];
  const float* fc2b   = (const float*)d_in[25];
  float* out = (float*)d_out;

  // ---- workspace carve-up (float offsets) ----
  float* W = (float*)d_ws;
  WsPtrs P;
  size_t off = 0;
  P.h     = W + off;               off += 20480512ull;   // 40001 x 512 fp32
  P.xat16 = (_Float16*)(W + off);  off += 10289152ull;   // NSEQ x 512 fp16
  float* R0 = W + off;                                   // fp16 q/k/v/vt region
  P.q16   = (_Float16*)R0;
  P.k16   = P.q16 + 20594688ull;   // 8 x 40224 x 64
  P.v16   = P.k16 + 20594688ull;
  P.vt16  = P.v16 + 20594688ull;   // 8 x 64 x 40224
  P.x16   = P.q16;                 // alias: fc1 input fp16 (dead before qkv GEMM)
  off += 41189376ull;              // 4 x 20594688 halfs / 2
  P.ql    = W + off; off += 131072;
  P.kl    = W + off; off += 131072;
  P.ql16  = (_Float16*)(W + off); off += 65536;
  P.kl16  = (_Float16*)(W + off); off += 65536;
  P.a2    = W + off; off += 524288;
  // fp16 pair region for pinv (sizes in halves -> float offsets are /2)
  _Float16* HP = (_Float16*)(W + off);
  size_t ho = 0;
  P.a2h = HP + ho; ho += 524288; P.a2l = HP + ho; ho += 524288;
  auto alloc4 = [&](Pair4& p, size_t n) {
    p.h = HP + ho; ho += n; p.l = HP + ho; ho += n;
    p.th = HP + ho; ho += n; p.tl = HP + ho; ho += n;
  };
  alloc4(P.zA, 524288); alloc4(P.zB, 524288); alloc4(P.xz, 524288);
  alloc4(P.u, 524288);  alloc4(P.u2, 524288);
  alloc4(P.w2, 131072);
  P.avth = HP + ho; ho += 131072; P.avtl = HP + ho; ho += 131072;
  off += (ho + 1) / 2;
  P.hmax  = W + off; P.scal = P.hmax + 16; off += 32;
  P.pm    = W + off; off += 131072;
  P.ps    = W + off; off += 131072;
  P.pacc  = W + off; off += 8388608;
  _Float16* fc1t  = (_Float16*)(W + off);   // 512x1024
  _Float16* qkv1t = fc1t  + 524288;         // 1536x512
  _Float16* out1t = qkv1t + 786432;         // 512x512
  _Float16* qkv2t = out1t + 262144;
  _Float16* out2t = qkv2t + 786432;

  // ---- weight fp32 -> fp16 transposed (N x K) ----
  k_wt16<<<dim3(INDIM / 32, DIMC / 32), 256, 0, stream>>>(fc1_w, fc1t, INDIM, DIMC);
  k_wt16<<<dim3(DIMC / 32, 1536 / 32), 256, 0, stream>>>(l1_qkv, qkv1t, DIMC, 1536);
  k_wt16<<<dim3(DIMC / 32, DIMC / 32), 256, 0, stream>>>(l1_ow, out1t, DIMC, DIMC);
  k_wt16<<<dim3(DIMC / 32, 1536 / 32), 256, 0, stream>>>(l2_qkv, qkv2t, DIMC, 1536);
  k_wt16<<<dim3(DIMC / 32, DIMC / 32), 256, 0, stream>>>(l2_ow, out2t, DIMC, DIMC);

  // fc1 + relu -> h rows 1..40000 ; cls token -> h row 0
  k_f32_to_f16<<<NPATCH * INDIM / 1024, 256, 0, stream>>>(x, P.x16);
  k_gemm16<<<dim3((NPATCH + 127) / 128, DIMC / 128), 256, 0, stream>>>(
      P.x16, fc1t, fc1_b, P.h + DIMC, nullptr, nullptr, nullptr, NPATCH, INDIM, DIMC, 1);
  k_set_cls<<<1, 512, 0, stream>>>(cls, P.h);

  // layer 1 attention
  attention_layer(P, l1_nw, l1_nb, qkv1t, out1t, l1_ob, l1_rw, stream);

  // PPEG (aliases the q/k/v fp16 region as fp32 scratch)
  float* fgrid = R0;
  float* cout  = R0 + 20480000ull;
  k_transpose_fw<<<dim3(NPATCH / 32, DIMC / 32), 256, 0, stream>>>(P.h, fgrid);
  k_ppeg<<<dim3(13 * 13, DIMC), 256, 0, stream>>>(fgrid, p7w, p7b, p5w, p5b, p3w, p3b, cout);
  k_transpose_bw<<<dim3(NPATCH / 32, DIMC / 32), 256, 0, stream>>>(cout, P.h);

  // layer 2 attention
  attention_layer(P, l2_nw, l2_nb, qkv2t, out2t, l2_ob, l2_rw, stream);

  // final layernorm (cls row only) + fc2
  k_final<<<1, 512, 0, stream>>>(P.h, nw, nb, fc2w, fc2b, out);
}